// Round 6
// baseline (932.555 us; speedup 1.0000x reference)
//
#include <hip/hip_runtime.h>
#include <hip/hip_bf16.h>
#include <stdint.h>

#define TOK_TOTAL 102400   // 32*3200
#define L_SEQ 3200

typedef __attribute__((ext_vector_type(8))) short bf16x8;
typedef __attribute__((ext_vector_type(4))) short s16x4;
typedef __attribute__((ext_vector_type(2))) short s16x2;
typedef __attribute__((ext_vector_type(4))) float f32x4;

__device__ __forceinline__ short f2bf(float f){
  union { __hip_bfloat16 h; short s; } u;
  u.h = __float2bfloat16(f);
  return u.s;
}

__device__ __forceinline__ f32x4 mfma16(bf16x8 a, bf16x8 b, f32x4 c){
  return __builtin_amdgcn_mfma_f32_16x16x32_bf16(a, b, c, 0, 0, 0);
}

__device__ __forceinline__ void glds16(const short* g, short* l){
  __builtin_amdgcn_global_load_lds((const __attribute__((address_space(1))) unsigned*)g,
                                   (__attribute__((address_space(3))) unsigned*)l, 16, 0, 0);
}

// bijective XCD-chunk swizzle (m204)
__device__ __forceinline__ int xswz(int bid, int nwg){
  int q = nwg >> 3, r = nwg & 7, x = bid & 7, k = bid >> 3;
  return (x < r ? x * (q + 1) : r * (q + 1) + (x - r) * q) + k;
}

// ---------------- embT: bf16 embedding table with sqrt(512) folded (100x512) ----------------
__global__ void embcast_k(const float* __restrict__ emb, short* __restrict__ embT){
  int gid = blockIdx.x * 256 + threadIdx.x;     // 6400 threads, 8 elems each
  const float SC = 22.627416997969522f;
  const float4 f0 = ((const float4*)emb)[gid*2];
  const float4 f1 = ((const float4*)emb)[gid*2+1];
  bf16x8 o;
  o[0]=f2bf(f0.x*SC); o[1]=f2bf(f0.y*SC); o[2]=f2bf(f0.z*SC); o[3]=f2bf(f0.w*SC);
  o[4]=f2bf(f1.x*SC); o[5]=f2bf(f1.y*SC); o[6]=f2bf(f1.z*SC); o[7]=f2bf(f1.w*SC);
  *(bf16x8*)(embT + gid*8) = o;
}

// ---------------- transpose f32 [R,C] -> bf16 [C,R], packed s16x4 stores ----------------
__global__ void transpose_cast(const float* __restrict__ in, short* __restrict__ out,
                               int R, int C){
  __shared__ float tile[32][33];
  int c0 = blockIdx.x * 32, r0 = blockIdx.y * 32;
  int tx = threadIdx.x, ty = threadIdx.y;       // 32x8
  #pragma unroll
  for (int i = 0; i < 32; i += 8)
    tile[ty + i][tx] = in[(size_t)(r0 + ty + i) * C + c0 + tx];
  __syncthreads();
  // write phase: flat remap, each thread emits one s16x4 (4 consecutive r of one c)
  const int t = ty * 32 + tx;                   // 0..255
  const int c = t >> 3;                         // 0..31
  const int r4 = (t & 7) << 2;                  // 0,4,...,28
  s16x4 o4;
  #pragma unroll
  for (int j = 0; j < 4; ++j) o4[j] = f2bf(tile[r4 + j][c]);
  *(s16x4*)(out + (size_t)(c0 + c) * R + r0 + r4) = o4;
}

// ---------------- plain cast f32 -> bf16 (8 elems/thread) ----------------
__global__ void cast_k(const float* __restrict__ in, short* __restrict__ out){
  int gid = blockIdx.x * 256 + threadIdx.x;
  const float4 f0 = ((const float4*)in)[gid*2];
  const float4 f1 = ((const float4*)in)[gid*2+1];
  bf16x8 o;
  o[0]=f2bf(f0.x); o[1]=f2bf(f0.y); o[2]=f2bf(f0.z); o[3]=f2bf(f0.w);
  o[4]=f2bf(f1.x); o[5]=f2bf(f1.y); o[6]=f2bf(f1.z); o[7]=f2bf(f1.w);
  *(bf16x8*)(out + gid*8) = o;
}

// ---------------- bias fold: cbadd[j] = sum_r bo[r&511] * wtpT[j][r] ----------------
__global__ void bias_fold_k(const short* __restrict__ wtpT, const float* __restrict__ bo,
                            float* __restrict__ cbadd, int Kpm){
  int j = blockIdx.x;
  const short* row = wtpT + (size_t)j * Kpm;
  float s = 0.f;
  for (int r = threadIdx.x; r < Kpm; r += 256){
    union { unsigned u; float f; } c; c.u = ((unsigned)(unsigned short)row[r]) << 16;
    s += c.f * bo[r & 511];
  }
  s += __shfl_xor(s, 1);  s += __shfl_xor(s, 2);  s += __shfl_xor(s, 4);
  s += __shfl_xor(s, 8);  s += __shfl_xor(s, 16); s += __shfl_xor(s, 32);
  __shared__ float red[4];
  if ((threadIdx.x & 63) == 0) red[threadIdx.x >> 6] = s;
  __syncthreads();
  if (threadIdx.x == 0) cbadd[j] = red[0] + red[1] + red[2] + red[3];
}

// ---------------- split-K reduce + bias (writes each out element exactly once) ----------------
__global__ void reduce_k(const float* __restrict__ part, float* __restrict__ out,
                         const float* __restrict__ pb, const float* __restrict__ cb,
                         int Mc, int S, int rpb, int roff){
  int gid = blockIdx.x * 256 + threadIdx.x;     // Mc*512 threads
  int col = gid & 511;
  int rr = gid >> 9;
  float s = pb[col] + cb[col];
  const float* p = part + (size_t)rr * 512 + col;
  const size_t stride = (size_t)Mc * 512;
  for (int k = 0; k < S; ++k) s += p[(size_t)k * stride];
  int ob = rr / rpb;
  int orow = rr - ob * rpb;
  out[(size_t)(ob * 375 + roff + orow) * 512 + col] = s;
}

// ---------------- 128^2 GEMM C = A[M,K] @ Bt[N,K]^T, BK=64, swizzled LDS ----------------
// MODE 0: bf16 store + f32 bias, C row-major [M][ldc]  (qkvtab precompute).
__global__ __launch_bounds__(256)
void gemm_bt(const short* __restrict__ A, int lda,
             const short* __restrict__ Bt, int ldb,
             void* __restrict__ Cv, int ldc,
             int M, int N, int K,
             const float* __restrict__ bias,
             int kc)
{
  __shared__ short alds[8192];   // [128][64]
  __shared__ short blds[8192];

  const int t = threadIdx.x;
  const int Mt = (M + 127) >> 7;
  const int Nt = N >> 7;
  int wg = xswz(blockIdx.x, gridDim.x);
  const int bn = wg % Nt; wg /= Nt;
  const int bm = wg % Mt; wg /= Mt;
  const int ksp = wg;
  int kbeg = ksp * kc, kend = kbeg + kc; if (kend > K) kend = K;

  const int srow = t >> 3;                      // 0..31
  const int scol = (t & 7) << 3;
  const int scolz = scol ^ ((srow & 7) << 3);   // swizzled SOURCE column (m173)
  const short* ga[4]; const short* gb[4];
  #pragma unroll
  for (int p = 0; p < 4; ++p){
    int arow = bm*128 + srow + p*32; if (arow >= M) arow = M - 1;
    ga[p] = A + (size_t)arow * lda + kbeg + scolz;
    gb[p] = Bt + (size_t)(bn*128 + srow + p*32) * ldb + kbeg + scolz;
  }
  short* la = alds + t * 8;
  short* lb = blds + t * 8;

  const int wave = t >> 6;
  const int lane = t & 63;
  const int wm = (wave >> 1) << 6;
  const int wn = (wave & 1) << 6;
  const int fr = lane & 15;
  const int fk = (lane >> 4) << 3;
  const int fx = (fr & 7) << 3;

  f32x4 acc[4][4] = {};

  for (int kt = kbeg; kt < kend; kt += 64) {
    #pragma unroll
    for (int p = 0; p < 4; ++p){
      glds16(ga[p], la + p*2048);
      glds16(gb[p], lb + p*2048);
      ga[p] += 64; gb[p] += 64;
    }
    __syncthreads();
    bf16x8 af[2][4], bfr[2][4];
    #pragma unroll
    for (int ks = 0; ks < 2; ++ks){
      const int kcz = (ks*32 + fk) ^ fx;
      #pragma unroll
      for (int m = 0; m < 4; ++m) af[ks][m] = *(const bf16x8*)(alds + (wm + m*16 + fr)*64 + kcz);
      #pragma unroll
      for (int n = 0; n < 4; ++n) bfr[ks][n] = *(const bf16x8*)(blds + (wn + n*16 + fr)*64 + kcz);
    }
    #pragma unroll
    for (int ks = 0; ks < 2; ++ks)
      #pragma unroll
      for (int m = 0; m < 4; ++m)
        #pragma unroll
        for (int n = 0; n < 4; ++n)
          acc[m][n] = mfma16(af[ks][m], bfr[ks][n], acc[m][n]);
    __syncthreads();
  }

  const int rb = (lane >> 4) << 2;
  short* C = (short*)Cv;
  #pragma unroll
  for (int m = 0; m < 4; ++m){
    const int row0 = bm*128 + wm + m*16 + rb;
    #pragma unroll
    for (int n = 0; n < 4; ++n){
      const int col = bn*128 + wn + n*16 + fr;
      const float bv = bias[col];
      #pragma unroll
      for (int r = 0; r < 4; ++r){
        const int rr = row0 + r;
        if (rr < M) C[(size_t)rr * ldc + col] = f2bf(acc[m][n][r] + bv);
      }
    }
  }
}

// ---------------- 256^2 deep-pipelined GEMM (T2+T3+T4+T5) ----------------
// MODE 0 (split-K patch-merge): Cpart[ksp][M][512] = A[M,lda] @ Bt[512,ldb]^T over
//        K-slice [ksp*kc, +kc), f32 partial store.
// MODE 1 (batched compose): per batch p (=ksp), C[j][p*512+c] = sum_m A[j][p*512+m]
//        * Bt[c][m] — A K-slice offset p*512, B K-offset 0, bf16 store, ldc stride.
// 512 thr = 8 waves (2Mx4N), per-wave C 128x64, BK=64, LDS 128 KiB = 2 dbuf x (A|B).
// 4 phases per K-tile; counted vmcnt (6)/(8), never drained in main loop.
template<int MODE>
__global__ __launch_bounds__(512, 2)
void gemm256_pm(const short* __restrict__ A, int lda,
                const short* __restrict__ Bt, int ldb,
                void* __restrict__ Cv, int M, int kc, int ldc)
{
  extern __shared__ short lds_s[];
  const int tid = threadIdx.x;
  const int Mt = (M + 255) >> 8;
  int wg = xswz(blockIdx.x, gridDim.x);
  const int bn = wg & 1; wg >>= 1;
  const int bm = wg % Mt;
  const int ksp = wg / Mt;
  const int kbeg = ksp * kc;
  const int kbegB = (MODE == 1) ? 0 : kbeg;     // compose: B K-range is always [0,512)

  const int wave = tid >> 6, lane = tid & 63;
  const int wm = wave >> 2, wn = wave & 3;   // 2M x 4N waves
  const int fr = lane & 15, kq = lane >> 4;
  const int fx = fr & 7;
  const int sx0 = (kq ^ fx) << 3;            // swizzled 16B slot, ks=0 (shorts)
  const int sx1 = ((4 + kq) ^ fx) << 3;      // ks=1
  const int aoff = (wm * 64 + fr) << 6;      // phys A row * 64 shorts
  const int boff = (wn * 32 + fr) << 6;

  const int sr = tid >> 3;
  const int kg = ((tid & 7) ^ (sr & 7)) << 3;
  const short* srcA[2][2]; const short* srcB[2][2];
  #pragma unroll
  for (int h = 0; h < 2; ++h)
    #pragma unroll
    for (int u = 0; u < 2; ++u){
      int r = bm * 256 + u * 128 + h * 64 + sr; if (r >= M) r = M - 1;
      srcA[h][u] = A + (size_t)r * lda + kbeg + kg;
      const int br = (u * 2 + (sr >> 5)) * 64 + h * 32 + (sr & 31);
      srcB[h][u] = Bt + (size_t)(bn * 256 + br) * ldb + kbegB + kg;
    }

#define STG_A(dst, h, ko) do { \
    glds16(srcA[h][0] + (ko), (dst) + (h)*8192 + tid*8); \
    glds16(srcA[h][1] + (ko), (dst) + (h)*8192 + 4096 + tid*8); } while(0)
#define STG_B(dst, h, ko) do { \
    glds16(srcB[h][0] + (ko), (dst) + 16384 + (h)*8192 + tid*8); \
    glds16(srcB[h][1] + (ko), (dst) + 16384 + (h)*8192 + 4096 + tid*8); } while(0)

  short* Lc = lds_s;
  short* Ln = lds_s + 32768;

  f32x4 acc[8][4] = {};
  bf16x8 af[4][2], b0[2][2], b1[2][2];

  STG_A(Lc, 0, 0);  STG_B(Lc, 0, 0);
  STG_A(Lc, 1, 0);  STG_B(Lc, 1, 0);
  STG_A(Ln, 0, 64); STG_B(Ln, 0, 64);
  asm volatile("s_waitcnt vmcnt(8)" ::: "memory");
  __builtin_amdgcn_s_barrier();

  const int T = kc >> 6;
  for (int t = 0; t < T; ++t){
    const int k1 = ((t + 1 < T) ? t + 1 : T - 1) << 6;
    const int k2 = ((t + 2 < T) ? t + 2 : T - 1) << 6;
    // ---- phase 0
    #pragma unroll
    for (int m = 0; m < 4; ++m){
      af[m][0] = *(const bf16x8*)(Lc + aoff + m*1024 + sx0);
      af[m][1] = *(const bf16x8*)(Lc + aoff + m*1024 + sx1);
    }
    #pragma unroll
    for (int n = 0; n < 2; ++n){
      b0[n][0] = *(const bf16x8*)(Lc + 16384 + boff + n*1024 + sx0);
      b0[n][1] = *(const bf16x8*)(Lc + 16384 + boff + n*1024 + sx1);
    }
    STG_A(Ln, 1, k1);
    __builtin_amdgcn_s_barrier();
    asm volatile("s_waitcnt lgkmcnt(0)");
    __builtin_amdgcn_s_setprio(1);
    #pragma unroll
    for (int m = 0; m < 4; ++m)
      #pragma unroll
      for (int n = 0; n < 2; ++n){
        acc[m][n] = mfma16(af[m][0], b0[n][0], acc[m][n]);
        acc[m][n] = mfma16(af[m][1], b0[n][1], acc[m][n]);
      }
    __builtin_amdgcn_s_setprio(0);
    asm volatile("s_waitcnt vmcnt(6)" ::: "memory");
    __builtin_amdgcn_s_barrier();
    // ---- phase 1
    #pragma unroll
    for (int n = 0; n < 2; ++n){
      b1[n][0] = *(const bf16x8*)(Lc + 24576 + boff + n*1024 + sx0);
      b1[n][1] = *(const bf16x8*)(Lc + 24576 + boff + n*1024 + sx1);
    }
    STG_B(Ln, 1, k1);
    __builtin_amdgcn_s_barrier();
    asm volatile("s_waitcnt lgkmcnt(0)");
    __builtin_amdgcn_s_setprio(1);
    #pragma unroll
    for (int m = 0; m < 4; ++m)
      #pragma unroll
      for (int n = 0; n < 2; ++n){
        acc[m][2+n] = mfma16(af[m][0], b1[n][0], acc[m][2+n]);
        acc[m][2+n] = mfma16(af[m][1], b1[n][1], acc[m][2+n]);
      }
    __builtin_amdgcn_s_setprio(0);
    __builtin_amdgcn_s_barrier();
    // ---- phase 2
    #pragma unroll
    for (int m = 0; m < 4; ++m){
      af[m][0] = *(const bf16x8*)(Lc + 8192 + aoff + m*1024 + sx0);
      af[m][1] = *(const bf16x8*)(Lc + 8192 + aoff + m*1024 + sx1);
    }
    STG_A(Lc, 0, k2);
    __builtin_amdgcn_s_barrier();
    asm volatile("s_waitcnt lgkmcnt(0)");
    __builtin_amdgcn_s_setprio(1);
    #pragma unroll
    for (int m = 0; m < 4; ++m)
      #pragma unroll
      for (int n = 0; n < 2; ++n){
        acc[4+m][n] = mfma16(af[m][0], b0[n][0], acc[4+m][n]);
        acc[4+m][n] = mfma16(af[m][1], b0[n][1], acc[4+m][n]);
      }
    __builtin_amdgcn_s_setprio(0);
    __builtin_amdgcn_s_barrier();
    // ---- phase 3
    STG_B(Lc, 0, k2);
    __builtin_amdgcn_s_barrier();
    __builtin_amdgcn_s_setprio(1);
    #pragma unroll
    for (int m = 0; m < 4; ++m)
      #pragma unroll
      for (int n = 0; n < 2; ++n){
        acc[4+m][2+n] = mfma16(af[m][0], b1[n][0], acc[4+m][2+n]);
        acc[4+m][2+n] = mfma16(af[m][1], b1[n][1], acc[4+m][2+n]);
      }
    __builtin_amdgcn_s_setprio(0);
    asm volatile("s_waitcnt vmcnt(8)" ::: "memory");
    __builtin_amdgcn_s_barrier();
    short* tp = Lc; Lc = Ln; Ln = tp;
  }
#undef STG_A
#undef STG_B

  const int rb4 = kq << 2;
  if (MODE == 0){
    float* Cp = (float*)Cv + (size_t)ksp * M * 512;
    #pragma unroll
    for (int mh = 0; mh < 2; ++mh)
      #pragma unroll
      for (int m = 0; m < 4; ++m){
        const int row0 = bm*256 + wm*128 + mh*64 + m*16 + rb4;
        #pragma unroll
        for (int r = 0; r < 4; ++r){
          const int rr = row0 + r;
          if (rr < M){
            float* Crow = Cp + (size_t)rr * 512 + bn*256 + wn*64 + fr;
            #pragma unroll
            for (int nh = 0; nh < 2; ++nh)
              #pragma unroll
              for (int n = 0; n < 2; ++n)
                Crow[nh*32 + n*16] = acc[mh*4+m][nh*2+n][r];
          }
        }
      }
  } else {
    // compose: bf16 store to C[j][kbeg + c], ldc = Kpm
    short* Cs = (short*)Cv;
    #pragma unroll
    for (int mh = 0; mh < 2; ++mh)
      #pragma unroll
      for (int m = 0; m < 4; ++m){
        const int row0 = bm*256 + wm*128 + mh*64 + m*16 + rb4;
        #pragma unroll
        for (int r = 0; r < 4; ++r){
          const int rr = row0 + r;
          if (rr < M){
            short* Crow = Cs + (size_t)rr * ldc + kbeg + bn*256 + wn*64 + fr;
            #pragma unroll
            for (int nh = 0; nh < 2; ++nh)
              #pragma unroll
              for (int n = 0; n < 2; ++n)
                Crow[nh*32 + n*16] = f2bf(acc[mh*4+m][nh*2+n][r]);
          }
        }
      }
  }
}

// ---------------- table-gather windowed MHA: one wave per (window, head) ----------------
// tab: [100][1536] bf16 per window (Q|K|V rows per vocab value, bias folded).
// v9: swapped QK^T (in-lane softmax), packed P/V/O stores, WIN=16 pad zero-fill.
template<int WIN>
__global__ __launch_bounds__(256)
void attn_g(const int* __restrict__ spec, const short* __restrict__ tab,
            short* __restrict__ ao){
  constexpr int WINP = (WIN < 32) ? 32 : WIN;     // padded k-dim
  constexpr int KMASK = WINP / 8 - 1;             // in-row swizzle key clamp
  constexpr int NT = WIN / 16;
  extern __shared__ short smem[];                 // per wave: Vt[64][WINP] + P[16][WINP]
  const int lane = threadIdx.x & 63;
  const int w = threadIdx.x >> 6;
  const int wh = blockIdx.x * 4 + w;
  const int wid = wh >> 3, h = wh & 7;
  const size_t tb = (size_t)wid * WIN;
  short* vt = smem + w * 80 * WINP;
  short* pl = vt + 64 * WINP;

  const int fr = lane & 15;
  const int fk = (lane >> 4) << 3;
  const int kq = lane >> 4;
  const int rb = kq << 2;

  // ---- V^T staging: (KRUN k x 8 d) cells, packed LDS writes.
  // element (d,k) -> vt[d*WINP + (k ^ ((d&KMASK)<<3))]
  {
    constexpr int KRUN = (WIN >= 32) ? 4 : 2;
    constexpr int ITER = (WIN / KRUN) * 8 / 64;   // 1,1,2,4
    const int dgrp = lane & 7;
    #pragma unroll
    for (int it = 0; it < ITER; ++it){
      const int kb = ((lane >> 3) + it * 8) * KRUN;
      bf16x8 vv[KRUN];
      #pragma unroll
      for (int kk = 0; kk < KRUN; ++kk)
        vv[kk] = *(const bf16x8*)(tab + (size_t)spec[tb + kb + kk] * 1536 + 1024 + h * 64 + dgrp * 8);
      #pragma unroll
      for (int j = 0; j < 8; ++j){
        const int d = dgrp * 8 + j;
        short* dst = vt + d * WINP + (kb ^ ((d & KMASK) << 3));
        if constexpr (KRUN == 4){
          s16x4 wv; wv[0]=vv[0][j]; wv[1]=vv[1][j]; wv[2]=vv[2][j]; wv[3]=vv[3][j];
          *(s16x4*)dst = wv;
        } else {
          s16x2 wv; wv[0]=vv[0][j]; wv[1]=vv[1][j];
          *(s16x2*)dst = wv;
        }
      }
    }
  }
  if constexpr (WIN == 16){
    // zero-fill V^T pad (logical k=16..31 of every d-row): uninitialized LDS may
    // hold NaN bf16 patterns and 0*NaN = NaN. lane == d (64 lanes, 64 rows).
    const int d = lane;
    const int key = (d & KMASK) << 3;
    short* vrow_ = vt + d * WINP;
    const s16x4 z = {0, 0, 0, 0};
    #pragma unroll
    for (int kk = 16; kk < 32; kk += 4)
      *(s16x4*)(vrow_ + (kk ^ key)) = z;
  }

  // ---- hoisted K row pointers; K fragments in regs for NT<=4
  const short* kp8[NT];
  #pragma unroll
  for (int nt = 0; nt < NT; ++nt)
    kp8[nt] = tab + (size_t)spec[tb + nt*16 + fr] * 1536 + 512 + h*64 + fk;

  bf16x8 bkh[(NT <= 4) ? NT : 1][2];
  if constexpr (NT <= 4){
    #pragma unroll
    for (int nt = 0; nt < NT; ++nt){
      bkh[nt][0] = *(const bf16x8*)(kp8[nt]);
      bkh[nt][1] = *(const bf16x8*)(kp8[nt] + 32);
    }
  }

  const int rxq = (fr & KMASK) << 3;              // P-row swizzle key (row = q = fr)
  short* plq = pl + fr * WINP;

  for (int qt = 0; qt < NT; ++qt){
    // Q row token == K row token for the same (tile, fr): reuse pointer, offset -512
    const short* qrow = kp8[qt] - 512;
    bf16x8 aq0 = *(const bf16x8*)(qrow);
    bf16x8 aq1 = *(const bf16x8*)(qrow + 32);
    float s[NT][4];
    #pragma unroll
    for (int nt = 0; nt < NT; ++nt){
      bf16x8 k0, k1;
      if constexpr (NT <= 4){ k0 = bkh[nt][0]; k1 = bkh[nt][1]; }
      else { k0 = *(const bf16x8*)(kp8[nt]); k1 = *(const bf16x8*)(kp8[nt] + 32); }
      f32x4 c = {0.f, 0.f, 0.f, 0.f};
      c = mfma16(k0, aq0, c);                     // swapped: C[k_local][q = lane&15]
      c = mfma16(k1, aq1, c);
      #pragma unroll
      for (int r = 0; r < 4; ++r) s[nt][r] = c[r] * 0.125f;
    }
    // in-lane softmax for q = fr: tree max/sum over 4*NT values + 2 shfls each
    float mm[NT];
    #pragma unroll
    for (int nt = 0; nt < NT; ++nt)
      mm[nt] = fmaxf(fmaxf(s[nt][0], s[nt][1]), fmaxf(s[nt][2], s[nt][3]));
    #pragma unroll
    for (int st = NT >> 1; st >= 1; st >>= 1)
      #pragma unroll
      for (int i = 0; i < st; ++i) mm[i] = fmaxf(mm[i], mm[i + st]);
    float m = mm[0];
    m = fmaxf(m, __shfl_xor(m, 16));
    m = fmaxf(m, __shfl_xor(m, 32));
    float ss[NT];
    #pragma unroll
    for (int nt = 0; nt < NT; ++nt){
      #pragma unroll
      for (int r = 0; r < 4; ++r) s[nt][r] = __expf(s[nt][r] - m);
      ss[nt] = (s[nt][0] + s[nt][1]) + (s[nt][2] + s[nt][3]);
    }
    #pragma unroll
    for (int st = NT >> 1; st >= 1; st >>= 1)
      #pragma unroll
      for (int i = 0; i < st; ++i) ss[i] += ss[i + st];
    float sum = ss[0];
    sum += __shfl_xor(sum, 16);
    sum += __shfl_xor(sum, 32);
    const float inv = 1.f / sum;
    // packed P store: lane owns k = nt*16 + rb + 0..3 of row q=fr (contiguous, b64)
    #pragma unroll
    for (int nt = 0; nt < NT; ++nt){
      s16x4 pw;
      pw[0] = f2bf(s[nt][0] * inv); pw[1] = f2bf(s[nt][1] * inv);
      pw[2] = f2bf(s[nt][2] * inv); pw[3] = f2bf(s[nt][3] * inv);
      *(s16x4*)(plq + ((nt*16 + rb) ^ rxq)) = pw;
    }
    if (WIN == 16){
      s16x4 pz = {0, 0, 0, 0};
      *(s16x4*)(plq + ((16 + rb) ^ rxq)) = pz;
    }
    // PV with swapped operands: lane (fr,kq) gets O[q=fr][d=d0*16+kq*4+r] -> packed store
    short* aorow = ao + (tb + qt*16 + fr) * 512 + h*64 + rb;
    if constexpr (WINP / 32 <= 2){
      // hoist P fragments once (d0-invariant); cheap in VGPRs for WIN<=64
      bf16x8 aph[WINP / 32];
      #pragma unroll
      for (int ks = 0; ks < WINP/32; ++ks)
        aph[ks] = *(const bf16x8*)(pl + fr * WINP + ((ks*32 + fk) ^ rxq));
      #pragma unroll
      for (int d0 = 0; d0 < 4; ++d0){
        const int vrow = d0*16 + fr;
        const int vx = (vrow & KMASK) << 3;
        f32x4 o = {0.f, 0.f, 0.f, 0.f};
        #pragma unroll
        for (int ks = 0; ks < WINP/32; ++ks){
          bf16x8 bv = *(const bf16x8*)(vt + vrow * WINP + ((ks*32 + fk) ^ vx));
          o = mfma16(bv, aph[ks], o);
        }
        s16x4 ov;
        ov[0]=f2bf(o[0]); ov[1]=f2bf(o[1]); ov[2]=f2bf(o[2]); ov[3]=f2bf(o[3]);
        *(s16x4*)(aorow + d0*16) = ov;
      }
    } else {
      // WIN=128: reload ap per d0 (keeps VGPR below the 128 cliff)
      #pragma unroll
      for (int d0 = 0; d0 < 4; ++d0){
        const int vrow = d0*16 + fr;
        const int vx = (vrow & KMASK) << 3;
        f32x4 o = {0.f, 0.f, 0.f, 0.f};
        #pragma unroll
        for (int ks = 0; ks < WINP/32; ++ks){
          bf16x8 ap = *(const bf16x8*)(pl + fr * WINP + ((ks*32 + fk) ^ rxq));
          bf16x8 bv = *(const bf16x8*)(vt + vrow * WINP + ((ks*32 + fk) ^ vx));
          o = mfma16(bv, ap, o);
        }
        s16x4 ov;
        ov[0]=f2bf(o[0]); ov[1]=f2bf(o[1]); ov[2]=f2bf(o[2]); ov[3]=f2bf(o[3]);
        *(s16x4*)(aorow + d0*16) = ov;
      }
    }
    // no __syncthreads: smem slices are wave-private; in-wave lgkmcnt ordering suffices
  }
}

// ---------------- host ----------------
extern "C" void kernel_launch(void* const* d_in, const int* in_sizes, int n_in,
                              void* d_out, int out_size, void* d_ws, size_t ws_size,
                              hipStream_t stream){
  const int*   spec   = (const int*)d_in[0];
  const float* emb    = (const float*)d_in[1];
  const float* attn_w = (const float*)d_in[2];
  const float* attn_b = (const float*)d_in[3];
  const float* pw[4]  = {(const float*)d_in[4], (const float*)d_in[6],
                         (const float*)d_in[8], (const float*)d_in[10]};
  const float* pb[4]  = {(const float*)d_in[5], (const float*)d_in[7],
                         (const float*)d_in[9], (const float*)d_in[11]};
  float* out = (float*)d_out;

  // fixed buffers (~135.5 MB): wtq | wcast | wtpc | cbadd | embT | qkvtab
  short* wtq    = (short*)d_ws;             // [4][1536][512] transposed q,k,v
  short* wcast  = wtq + 3145728;            // [4][512][512] Wo cast
  short* wtpc   = wcast + 1048576;          // composed pm weights
  float* cbadd  = (float*)(wtpc + 62914560);// [4][512]
  short* embT   = (short*)(cbadd + 2048);   // [100][512]
  short* qkvtab = embT + 51200;             // [4][100][1536]
  short* dyn    = qkvtab + 614400;

  short* aob  = dyn;                        // [102400][512] bf16 (105 MB)
  float* pbuf = (float*)(aob + (size_t)TOK_TOTAL * 512); // split-K partials (52 MB)
  short* scratch = dyn;                     // pw^T staging (prep only, aliases aob)

  static const int winv[4]  = {16, 32, 64, 128};
  static const int wpoff[4] = {0, 16*262144, 48*262144, 112*262144};
  static const int roffv[4] = {0, 200, 300, 350};

  (void)hipFuncSetAttribute(reinterpret_cast<const void*>(gemm256_pm<0>),
                            hipFuncAttributeMaxDynamicSharedMemorySize, 131072);
  (void)hipFuncSetAttribute(reinterpret_cast<const void*>(gemm256_pm<1>),
                            hipFuncAttributeMaxDynamicSharedMemorySize, 131072);

  embcast_k<<<25, 256, 0, stream>>>(emb, embT);
  dim3 tb(32, 8);
  for (int i = 0; i < 4; ++i){
    const int win = winv[i];
    const int Kpm = win * 512;
    for (int j = 0; j < 3; ++j)
      transpose_cast<<<dim3(16,16), tb, 0, stream>>>(attn_w + (size_t)(i*4+j)*262144,
                                                     wtq + (size_t)(i*3+j)*262144, 512, 512);
    cast_k<<<128, 256, 0, stream>>>(attn_w + (size_t)(i*4+3)*262144, wcast + (size_t)i*262144);
    transpose_cast<<<dim3(16, win*16), tb, 0, stream>>>(pw[i], scratch, Kpm, 512);
    bias_fold_k<<<512, 256, 0, stream>>>(scratch, attn_b + i*2048 + 1536, cbadd + i*512, Kpm);
    // compose wtpc[j][p*512+c] = sum_m scratch[j][p*512+m] * wcast[c][m]  (deep-pipelined)
    gemm256_pm<1><<<win*4, 512, 131072, stream>>>(scratch, Kpm, wcast + (size_t)i*262144, 512,
                                                  wtpc + wpoff[i], 512, 512, Kpm);
    // qkvtab_i[100][1536] = embT @ wtq_i^T + bias(q|k|v)
    gemm_bt<<<12, 256, 0, stream>>>(embT, 512, wtq + (size_t)i*3*262144, 512,
                                    qkvtab + (size_t)i*153600, 1536,
                                    100, 1536, 512, attn_b + i*2048, 512);
  }

  for (int i = 0; i < 4; ++i){
    const int win = winv[i];
    const short* tabw = qkvtab + (size_t)i * 153600;
    const int blocks = (TOK_TOTAL / win) * 8 / 4;
    const int winp = (win < 32) ? 32 : win;
    const size_t shmem = (size_t)4 * 80 * winp * 2;
    if (win == 16)       attn_g<16 ><<<blocks, 256, shmem, stream>>>(spec, tabw, aob);
    else if (win == 32)  attn_g<32 ><<<blocks, 256, shmem, stream>>>(spec, tabw, aob);
    else if (win == 64)  attn_g<64 ><<<blocks, 256, shmem, stream>>>(spec, tabw, aob);
    else                 attn_g<128><<<blocks, 256, shmem, stream>>>(spec, tabw, aob);
    // patch-merge split-K (kc=2048) via 256^2 pipelined GEMM, then deterministic reduce (+bias)
    const int Kpm = win * 512;
    const int S = Kpm / 2048;
    const int Mc = TOK_TOTAL / win;
    const int mtp = (Mc + 255) >> 8;
    gemm256_pm<0><<<mtp * 2 * S, 512, 131072, stream>>>(aob, Kpm, wtpc + wpoff[i], Kpm,
                                                        pbuf, Mc, 2048, 512);
    reduce_k<<<Mc * 2, 256, 0, stream>>>(pbuf, out, pb[i], cbadd + i*512,
                                         Mc, S, L_SEQ / win, roffv[i]);
  }
}

// Round 7
// 915.765 us; speedup vs baseline: 1.0183x; 1.0183x over previous
//
#include <hip/hip_runtime.h>
#include <hip/hip_bf16.h>
#include <stdint.h>

#define TOK_TOTAL 102400   // 32*3200
#define L_SEQ 3200

typedef __attribute__((ext_vector_type(8))) short bf16x8;
typedef __attribute__((ext_vector_type(4))) short s16x4;
typedef __attribute__((ext_vector_type(2))) short s16x2;
typedef __attribute__((ext_vector_type(4))) float f32x4;

__device__ __forceinline__ short f2bf(float f){
  union { __hip_bfloat16 h; short s; } u;
  u.h = __float2bfloat16(f);
  return u.s;
}

__device__ __forceinline__ f32x4 mfma16(bf16x8 a, bf16x8 b, f32x4 c){
  return __builtin_amdgcn_mfma_f32_16x16x32_bf16(a, b, c, 0, 0, 0);
}

__device__ __forceinline__ void glds16(const short* g, short* l){
  __builtin_amdgcn_global_load_lds((const __attribute__((address_space(1))) unsigned*)g,
                                   (__attribute__((address_space(3))) unsigned*)l, 16, 0, 0);
}

// bijective XCD-chunk swizzle (m204)
__device__ __forceinline__ int xswz(int bid, int nwg){
  int q = nwg >> 3, r = nwg & 7, x = bid & 7, k = bid >> 3;
  return (x < r ? x * (q + 1) : r * (q + 1) + (x - r) * q) + k;
}

// ---------------- embT: bf16 embedding table with sqrt(512) folded (100x512) ----------------
__global__ void embcast_k(const float* __restrict__ emb, short* __restrict__ embT){
  int gid = blockIdx.x * 256 + threadIdx.x;     // 6400 threads, 8 elems each
  const float SC = 22.627416997969522f;
  const float4 f0 = ((const float4*)emb)[gid*2];
  const float4 f1 = ((const float4*)emb)[gid*2+1];
  bf16x8 o;
  o[0]=f2bf(f0.x*SC); o[1]=f2bf(f0.y*SC); o[2]=f2bf(f0.z*SC); o[3]=f2bf(f0.w*SC);
  o[4]=f2bf(f1.x*SC); o[5]=f2bf(f1.y*SC); o[6]=f2bf(f1.z*SC); o[7]=f2bf(f1.w*SC);
  *(bf16x8*)(embT + gid*8) = o;
}

// ---------------- transpose f32 [R,C] -> bf16 [C,R], packed s16x4 stores ----------------
__global__ void transpose_cast(const float* __restrict__ in, short* __restrict__ out,
                               int R, int C){
  __shared__ float tile[32][33];
  int c0 = blockIdx.x * 32, r0 = blockIdx.y * 32;
  int tx = threadIdx.x, ty = threadIdx.y;       // 32x8
  #pragma unroll
  for (int i = 0; i < 32; i += 8)
    tile[ty + i][tx] = in[(size_t)(r0 + ty + i) * C + c0 + tx];
  __syncthreads();
  // write phase: flat remap, each thread emits one s16x4 (4 consecutive r of one c)
  const int t = ty * 32 + tx;                   // 0..255
  const int c = t >> 3;                         // 0..31
  const int r4 = (t & 7) << 2;                  // 0,4,...,28
  s16x4 o4;
  #pragma unroll
  for (int j = 0; j < 4; ++j) o4[j] = f2bf(tile[r4 + j][c]);
  *(s16x4*)(out + (size_t)(c0 + c) * R + r0 + r4) = o4;
}

// ---------------- plain cast f32 -> bf16 (8 elems/thread) ----------------
__global__ void cast_k(const float* __restrict__ in, short* __restrict__ out){
  int gid = blockIdx.x * 256 + threadIdx.x;
  const float4 f0 = ((const float4*)in)[gid*2];
  const float4 f1 = ((const float4*)in)[gid*2+1];
  bf16x8 o;
  o[0]=f2bf(f0.x); o[1]=f2bf(f0.y); o[2]=f2bf(f0.z); o[3]=f2bf(f0.w);
  o[4]=f2bf(f1.x); o[5]=f2bf(f1.y); o[6]=f2bf(f1.z); o[7]=f2bf(f1.w);
  *(bf16x8*)(out + gid*8) = o;
}

// ---------------- bias fold: cbadd[j] = sum_r bo[r&511] * wtpT[j][r] ----------------
__global__ void bias_fold_k(const short* __restrict__ wtpT, const float* __restrict__ bo,
                            float* __restrict__ cbadd, int Kpm){
  int j = blockIdx.x;
  const short* row = wtpT + (size_t)j * Kpm;
  float s = 0.f;
  for (int r = threadIdx.x; r < Kpm; r += 256){
    union { unsigned u; float f; } c; c.u = ((unsigned)(unsigned short)row[r]) << 16;
    s += c.f * bo[r & 511];
  }
  s += __shfl_xor(s, 1);  s += __shfl_xor(s, 2);  s += __shfl_xor(s, 4);
  s += __shfl_xor(s, 8);  s += __shfl_xor(s, 16); s += __shfl_xor(s, 32);
  __shared__ float red[4];
  if ((threadIdx.x & 63) == 0) red[threadIdx.x >> 6] = s;
  __syncthreads();
  if (threadIdx.x == 0) cbadd[j] = red[0] + red[1] + red[2] + red[3];
}

// ---------------- split-K reduce + bias, float4 (writes each out element exactly once) --------
__global__ void reduce_k(const float* __restrict__ part, float* __restrict__ out,
                         const float* __restrict__ pb, const float* __restrict__ cb,
                         int Mc, int S, int rpb, int roff){
  int gid = blockIdx.x * 256 + threadIdx.x;     // Mc*128 threads
  int c4 = (gid & 127) << 2;
  int rr = gid >> 7;
  float4 s = *(const float4*)(pb + c4);
  const float4 cv = *(const float4*)(cb + c4);
  s.x += cv.x; s.y += cv.y; s.z += cv.z; s.w += cv.w;
  const float* p = part + (size_t)rr * 512 + c4;
  const size_t stride = (size_t)Mc * 512;
  for (int k = 0; k < S; ++k){
    const float4 v = *(const float4*)(p + (size_t)k * stride);
    s.x += v.x; s.y += v.y; s.z += v.z; s.w += v.w;
  }
  int ob = rr / rpb;
  int orow = rr - ob * rpb;
  *(float4*)(out + (size_t)(ob * 375 + roff + orow) * 512 + c4) = s;
}

// ---------------- 128^2 GEMM C = A[M,K] @ Bt[N,K]^T, BK=64, swizzled LDS ----------------
// bf16 store + f32 bias, C row-major [M][ldc]  (qkvtab precompute).
__global__ __launch_bounds__(256)
void gemm_bt(const short* __restrict__ A, int lda,
             const short* __restrict__ Bt, int ldb,
             void* __restrict__ Cv, int ldc,
             int M, int N, int K,
             const float* __restrict__ bias,
             int kc)
{
  __shared__ short alds[8192];   // [128][64]
  __shared__ short blds[8192];

  const int t = threadIdx.x;
  const int Mt = (M + 127) >> 7;
  const int Nt = N >> 7;
  int wg = xswz(blockIdx.x, gridDim.x);
  const int bn = wg % Nt; wg /= Nt;
  const int bm = wg % Mt; wg /= Mt;
  const int ksp = wg;
  int kbeg = ksp * kc, kend = kbeg + kc; if (kend > K) kend = K;

  const int srow = t >> 3;                      // 0..31
  const int scol = (t & 7) << 3;
  const int scolz = scol ^ ((srow & 7) << 3);   // swizzled SOURCE column (m173)
  const short* ga[4]; const short* gb[4];
  #pragma unroll
  for (int p = 0; p < 4; ++p){
    int arow = bm*128 + srow + p*32; if (arow >= M) arow = M - 1;
    ga[p] = A + (size_t)arow * lda + kbeg + scolz;
    gb[p] = Bt + (size_t)(bn*128 + srow + p*32) * ldb + kbeg + scolz;
  }
  short* la = alds + t * 8;
  short* lb = blds + t * 8;

  const int wave = t >> 6;
  const int lane = t & 63;
  const int wm = (wave >> 1) << 6;
  const int wn = (wave & 1) << 6;
  const int fr = lane & 15;
  const int fk = (lane >> 4) << 3;
  const int fx = (fr & 7) << 3;

  f32x4 acc[4][4] = {};

  for (int kt = kbeg; kt < kend; kt += 64) {
    #pragma unroll
    for (int p = 0; p < 4; ++p){
      glds16(ga[p], la + p*2048);
      glds16(gb[p], lb + p*2048);
      ga[p] += 64; gb[p] += 64;
    }
    __syncthreads();
    bf16x8 af[2][4], bfr[2][4];
    #pragma unroll
    for (int ks = 0; ks < 2; ++ks){
      const int kcz = (ks*32 + fk) ^ fx;
      #pragma unroll
      for (int m = 0; m < 4; ++m) af[ks][m] = *(const bf16x8*)(alds + (wm + m*16 + fr)*64 + kcz);
      #pragma unroll
      for (int n = 0; n < 4; ++n) bfr[ks][n] = *(const bf16x8*)(blds + (wn + n*16 + fr)*64 + kcz);
    }
    #pragma unroll
    for (int ks = 0; ks < 2; ++ks)
      #pragma unroll
      for (int m = 0; m < 4; ++m)
        #pragma unroll
        for (int n = 0; n < 4; ++n)
          acc[m][n] = mfma16(af[ks][m], bfr[ks][n], acc[m][n]);
    __syncthreads();
  }

  const int rb = (lane >> 4) << 2;
  short* C = (short*)Cv;
  #pragma unroll
  for (int m = 0; m < 4; ++m){
    const int row0 = bm*128 + wm + m*16 + rb;
    #pragma unroll
    for (int n = 0; n < 4; ++n){
      const int col = bn*128 + wn + n*16 + fr;
      const float bv = bias[col];
      #pragma unroll
      for (int r = 0; r < 4; ++r){
        const int rr = row0 + r;
        if (rr < M) C[(size_t)rr * ldc + col] = f2bf(acc[m][n][r] + bv);
      }
    }
  }
}

// ---------------- 256^2 deep-pipelined GEMM (T2+T3+T4+T5) ----------------
// MODE 0 (split-K patch-merge): Cpart[ksp][M][512] = A[M,lda] @ Bt[512,ldb]^T over
//        K-slice [ksp*kc, +kc), f32 partial store.
// MODE 1 (batched compose): per batch p (=ksp), C[j][p*512+c] = sum_m A[j][p*512+m]
//        * Bt[c][m] — A K-slice offset p*512, B K-offset 0, bf16 store, ldc stride.
// 512 thr = 8 waves (2Mx4N), per-wave C 128x64, BK=64, LDS 128 KiB = 2 dbuf x (A|B).
// 4 phases per K-tile; counted vmcnt (6)/(8), never drained in main loop.
template<int MODE>
__global__ __launch_bounds__(512, 2)
void gemm256_pm(const short* __restrict__ A, int lda,
                const short* __restrict__ Bt, int ldb,
                void* __restrict__ Cv, int M, int kc, int ldc)
{
  extern __shared__ short lds_s[];
  const int tid = threadIdx.x;
  const int Mt = (M + 255) >> 8;
  int wg = xswz(blockIdx.x, gridDim.x);
  const int bn = wg & 1; wg >>= 1;
  const int bm = wg % Mt;
  const int ksp = wg / Mt;
  const int kbeg = ksp * kc;
  const int kbegB = (MODE == 1) ? 0 : kbeg;     // compose: B K-range is always [0,512)

  const int wave = tid >> 6, lane = tid & 63;
  const int wm = wave >> 2, wn = wave & 3;   // 2M x 4N waves
  const int fr = lane & 15, kq = lane >> 4;
  const int fx = fr & 7;
  const int sx0 = (kq ^ fx) << 3;            // swizzled 16B slot, ks=0 (shorts)
  const int sx1 = ((4 + kq) ^ fx) << 3;      // ks=1
  const int aoff = (wm * 64 + fr) << 6;      // phys A row * 64 shorts
  const int boff = (wn * 32 + fr) << 6;

  const int sr = tid >> 3;
  const int kg = ((tid & 7) ^ (sr & 7)) << 3;
  const short* srcA[2][2]; const short* srcB[2][2];
  #pragma unroll
  for (int h = 0; h < 2; ++h)
    #pragma unroll
    for (int u = 0; u < 2; ++u){
      int r = bm * 256 + u * 128 + h * 64 + sr; if (r >= M) r = M - 1;
      srcA[h][u] = A + (size_t)r * lda + kbeg + kg;
      const int br = (u * 2 + (sr >> 5)) * 64 + h * 32 + (sr & 31);
      srcB[h][u] = Bt + (size_t)(bn * 256 + br) * ldb + kbegB + kg;
    }

#define STG_A(dst, h, ko) do { \
    glds16(srcA[h][0] + (ko), (dst) + (h)*8192 + tid*8); \
    glds16(srcA[h][1] + (ko), (dst) + (h)*8192 + 4096 + tid*8); } while(0)
#define STG_B(dst, h, ko) do { \
    glds16(srcB[h][0] + (ko), (dst) + 16384 + (h)*8192 + tid*8); \
    glds16(srcB[h][1] + (ko), (dst) + 16384 + (h)*8192 + 4096 + tid*8); } while(0)

  short* Lc = lds_s;
  short* Ln = lds_s + 32768;

  f32x4 acc[8][4] = {};
  bf16x8 af[4][2], b0[2][2], b1[2][2];

  STG_A(Lc, 0, 0);  STG_B(Lc, 0, 0);
  STG_A(Lc, 1, 0);  STG_B(Lc, 1, 0);
  STG_A(Ln, 0, 64); STG_B(Ln, 0, 64);
  asm volatile("s_waitcnt vmcnt(8)" ::: "memory");
  __builtin_amdgcn_s_barrier();

  const int T = kc >> 6;
  for (int t = 0; t < T; ++t){
    const int k1 = ((t + 1 < T) ? t + 1 : T - 1) << 6;
    const int k2 = ((t + 2 < T) ? t + 2 : T - 1) << 6;
    // ---- phase 0
    #pragma unroll
    for (int m = 0; m < 4; ++m){
      af[m][0] = *(const bf16x8*)(Lc + aoff + m*1024 + sx0);
      af[m][1] = *(const bf16x8*)(Lc + aoff + m*1024 + sx1);
    }
    #pragma unroll
    for (int n = 0; n < 2; ++n){
      b0[n][0] = *(const bf16x8*)(Lc + 16384 + boff + n*1024 + sx0);
      b0[n][1] = *(const bf16x8*)(Lc + 16384 + boff + n*1024 + sx1);
    }
    STG_A(Ln, 1, k1);
    __builtin_amdgcn_s_barrier();
    asm volatile("s_waitcnt lgkmcnt(0)");
    __builtin_amdgcn_s_setprio(1);
    #pragma unroll
    for (int m = 0; m < 4; ++m)
      #pragma unroll
      for (int n = 0; n < 2; ++n){
        acc[m][n] = mfma16(af[m][0], b0[n][0], acc[m][n]);
        acc[m][n] = mfma16(af[m][1], b0[n][1], acc[m][n]);
      }
    __builtin_amdgcn_s_setprio(0);
    asm volatile("s_waitcnt vmcnt(6)" ::: "memory");
    __builtin_amdgcn_s_barrier();
    // ---- phase 1
    #pragma unroll
    for (int n = 0; n < 2; ++n){
      b1[n][0] = *(const bf16x8*)(Lc + 24576 + boff + n*1024 + sx0);
      b1[n][1] = *(const bf16x8*)(Lc + 24576 + boff + n*1024 + sx1);
    }
    STG_B(Ln, 1, k1);
    __builtin_amdgcn_s_barrier();
    asm volatile("s_waitcnt lgkmcnt(0)");
    __builtin_amdgcn_s_setprio(1);
    #pragma unroll
    for (int m = 0; m < 4; ++m)
      #pragma unroll
      for (int n = 0; n < 2; ++n){
        acc[m][2+n] = mfma16(af[m][0], b1[n][0], acc[m][2+n]);
        acc[m][2+n] = mfma16(af[m][1], b1[n][1], acc[m][2+n]);
      }
    __builtin_amdgcn_s_setprio(0);
    __builtin_amdgcn_s_barrier();
    // ---- phase 2
    #pragma unroll
    for (int m = 0; m < 4; ++m){
      af[m][0] = *(const bf16x8*)(Lc + 8192 + aoff + m*1024 + sx0);
      af[m][1] = *(const bf16x8*)(Lc + 8192 + aoff + m*1024 + sx1);
    }
    STG_A(Lc, 0, k2);
    __builtin_amdgcn_s_barrier();
    asm volatile("s_waitcnt lgkmcnt(0)");
    __builtin_amdgcn_s_setprio(1);
    #pragma unroll
    for (int m = 0; m < 4; ++m)
      #pragma unroll
      for (int n = 0; n < 2; ++n){
        acc[4+m][n] = mfma16(af[m][0], b0[n][0], acc[4+m][n]);
        acc[4+m][n] = mfma16(af[m][1], b0[n][1], acc[4+m][n]);
      }
    __builtin_amdgcn_s_setprio(0);
    __builtin_amdgcn_s_barrier();
    // ---- phase 3
    STG_B(Lc, 0, k2);
    __builtin_amdgcn_s_barrier();
    __builtin_amdgcn_s_setprio(1);
    #pragma unroll
    for (int m = 0; m < 4; ++m)
      #pragma unroll
      for (int n = 0; n < 2; ++n){
        acc[4+m][2+n] = mfma16(af[m][0], b1[n][0], acc[4+m][2+n]);
        acc[4+m][2+n] = mfma16(af[m][1], b1[n][1], acc[4+m][2+n]);
      }
    __builtin_amdgcn_s_setprio(0);
    asm volatile("s_waitcnt vmcnt(8)" ::: "memory");
    __builtin_amdgcn_s_barrier();
    short* tp = Lc; Lc = Ln; Ln = tp;
  }
#undef STG_A
#undef STG_B

  const int rb4 = kq << 2;
  if (MODE == 0){
    float* Cp = (float*)Cv + (size_t)ksp * M * 512;
    #pragma unroll
    for (int mh = 0; mh < 2; ++mh)
      #pragma unroll
      for (int m = 0; m < 4; ++m){
        const int row0 = bm*256 + wm*128 + mh*64 + m*16 + rb4;
        #pragma unroll
        for (int r = 0; r < 4; ++r){
          const int rr = row0 + r;
          if (rr < M){
            float* Crow = Cp + (size_t)rr * 512 + bn*256 + wn*64 + fr;
            #pragma unroll
            for (int nh = 0; nh < 2; ++nh)
              #pragma unroll
              for (int n = 0; n < 2; ++n)
                Crow[nh*32 + n*16] = acc[mh*4+m][nh*2+n][r];
          }
        }
      }
  } else {
    // compose: bf16 store to C[j][kbeg + c], ldc = Kpm
    short* Cs = (short*)Cv;
    #pragma unroll
    for (int mh = 0; mh < 2; ++mh)
      #pragma unroll
      for (int m = 0; m < 4; ++m){
        const int row0 = bm*256 + wm*128 + mh*64 + m*16 + rb4;
        #pragma unroll
        for (int r = 0; r < 4; ++r){
          const int rr = row0 + r;
          if (rr < M){
            short* Crow = Cs + (size_t)rr * ldc + kbeg + bn*256 + wn*64 + fr;
            #pragma unroll
            for (int nh = 0; nh < 2; ++nh)
              #pragma unroll
              for (int n = 0; n < 2; ++n)
                Crow[nh*32 + n*16] = f2bf(acc[mh*4+m][nh*2+n][r]);
          }
        }
      }
  }
}

// ---------------- table-gather windowed MHA: one wave per (window, head) ----------------
// tab: [100][1536] bf16 per window (Q|K|V rows per vocab value, bias folded).
// v10 = v9 + conflict-spreading swizzle key: key(x) = ((x + (x>>3)) & KMASK) << 3.
//      v9's key (x & KMASK)<<3 ignored the row-group bits, so the 8 lanes of a
//      staging store sharing (sr, j) (differing only in dgrp = d>>3) got identical
//      keys -> same bank -> 8-way (win64) / 4-way (win128) conflicts (7.37M counter).
//      New key folds d>>3 in; applied consistently at all write AND read sites
//      (per-row bijection on 8-short granules; alignment preserved).
template<int WIN>
__global__ __launch_bounds__(256)
void attn_g(const int* __restrict__ spec, const short* __restrict__ tab,
            short* __restrict__ ao){
  constexpr int WINP = (WIN < 32) ? 32 : WIN;     // padded k-dim
  constexpr int KMASK = WINP / 8 - 1;             // in-row swizzle key clamp
  constexpr int NT = WIN / 16;
  extern __shared__ short smem[];                 // per wave: Vt[64][WINP] + P[16][WINP]
  const int lane = threadIdx.x & 63;
  const int w = threadIdx.x >> 6;
  const int wh = blockIdx.x * 4 + w;
  const int wid = wh >> 3, h = wh & 7;
  const size_t tb = (size_t)wid * WIN;
  short* vt = smem + w * 80 * WINP;
  short* pl = vt + 64 * WINP;

  const int fr = lane & 15;
  const int fk = (lane >> 4) << 3;
  const int kq = lane >> 4;
  const int rb = kq << 2;

  // ---- V^T staging: (KRUN k x 8 d) cells, packed LDS writes.
  // element (d,k) -> vt[d*WINP + (k ^ key(d))], key(x) = ((x + (x>>3)) & KMASK) << 3
  {
    constexpr int KRUN = (WIN >= 32) ? 4 : 2;
    constexpr int ITER = (WIN / KRUN) * 8 / 64;   // 1,1,2,4
    const int dgrp = lane & 7;
    #pragma unroll
    for (int it = 0; it < ITER; ++it){
      const int kb = ((lane >> 3) + it * 8) * KRUN;
      bf16x8 vv[KRUN];
      #pragma unroll
      for (int kk = 0; kk < KRUN; ++kk)
        vv[kk] = *(const bf16x8*)(tab + (size_t)spec[tb + kb + kk] * 1536 + 1024 + h * 64 + dgrp * 8);
      #pragma unroll
      for (int j = 0; j < 8; ++j){
        const int d = dgrp * 8 + j;
        const int key = ((d + (d >> 3)) & KMASK) << 3;
        short* dst = vt + d * WINP + (kb ^ key);
        if constexpr (KRUN == 4){
          s16x4 wv; wv[0]=vv[0][j]; wv[1]=vv[1][j]; wv[2]=vv[2][j]; wv[3]=vv[3][j];
          *(s16x4*)dst = wv;
        } else {
          s16x2 wv; wv[0]=vv[0][j]; wv[1]=vv[1][j];
          *(s16x2*)dst = wv;
        }
      }
    }
  }
  if constexpr (WIN == 16){
    // zero-fill V^T pad (logical k=16..31 of every d-row): uninitialized LDS may
    // hold NaN bf16 patterns and 0*NaN = NaN. lane == d (64 lanes, 64 rows).
    const int d = lane;
    const int key = ((d + (d >> 3)) & KMASK) << 3;
    short* vrow_ = vt + d * WINP;
    const s16x4 z = {0, 0, 0, 0};
    #pragma unroll
    for (int kk = 16; kk < 32; kk += 4)
      *(s16x4*)(vrow_ + (kk ^ key)) = z;
  }

  // ---- hoisted K row pointers; K fragments in regs for NT<=4
  const short* kp8[NT];
  #pragma unroll
  for (int nt = 0; nt < NT; ++nt)
    kp8[nt] = tab + (size_t)spec[tb + nt*16 + fr] * 1536 + 512 + h*64 + fk;

  bf16x8 bkh[(NT <= 4) ? NT : 1][2];
  if constexpr (NT <= 4){
    #pragma unroll
    for (int nt = 0; nt < NT; ++nt){
      bkh[nt][0] = *(const bf16x8*)(kp8[nt]);
      bkh[nt][1] = *(const bf16x8*)(kp8[nt] + 32);
    }
  }

  const int rxq = ((fr + (fr >> 3)) & KMASK) << 3; // P-row swizzle key (row = q = fr)
  short* plq = pl + fr * WINP;

  for (int qt = 0; qt < NT; ++qt){
    // Q row token == K row token for the same (tile, fr): reuse pointer, offset -512
    const short* qrow = kp8[qt] - 512;
    bf16x8 aq0 = *(const bf16x8*)(qrow);
    bf16x8 aq1 = *(const bf16x8*)(qrow + 32);
    float s[NT][4];
    #pragma unroll
    for (int nt = 0; nt < NT; ++nt){
      bf16x8 k0, k1;
      if constexpr (NT <= 4){ k0 = bkh[nt][0]; k1 = bkh[nt][1]; }
      else { k0 = *(const bf16x8*)(kp8[nt]); k1 = *(const bf16x8*)(kp8[nt] + 32); }
      f32x4 c = {0.f, 0.f, 0.f, 0.f};
      c = mfma16(k0, aq0, c);                     // swapped: C[k_local][q = lane&15]
      c = mfma16(k1, aq1, c);
      #pragma unroll
      for (int r = 0; r < 4; ++r) s[nt][r] = c[r] * 0.125f;
    }
    // in-lane softmax for q = fr: tree max/sum over 4*NT values + 2 shfls each
    float mm[NT];
    #pragma unroll
    for (int nt = 0; nt < NT; ++nt)
      mm[nt] = fmaxf(fmaxf(s[nt][0], s[nt][1]), fmaxf(s[nt][2], s[nt][3]));
    #pragma unroll
    for (int st = NT >> 1; st >= 1; st >>= 1)
      #pragma unroll
      for (int i = 0; i < st; ++i) mm[i] = fmaxf(mm[i], mm[i + st]);
    float m = mm[0];
    m = fmaxf(m, __shfl_xor(m, 16));
    m = fmaxf(m, __shfl_xor(m, 32));
    float ss[NT];
    #pragma unroll
    for (int nt = 0; nt < NT; ++nt){
      #pragma unroll
      for (int r = 0; r < 4; ++r) s[nt][r] = __expf(s[nt][r] - m);
      ss[nt] = (s[nt][0] + s[nt][1]) + (s[nt][2] + s[nt][3]);
    }
    #pragma unroll
    for (int st = NT >> 1; st >= 1; st >>= 1)
      #pragma unroll
      for (int i = 0; i < st; ++i) ss[i] += ss[i + st];
    float sum = ss[0];
    sum += __shfl_xor(sum, 16);
    sum += __shfl_xor(sum, 32);
    const float inv = 1.f / sum;
    // packed P store: lane owns k = nt*16 + rb + 0..3 of row q=fr (contiguous, b64)
    #pragma unroll
    for (int nt = 0; nt < NT; ++nt){
      s16x4 pw;
      pw[0] = f2bf(s[nt][0] * inv); pw[1] = f2bf(s[nt][1] * inv);
      pw[2] = f2bf(s[nt][2] * inv); pw[3] = f2bf(s[nt][3] * inv);
      *(s16x4*)(plq + ((nt*16 + rb) ^ rxq)) = pw;
    }
    if (WIN == 16){
      s16x4 pz = {0, 0, 0, 0};
      *(s16x4*)(plq + ((16 + rb) ^ rxq)) = pz;
    }
    // PV with swapped operands: lane (fr,kq) gets O[q=fr][d=d0*16+kq*4+r] -> packed store
    short* aorow = ao + (tb + qt*16 + fr) * 512 + h*64 + rb;
    if constexpr (WINP / 32 <= 2){
      // hoist P fragments once (d0-invariant); cheap in VGPRs for WIN<=64
      bf16x8 aph[WINP / 32];
      #pragma unroll
      for (int ks = 0; ks < WINP/32; ++ks)
        aph[ks] = *(const bf16x8*)(pl + fr * WINP + ((ks*32 + fk) ^ rxq));
      #pragma unroll
      for (int d0 = 0; d0 < 4; ++d0){
        const int vrow = d0*16 + fr;
        const int vx = ((vrow + (vrow >> 3)) & KMASK) << 3;
        f32x4 o = {0.f, 0.f, 0.f, 0.f};
        #pragma unroll
        for (int ks = 0; ks < WINP/32; ++ks){
          bf16x8 bv = *(const bf16x8*)(vt + vrow * WINP + ((ks*32 + fk) ^ vx));
          o = mfma16(bv, aph[ks], o);
        }
        s16x4 ov;
        ov[0]=f2bf(o[0]); ov[1]=f2bf(o[1]); ov[2]=f2bf(o[2]); ov[3]=f2bf(o[3]);
        *(s16x4*)(aorow + d0*16) = ov;
      }
    } else {
      // WIN=128: reload ap per d0 (keeps VGPR below the 128 cliff)
      #pragma unroll
      for (int d0 = 0; d0 < 4; ++d0){
        const int vrow = d0*16 + fr;
        const int vx = ((vrow + (vrow >> 3)) & KMASK) << 3;
        f32x4 o = {0.f, 0.f, 0.f, 0.f};
        #pragma unroll
        for (int ks = 0; ks < WINP/32; ++ks){
          bf16x8 ap = *(const bf16x8*)(pl + fr * WINP + ((ks*32 + fk) ^ rxq));
          bf16x8 bv = *(const bf16x8*)(vt + vrow * WINP + ((ks*32 + fk) ^ vx));
          o = mfma16(bv, ap, o);
        }
        s16x4 ov;
        ov[0]=f2bf(o[0]); ov[1]=f2bf(o[1]); ov[2]=f2bf(o[2]); ov[3]=f2bf(o[3]);
        *(s16x4*)(aorow + d0*16) = ov;
      }
    }
    // no __syncthreads: smem slices are wave-private; in-wave lgkmcnt ordering suffices
  }
}

// ---------------- host ----------------
extern "C" void kernel_launch(void* const* d_in, const int* in_sizes, int n_in,
                              void* d_out, int out_size, void* d_ws, size_t ws_size,
                              hipStream_t stream){
  const int*   spec   = (const int*)d_in[0];
  const float* emb    = (const float*)d_in[1];
  const float* attn_w = (const float*)d_in[2];
  const float* attn_b = (const float*)d_in[3];
  const float* pw[4]  = {(const float*)d_in[4], (const float*)d_in[6],
                         (const float*)d_in[8], (const float*)d_in[10]};
  const float* pb[4]  = {(const float*)d_in[5], (const float*)d_in[7],
                         (const float*)d_in[9], (const float*)d_in[11]};
  float* out = (float*)d_out;

  // fixed buffers (~135.5 MB): wtq | wcast | wtpc | cbadd | embT | qkvtab
  short* wtq    = (short*)d_ws;             // [4][1536][512] transposed q,k,v
  short* wcast  = wtq + 3145728;            // [4][512][512] Wo cast
  short* wtpc   = wcast + 1048576;          // composed pm weights
  float* cbadd  = (float*)(wtpc + 62914560);// [4][512]
  short* embT   = (short*)(cbadd + 2048);   // [100][512]
  short* qkvtab = embT + 51200;             // [4][100][1536]
  short* dyn    = qkvtab + 614400;

  short* aob  = dyn;                        // [102400][512] bf16 (105 MB)
  float* pbuf = (float*)(aob + (size_t)TOK_TOTAL * 512); // split-K partials (52 MB)
  short* scratch = dyn;                     // pw^T staging (prep only, aliases aob)

  static const int winv[4]  = {16, 32, 64, 128};
  static const int wpoff[4] = {0, 16*262144, 48*262144, 112*262144};
  static const int roffv[4] = {0, 200, 300, 350};

  (void)hipFuncSetAttribute(reinterpret_cast<const void*>(gemm256_pm<0>),
                            hipFuncAttributeMaxDynamicSharedMemorySize, 131072);
  (void)hipFuncSetAttribute(reinterpret_cast<const void*>(gemm256_pm<1>),
                            hipFuncAttributeMaxDynamicSharedMemorySize, 131072);

  embcast_k<<<25, 256, 0, stream>>>(emb, embT);
  dim3 tb(32, 8);
  for (int i = 0; i < 4; ++i){
    const int win = winv[i];
    const int Kpm = win * 512;
    for (int j = 0; j < 3; ++j)
      transpose_cast<<<dim3(16,16), tb, 0, stream>>>(attn_w + (size_t)(i*4+j)*262144,
                                                     wtq + (size_t)(i*3+j)*262144, 512, 512);
    cast_k<<<128, 256, 0, stream>>>(attn_w + (size_t)(i*4+3)*262144, wcast + (size_t)i*262144);
    transpose_cast<<<dim3(16, win*16), tb, 0, stream>>>(pw[i], scratch, Kpm, 512);
    bias_fold_k<<<512, 256, 0, stream>>>(scratch, attn_b + i*2048 + 1536, cbadd + i*512, Kpm);
    // compose wtpc[j][p*512+c] = sum_m scratch[j][p*512+m] * wcast[c][m]  (deep-pipelined)
    gemm256_pm<1><<<win*4, 512, 131072, stream>>>(scratch, Kpm, wcast + (size_t)i*262144, 512,
                                                  wtpc + wpoff[i], 512, 512, Kpm);
    // qkvtab_i[100][1536] = embT @ wtq_i^T + bias(q|k|v)
    gemm_bt<<<12, 256, 0, stream>>>(embT, 512, wtq + (size_t)i*3*262144, 512,
                                    qkvtab + (size_t)i*153600, 1536,
                                    100, 1536, 512, attn_b + i*2048, 512);
  }

  for (int i = 0; i < 4; ++i){
    const int win = winv[i];
    const short* tabw = qkvtab + (size_t)i * 153600;
    const int blocks = (TOK_TOTAL / win) * 8 / 4;
    const int winp = (win < 32) ? 32 : win;
    const size_t shmem = (size_t)4 * 80 * winp * 2;
    if (win == 16)       attn_g<16 ><<<blocks, 256, shmem, stream>>>(spec, tabw, aob);
    else if (win == 32)  attn_g<32 ><<<blocks, 256, shmem, stream>>>(spec, tabw, aob);
    else if (win == 64)  attn_g<64 ><<<blocks, 256, shmem, stream>>>(spec, tabw, aob);
    else                 attn_g<128><<<blocks, 256, shmem, stream>>>(spec, tabw, aob);
    // patch-merge split-K (kc=2048) via 256^2 pipelined GEMM, then deterministic reduce (+bias)
    const int Kpm = win * 512;
    const int S = Kpm / 2048;
    const int Mc = TOK_TOTAL / win;
    const int mtp = (Mc + 255) >> 8;
    gemm256_pm<0><<<mtp * 2 * S, 512, 131072, stream>>>(aob, Kpm, wtpc + wpoff[i], Kpm,
                                                        pbuf, Mc, 2048, 512);
    reduce_k<<<Mc / 2, 256, 0, stream>>>(pbuf, out, pb[i], cbadd + i*512,
                                         Mc, S, L_SEQ / win, roffv[i]);
  }
}

// Round 8
// 915.452 us; speedup vs baseline: 1.0187x; 1.0003x over previous
//
#include <hip/hip_runtime.h>
#include <hip/hip_bf16.h>
#include <stdint.h>

#define TOK_TOTAL 102400   // 32*3200
#define L_SEQ 3200

typedef __attribute__((ext_vector_type(8))) short bf16x8;
typedef __attribute__((ext_vector_type(4))) short s16x4;
typedef __attribute__((ext_vector_type(2))) short s16x2;
typedef __attribute__((ext_vector_type(4))) float f32x4;

__device__ __forceinline__ short f2bf(float f){
  union { __hip_bfloat16 h; short s; } u;
  u.h = __float2bfloat16(f);
  return u.s;
}

__device__ __forceinline__ f32x4 mfma16(bf16x8 a, bf16x8 b, f32x4 c){
  return __builtin_amdgcn_mfma_f32_16x16x32_bf16(a, b, c, 0, 0, 0);
}

__device__ __forceinline__ void glds16(const short* g, short* l){
  __builtin_amdgcn_global_load_lds((const __attribute__((address_space(1))) unsigned*)g,
                                   (__attribute__((address_space(3))) unsigned*)l, 16, 0, 0);
}

// bijective XCD-chunk swizzle (m204)
__device__ __forceinline__ int xswz(int bid, int nwg){
  int q = nwg >> 3, r = nwg & 7, x = bid & 7, k = bid >> 3;
  return (x < r ? x * (q + 1) : r * (q + 1) + (x - r) * q) + k;
}

// ---------------- embT: bf16 embedding table with sqrt(512) folded (100x512) ----------------
__global__ void embcast_k(const float* __restrict__ emb, short* __restrict__ embT){
  int gid = blockIdx.x * 256 + threadIdx.x;     // 6400 threads, 8 elems each
  const float SC = 22.627416997969522f;
  const float4 f0 = ((const float4*)emb)[gid*2];
  const float4 f1 = ((const float4*)emb)[gid*2+1];
  bf16x8 o;
  o[0]=f2bf(f0.x*SC); o[1]=f2bf(f0.y*SC); o[2]=f2bf(f0.z*SC); o[3]=f2bf(f0.w*SC);
  o[4]=f2bf(f1.x*SC); o[5]=f2bf(f1.y*SC); o[6]=f2bf(f1.z*SC); o[7]=f2bf(f1.w*SC);
  *(bf16x8*)(embT + gid*8) = o;
}

// ---------------- transpose f32 [R,C] -> bf16 [C,R], packed s16x4 stores ----------------
__global__ void transpose_cast(const float* __restrict__ in, short* __restrict__ out,
                               int R, int C){
  __shared__ float tile[32][33];
  int c0 = blockIdx.x * 32, r0 = blockIdx.y * 32;
  int tx = threadIdx.x, ty = threadIdx.y;       // 32x8
  #pragma unroll
  for (int i = 0; i < 32; i += 8)
    tile[ty + i][tx] = in[(size_t)(r0 + ty + i) * C + c0 + tx];
  __syncthreads();
  // write phase: flat remap, each thread emits one s16x4 (4 consecutive r of one c)
  const int t = ty * 32 + tx;                   // 0..255
  const int c = t >> 3;                         // 0..31
  const int r4 = (t & 7) << 2;                  // 0,4,...,28
  s16x4 o4;
  #pragma unroll
  for (int j = 0; j < 4; ++j) o4[j] = f2bf(tile[r4 + j][c]);
  *(s16x4*)(out + (size_t)(c0 + c) * R + r0 + r4) = o4;
}

// ---------------- plain cast f32 -> bf16 (8 elems/thread) ----------------
__global__ void cast_k(const float* __restrict__ in, short* __restrict__ out){
  int gid = blockIdx.x * 256 + threadIdx.x;
  const float4 f0 = ((const float4*)in)[gid*2];
  const float4 f1 = ((const float4*)in)[gid*2+1];
  bf16x8 o;
  o[0]=f2bf(f0.x); o[1]=f2bf(f0.y); o[2]=f2bf(f0.z); o[3]=f2bf(f0.w);
  o[4]=f2bf(f1.x); o[5]=f2bf(f1.y); o[6]=f2bf(f1.z); o[7]=f2bf(f1.w);
  *(bf16x8*)(out + gid*8) = o;
}

// ---------------- bias fold: cbadd[j] = sum_r bo[r&511] * wtpT[j][r] ----------------
__global__ void bias_fold_k(const short* __restrict__ wtpT, const float* __restrict__ bo,
                            float* __restrict__ cbadd, int Kpm){
  int j = blockIdx.x;
  const short* row = wtpT + (size_t)j * Kpm;
  float s = 0.f;
  for (int r = threadIdx.x; r < Kpm; r += 256){
    union { unsigned u; float f; } c; c.u = ((unsigned)(unsigned short)row[r]) << 16;
    s += c.f * bo[r & 511];
  }
  s += __shfl_xor(s, 1);  s += __shfl_xor(s, 2);  s += __shfl_xor(s, 4);
  s += __shfl_xor(s, 8);  s += __shfl_xor(s, 16); s += __shfl_xor(s, 32);
  __shared__ float red[4];
  if ((threadIdx.x & 63) == 0) red[threadIdx.x >> 6] = s;
  __syncthreads();
  if (threadIdx.x == 0) cbadd[j] = red[0] + red[1] + red[2] + red[3];
}

// ---------------- split-K reduce + bias, float4 (writes each out element exactly once) --------
__global__ void reduce_k(const float* __restrict__ part, float* __restrict__ out,
                         const float* __restrict__ pb, const float* __restrict__ cb,
                         int Mc, int S, int rpb, int roff){
  int gid = blockIdx.x * 256 + threadIdx.x;     // Mc*128 threads
  int c4 = (gid & 127) << 2;
  int rr = gid >> 7;
  float4 s = *(const float4*)(pb + c4);
  const float4 cv = *(const float4*)(cb + c4);
  s.x += cv.x; s.y += cv.y; s.z += cv.z; s.w += cv.w;
  const float* p = part + (size_t)rr * 512 + c4;
  const size_t stride = (size_t)Mc * 512;
  for (int k = 0; k < S; ++k){
    const float4 v = *(const float4*)(p + (size_t)k * stride);
    s.x += v.x; s.y += v.y; s.z += v.z; s.w += v.w;
  }
  int ob = rr / rpb;
  int orow = rr - ob * rpb;
  *(float4*)(out + (size_t)(ob * 375 + roff + orow) * 512 + c4) = s;
}

// ---------------- 128^2 GEMM C = A[M,K] @ Bt[N,K]^T, BK=64, swizzled LDS ----------------
// bf16 store + f32 bias, C row-major [M][ldc]  (qkvtab precompute).
__global__ __launch_bounds__(256)
void gemm_bt(const short* __restrict__ A, int lda,
             const short* __restrict__ Bt, int ldb,
             void* __restrict__ Cv, int ldc,
             int M, int N, int K,
             const float* __restrict__ bias,
             int kc)
{
  __shared__ short alds[8192];   // [128][64]
  __shared__ short blds[8192];

  const int t = threadIdx.x;
  const int Mt = (M + 127) >> 7;
  const int Nt = N >> 7;
  int wg = xswz(blockIdx.x, gridDim.x);
  const int bn = wg % Nt; wg /= Nt;
  const int bm = wg % Mt; wg /= Mt;
  const int ksp = wg;
  int kbeg = ksp * kc, kend = kbeg + kc; if (kend > K) kend = K;

  const int srow = t >> 3;                      // 0..31
  const int scol = (t & 7) << 3;
  const int scolz = scol ^ ((srow & 7) << 3);   // swizzled SOURCE column (m173)
  const short* ga[4]; const short* gb[4];
  #pragma unroll
  for (int p = 0; p < 4; ++p){
    int arow = bm*128 + srow + p*32; if (arow >= M) arow = M - 1;
    ga[p] = A + (size_t)arow * lda + kbeg + scolz;
    gb[p] = Bt + (size_t)(bn*128 + srow + p*32) * ldb + kbeg + scolz;
  }
  short* la = alds + t * 8;
  short* lb = blds + t * 8;

  const int wave = t >> 6;
  const int lane = t & 63;
  const int wm = (wave >> 1) << 6;
  const int wn = (wave & 1) << 6;
  const int fr = lane & 15;
  const int fk = (lane >> 4) << 3;
  const int fx = (fr & 7) << 3;

  f32x4 acc[4][4] = {};

  for (int kt = kbeg; kt < kend; kt += 64) {
    #pragma unroll
    for (int p = 0; p < 4; ++p){
      glds16(ga[p], la + p*2048);
      glds16(gb[p], lb + p*2048);
      ga[p] += 64; gb[p] += 64;
    }
    __syncthreads();
    bf16x8 af[2][4], bfr[2][4];
    #pragma unroll
    for (int ks = 0; ks < 2; ++ks){
      const int kcz = (ks*32 + fk) ^ fx;
      #pragma unroll
      for (int m = 0; m < 4; ++m) af[ks][m] = *(const bf16x8*)(alds + (wm + m*16 + fr)*64 + kcz);
      #pragma unroll
      for (int n = 0; n < 4; ++n) bfr[ks][n] = *(const bf16x8*)(blds + (wn + n*16 + fr)*64 + kcz);
    }
    #pragma unroll
    for (int ks = 0; ks < 2; ++ks)
      #pragma unroll
      for (int m = 0; m < 4; ++m)
        #pragma unroll
        for (int n = 0; n < 4; ++n)
          acc[m][n] = mfma16(af[ks][m], bfr[ks][n], acc[m][n]);
    __syncthreads();
  }

  const int rb = (lane >> 4) << 2;
  short* C = (short*)Cv;
  #pragma unroll
  for (int m = 0; m < 4; ++m){
    const int row0 = bm*128 + wm + m*16 + rb;
    #pragma unroll
    for (int n = 0; n < 4; ++n){
      const int col = bn*128 + wn + n*16 + fr;
      const float bv = bias[col];
      #pragma unroll
      for (int r = 0; r < 4; ++r){
        const int rr = row0 + r;
        if (rr < M) C[(size_t)rr * ldc + col] = f2bf(acc[m][n][r] + bv);
      }
    }
  }
}

// ---------------- 256^2 deep-pipelined GEMM (T2+T3+T4+T5) ----------------
// MODE 0 (split-K patch-merge): Cpart[ksp][M][512] = A[M,lda] @ Bt[512,ldb]^T over
//        K-slice [ksp*kc, +kc), f32 partial store.
// MODE 1 (batched compose): per batch p (=ksp), C[j][p*512+c] = sum_m A[j][p*512+m]
//        * Bt[c][m] — A K-slice offset p*512, B K-offset 0, bf16 store, ldc stride.
// 512 thr = 8 waves (2Mx4N), per-wave C 128x64, BK=64, LDS 128 KiB = 2 dbuf x (A|B).
// 4 phases per K-tile; counted vmcnt (6)/(8), never drained in main loop.
template<int MODE>
__global__ __launch_bounds__(512, 2)
void gemm256_pm(const short* __restrict__ A, int lda,
                const short* __restrict__ Bt, int ldb,
                void* __restrict__ Cv, int M, int kc, int ldc)
{
  extern __shared__ short lds_s[];
  const int tid = threadIdx.x;
  const int Mt = (M + 255) >> 8;
  int wg = xswz(blockIdx.x, gridDim.x);
  const int bn = wg & 1; wg >>= 1;
  const int bm = wg % Mt;
  const int ksp = wg / Mt;
  const int kbeg = ksp * kc;
  const int kbegB = (MODE == 1) ? 0 : kbeg;     // compose: B K-range is always [0,512)

  const int wave = tid >> 6, lane = tid & 63;
  const int wm = wave >> 2, wn = wave & 3;   // 2M x 4N waves
  const int fr = lane & 15, kq = lane >> 4;
  const int fx = fr & 7;
  const int sx0 = (kq ^ fx) << 3;            // swizzled 16B slot, ks=0 (shorts)
  const int sx1 = ((4 + kq) ^ fx) << 3;      // ks=1
  const int aoff = (wm * 64 + fr) << 6;      // phys A row * 64 shorts
  const int boff = (wn * 32 + fr) << 6;

  const int sr = tid >> 3;
  const int kg = ((tid & 7) ^ (sr & 7)) << 3;
  const short* srcA[2][2]; const short* srcB[2][2];
  #pragma unroll
  for (int h = 0; h < 2; ++h)
    #pragma unroll
    for (int u = 0; u < 2; ++u){
      int r = bm * 256 + u * 128 + h * 64 + sr; if (r >= M) r = M - 1;
      srcA[h][u] = A + (size_t)r * lda + kbeg + kg;
      const int br = (u * 2 + (sr >> 5)) * 64 + h * 32 + (sr & 31);
      srcB[h][u] = Bt + (size_t)(bn * 256 + br) * ldb + kbegB + kg;
    }

#define STG_A(dst, h, ko) do { \
    glds16(srcA[h][0] + (ko), (dst) + (h)*8192 + tid*8); \
    glds16(srcA[h][1] + (ko), (dst) + (h)*8192 + 4096 + tid*8); } while(0)
#define STG_B(dst, h, ko) do { \
    glds16(srcB[h][0] + (ko), (dst) + 16384 + (h)*8192 + tid*8); \
    glds16(srcB[h][1] + (ko), (dst) + 16384 + (h)*8192 + 4096 + tid*8); } while(0)

  short* Lc = lds_s;
  short* Ln = lds_s + 32768;

  f32x4 acc[8][4] = {};
  bf16x8 af[4][2], b0[2][2], b1[2][2];

  STG_A(Lc, 0, 0);  STG_B(Lc, 0, 0);
  STG_A(Lc, 1, 0);  STG_B(Lc, 1, 0);
  STG_A(Ln, 0, 64); STG_B(Ln, 0, 64);
  asm volatile("s_waitcnt vmcnt(8)" ::: "memory");
  __builtin_amdgcn_s_barrier();

  const int T = kc >> 6;
  for (int t = 0; t < T; ++t){
    const int k1 = ((t + 1 < T) ? t + 1 : T - 1) << 6;
    const int k2 = ((t + 2 < T) ? t + 2 : T - 1) << 6;
    // ---- phase 0
    #pragma unroll
    for (int m = 0; m < 4; ++m){
      af[m][0] = *(const bf16x8*)(Lc + aoff + m*1024 + sx0);
      af[m][1] = *(const bf16x8*)(Lc + aoff + m*1024 + sx1);
    }
    #pragma unroll
    for (int n = 0; n < 2; ++n){
      b0[n][0] = *(const bf16x8*)(Lc + 16384 + boff + n*1024 + sx0);
      b0[n][1] = *(const bf16x8*)(Lc + 16384 + boff + n*1024 + sx1);
    }
    STG_A(Ln, 1, k1);
    __builtin_amdgcn_s_barrier();
    asm volatile("s_waitcnt lgkmcnt(0)");
    __builtin_amdgcn_s_setprio(1);
    #pragma unroll
    for (int m = 0; m < 4; ++m)
      #pragma unroll
      for (int n = 0; n < 2; ++n){
        acc[m][n] = mfma16(af[m][0], b0[n][0], acc[m][n]);
        acc[m][n] = mfma16(af[m][1], b0[n][1], acc[m][n]);
      }
    __builtin_amdgcn_s_setprio(0);
    asm volatile("s_waitcnt vmcnt(6)" ::: "memory");
    __builtin_amdgcn_s_barrier();
    // ---- phase 1
    #pragma unroll
    for (int n = 0; n < 2; ++n){
      b1[n][0] = *(const bf16x8*)(Lc + 24576 + boff + n*1024 + sx0);
      b1[n][1] = *(const bf16x8*)(Lc + 24576 + boff + n*1024 + sx1);
    }
    STG_B(Ln, 1, k1);
    __builtin_amdgcn_s_barrier();
    asm volatile("s_waitcnt lgkmcnt(0)");
    __builtin_amdgcn_s_setprio(1);
    #pragma unroll
    for (int m = 0; m < 4; ++m)
      #pragma unroll
      for (int n = 0; n < 2; ++n){
        acc[m][2+n] = mfma16(af[m][0], b1[n][0], acc[m][2+n]);
        acc[m][2+n] = mfma16(af[m][1], b1[n][1], acc[m][2+n]);
      }
    __builtin_amdgcn_s_setprio(0);
    __builtin_amdgcn_s_barrier();
    // ---- phase 2
    #pragma unroll
    for (int m = 0; m < 4; ++m){
      af[m][0] = *(const bf16x8*)(Lc + 8192 + aoff + m*1024 + sx0);
      af[m][1] = *(const bf16x8*)(Lc + 8192 + aoff + m*1024 + sx1);
    }
    STG_A(Lc, 0, k2);
    __builtin_amdgcn_s_barrier();
    asm volatile("s_waitcnt lgkmcnt(0)");
    __builtin_amdgcn_s_setprio(1);
    #pragma unroll
    for (int m = 0; m < 4; ++m)
      #pragma unroll
      for (int n = 0; n < 2; ++n){
        acc[4+m][n] = mfma16(af[m][0], b0[n][0], acc[4+m][n]);
        acc[4+m][n] = mfma16(af[m][1], b0[n][1], acc[4+m][n]);
      }
    __builtin_amdgcn_s_setprio(0);
    __builtin_amdgcn_s_barrier();
    // ---- phase 3
    STG_B(Lc, 0, k2);
    __builtin_amdgcn_s_barrier();
    __builtin_amdgcn_s_setprio(1);
    #pragma unroll
    for (int m = 0; m < 4; ++m)
      #pragma unroll
      for (int n = 0; n < 2; ++n){
        acc[4+m][2+n] = mfma16(af[m][0], b1[n][0], acc[4+m][2+n]);
        acc[4+m][2+n] = mfma16(af[m][1], b1[n][1], acc[4+m][2+n]);
      }
    __builtin_amdgcn_s_setprio(0);
    asm volatile("s_waitcnt vmcnt(8)" ::: "memory");
    __builtin_amdgcn_s_barrier();
    short* tp = Lc; Lc = Ln; Ln = tp;
  }
#undef STG_A
#undef STG_B

  const int rb4 = kq << 2;
  if (MODE == 0){
    float* Cp = (float*)Cv + (size_t)ksp * M * 512;
    #pragma unroll
    for (int mh = 0; mh < 2; ++mh)
      #pragma unroll
      for (int m = 0; m < 4; ++m){
        const int row0 = bm*256 + wm*128 + mh*64 + m*16 + rb4;
        #pragma unroll
        for (int r = 0; r < 4; ++r){
          const int rr = row0 + r;
          if (rr < M){
            float* Crow = Cp + (size_t)rr * 512 + bn*256 + wn*64 + fr;
            #pragma unroll
            for (int nh = 0; nh < 2; ++nh)
              #pragma unroll
              for (int n = 0; n < 2; ++n)
                Crow[nh*32 + n*16] = acc[mh*4+m][nh*2+n][r];
          }
        }
      }
  } else {
    // compose: bf16 store to C[j][kbeg + c], ldc = Kpm
    short* Cs = (short*)Cv;
    #pragma unroll
    for (int mh = 0; mh < 2; ++mh)
      #pragma unroll
      for (int m = 0; m < 4; ++m){
        const int row0 = bm*256 + wm*128 + mh*64 + m*16 + rb4;
        #pragma unroll
        for (int r = 0; r < 4; ++r){
          const int rr = row0 + r;
          if (rr < M){
            short* Crow = Cs + (size_t)rr * ldc + kbeg + bn*256 + wn*64 + fr;
            #pragma unroll
            for (int nh = 0; nh < 2; ++nh)
              #pragma unroll
              for (int n = 0; n < 2; ++n)
                Crow[nh*32 + n*16] = f2bf(acc[mh*4+m][nh*2+n][r]);
          }
        }
      }
  }
}

// ---------------- table-gather windowed MHA: one wave per (window-instance, head) ------------
// tab: [100][1536] bf16 per window (Q|K|V rows per vocab value, bias folded).
// v11 = v10 + waves-per-block from blockDim (wpb): win128 launches with 2-wave
//      blocks so block shmem = 40960 B -> 4 blocks/CU (LDS) -> 8 resident waves/CU
//      (vs <=2 blocks at 80 KB). Per-wave logic unchanged (waves are independent;
//      no __syncthreads).
template<int WIN>
__global__ __launch_bounds__(256)
void attn_g(const int* __restrict__ spec, const short* __restrict__ tab,
            short* __restrict__ ao){
  constexpr int WINP = (WIN < 32) ? 32 : WIN;     // padded k-dim
  constexpr int KMASK = WINP / 8 - 1;             // in-row swizzle key clamp
  constexpr int NT = WIN / 16;
  extern __shared__ short smem[];                 // per wave: Vt[64][WINP] + P[16][WINP]
  const int lane = threadIdx.x & 63;
  const int w = threadIdx.x >> 6;
  const int wpb = (int)(blockDim.x >> 6);
  const int wh = blockIdx.x * wpb + w;
  const int wid = wh >> 3, h = wh & 7;
  const size_t tb = (size_t)wid * WIN;
  short* vt = smem + w * 80 * WINP;
  short* pl = vt + 64 * WINP;

  const int fr = lane & 15;
  const int fk = (lane >> 4) << 3;
  const int kq = lane >> 4;
  const int rb = kq << 2;

  // ---- V^T staging: (KRUN k x 8 d) cells, packed LDS writes.
  // element (d,k) -> vt[d*WINP + (k ^ key(d))], key(x) = ((x + (x>>3)) & KMASK) << 3
  {
    constexpr int KRUN = (WIN >= 32) ? 4 : 2;
    constexpr int ITER = (WIN / KRUN) * 8 / 64;   // 1,1,2,4
    const int dgrp = lane & 7;
    #pragma unroll
    for (int it = 0; it < ITER; ++it){
      const int kb = ((lane >> 3) + it * 8) * KRUN;
      bf16x8 vv[KRUN];
      #pragma unroll
      for (int kk = 0; kk < KRUN; ++kk)
        vv[kk] = *(const bf16x8*)(tab + (size_t)spec[tb + kb + kk] * 1536 + 1024 + h * 64 + dgrp * 8);
      #pragma unroll
      for (int j = 0; j < 8; ++j){
        const int d = dgrp * 8 + j;
        const int key = ((d + (d >> 3)) & KMASK) << 3;
        short* dst = vt + d * WINP + (kb ^ key);
        if constexpr (KRUN == 4){
          s16x4 wv; wv[0]=vv[0][j]; wv[1]=vv[1][j]; wv[2]=vv[2][j]; wv[3]=vv[3][j];
          *(s16x4*)dst = wv;
        } else {
          s16x2 wv; wv[0]=vv[0][j]; wv[1]=vv[1][j];
          *(s16x2*)dst = wv;
        }
      }
    }
  }
  if constexpr (WIN == 16){
    // zero-fill V^T pad (logical k=16..31 of every d-row): uninitialized LDS may
    // hold NaN bf16 patterns and 0*NaN = NaN. lane == d (64 lanes, 64 rows).
    const int d = lane;
    const int key = ((d + (d >> 3)) & KMASK) << 3;
    short* vrow_ = vt + d * WINP;
    const s16x4 z = {0, 0, 0, 0};
    #pragma unroll
    for (int kk = 16; kk < 32; kk += 4)
      *(s16x4*)(vrow_ + (kk ^ key)) = z;
  }

  // ---- hoisted K row pointers; K fragments in regs for NT<=4
  const short* kp8[NT];
  #pragma unroll
  for (int nt = 0; nt < NT; ++nt)
    kp8[nt] = tab + (size_t)spec[tb + nt*16 + fr] * 1536 + 512 + h*64 + fk;

  bf16x8 bkh[(NT <= 4) ? NT : 1][2];
  if constexpr (NT <= 4){
    #pragma unroll
    for (int nt = 0; nt < NT; ++nt){
      bkh[nt][0] = *(const bf16x8*)(kp8[nt]);
      bkh[nt][1] = *(const bf16x8*)(kp8[nt] + 32);
    }
  }

  const int rxq = ((fr + (fr >> 3)) & KMASK) << 3; // P-row swizzle key (row = q = fr)
  short* plq = pl + fr * WINP;

  for (int qt = 0; qt < NT; ++qt){
    // Q row token == K row token for the same (tile, fr): reuse pointer, offset -512
    const short* qrow = kp8[qt] - 512;
    bf16x8 aq0 = *(const bf16x8*)(qrow);
    bf16x8 aq1 = *(const bf16x8*)(qrow + 32);
    float s[NT][4];
    #pragma unroll
    for (int nt = 0; nt < NT; ++nt){
      bf16x8 k0, k1;
      if constexpr (NT <= 4){ k0 = bkh[nt][0]; k1 = bkh[nt][1]; }
      else { k0 = *(const bf16x8*)(kp8[nt]); k1 = *(const bf16x8*)(kp8[nt] + 32); }
      f32x4 c = {0.f, 0.f, 0.f, 0.f};
      c = mfma16(k0, aq0, c);                     // swapped: C[k_local][q = lane&15]
      c = mfma16(k1, aq1, c);
      #pragma unroll
      for (int r = 0; r < 4; ++r) s[nt][r] = c[r] * 0.125f;
    }
    // in-lane softmax for q = fr: tree max/sum over 4*NT values + 2 shfls each
    float mm[NT];
    #pragma unroll
    for (int nt = 0; nt < NT; ++nt)
      mm[nt] = fmaxf(fmaxf(s[nt][0], s[nt][1]), fmaxf(s[nt][2], s[nt][3]));
    #pragma unroll
    for (int st = NT >> 1; st >= 1; st >>= 1)
      #pragma unroll
      for (int i = 0; i < st; ++i) mm[i] = fmaxf(mm[i], mm[i + st]);
    float m = mm[0];
    m = fmaxf(m, __shfl_xor(m, 16));
    m = fmaxf(m, __shfl_xor(m, 32));
    float ss[NT];
    #pragma unroll
    for (int nt = 0; nt < NT; ++nt){
      #pragma unroll
      for (int r = 0; r < 4; ++r) s[nt][r] = __expf(s[nt][r] - m);
      ss[nt] = (s[nt][0] + s[nt][1]) + (s[nt][2] + s[nt][3]);
    }
    #pragma unroll
    for (int st = NT >> 1; st >= 1; st >>= 1)
      #pragma unroll
      for (int i = 0; i < st; ++i) ss[i] += ss[i + st];
    float sum = ss[0];
    sum += __shfl_xor(sum, 16);
    sum += __shfl_xor(sum, 32);
    const float inv = 1.f / sum;
    // packed P store: lane owns k = nt*16 + rb + 0..3 of row q=fr (contiguous, b64)
    #pragma unroll
    for (int nt = 0; nt < NT; ++nt){
      s16x4 pw;
      pw[0] = f2bf(s[nt][0] * inv); pw[1] = f2bf(s[nt][1] * inv);
      pw[2] = f2bf(s[nt][2] * inv); pw[3] = f2bf(s[nt][3] * inv);
      *(s16x4*)(plq + ((nt*16 + rb) ^ rxq)) = pw;
    }
    if (WIN == 16){
      s16x4 pz = {0, 0, 0, 0};
      *(s16x4*)(plq + ((16 + rb) ^ rxq)) = pz;
    }
    // PV with swapped operands: lane (fr,kq) gets O[q=fr][d=d0*16+kq*4+r] -> packed store
    short* aorow = ao + (tb + qt*16 + fr) * 512 + h*64 + rb;
    if constexpr (WINP / 32 <= 2){
      // hoist P fragments once (d0-invariant); cheap in VGPRs for WIN<=64
      bf16x8 aph[WINP / 32];
      #pragma unroll
      for (int ks = 0; ks < WINP/32; ++ks)
        aph[ks] = *(const bf16x8*)(pl + fr * WINP + ((ks*32 + fk) ^ rxq));
      #pragma unroll
      for (int d0 = 0; d0 < 4; ++d0){
        const int vrow = d0*16 + fr;
        const int vx = ((vrow + (vrow >> 3)) & KMASK) << 3;
        f32x4 o = {0.f, 0.f, 0.f, 0.f};
        #pragma unroll
        for (int ks = 0; ks < WINP/32; ++ks){
          bf16x8 bv = *(const bf16x8*)(vt + vrow * WINP + ((ks*32 + fk) ^ vx));
          o = mfma16(bv, aph[ks], o);
        }
        s16x4 ov;
        ov[0]=f2bf(o[0]); ov[1]=f2bf(o[1]); ov[2]=f2bf(o[2]); ov[3]=f2bf(o[3]);
        *(s16x4*)(aorow + d0*16) = ov;
      }
    } else {
      // WIN=128: reload ap per d0 (keeps VGPR below the 128 cliff)
      #pragma unroll
      for (int d0 = 0; d0 < 4; ++d0){
        const int vrow = d0*16 + fr;
        const int vx = ((vrow + (vrow >> 3)) & KMASK) << 3;
        f32x4 o = {0.f, 0.f, 0.f, 0.f};
        #pragma unroll
        for (int ks = 0; ks < WINP/32; ++ks){
          bf16x8 ap = *(const bf16x8*)(pl + fr * WINP + ((ks*32 + fk) ^ rxq));
          bf16x8 bv = *(const bf16x8*)(vt + vrow * WINP + ((ks*32 + fk) ^ vx));
          o = mfma16(bv, ap, o);
        }
        s16x4 ov;
        ov[0]=f2bf(o[0]); ov[1]=f2bf(o[1]); ov[2]=f2bf(o[2]); ov[3]=f2bf(o[3]);
        *(s16x4*)(aorow + d0*16) = ov;
      }
    }
    // no __syncthreads: smem slices are wave-private; in-wave lgkmcnt ordering suffices
  }
}

// ---------------- host ----------------
extern "C" void kernel_launch(void* const* d_in, const int* in_sizes, int n_in,
                              void* d_out, int out_size, void* d_ws, size_t ws_size,
                              hipStream_t stream){
  const int*   spec   = (const int*)d_in[0];
  const float* emb    = (const float*)d_in[1];
  const float* attn_w = (const float*)d_in[2];
  const float* attn_b = (const float*)d_in[3];
  const float* pw[4]  = {(const float*)d_in[4], (const float*)d_in[6],
                         (const float*)d_in[8], (const float*)d_in[10]};
  const float* pb[4]  = {(const float*)d_in[5], (const float*)d_in[7],
                         (const float*)d_in[9], (const float*)d_in[11]};
  float* out = (float*)d_out;

  // fixed buffers (~135.5 MB): wtq | wcast | wtpc | cbadd | embT | qkvtab
  short* wtq    = (short*)d_ws;             // [4][1536][512] transposed q,k,v
  short* wcast  = wtq + 3145728;            // [4][512][512] Wo cast
  short* wtpc   = wcast + 1048576;          // composed pm weights
  float* cbadd  = (float*)(wtpc + 62914560);// [4][512]
  short* embT   = (short*)(cbadd + 2048);   // [100][512]
  short* qkvtab = embT + 51200;             // [4][100][1536]
  short* dyn    = qkvtab + 614400;

  short* aob  = dyn;                        // [102400][512] bf16 (105 MB)
  float* pbuf = (float*)(aob + (size_t)TOK_TOTAL * 512); // split-K partials (52 MB)
  short* scratch = dyn;                     // pw^T staging (prep only, aliases aob)

  static const int winv[4]  = {16, 32, 64, 128};
  static const int wpoff[4] = {0, 16*262144, 48*262144, 112*262144};
  static const int roffv[4] = {0, 200, 300, 350};
  static const int wpbv[4]  = {4, 4, 4, 2};  // waves/block: win128 uses 2-wave blocks
                                             // (40960 B shmem -> 4 blocks/CU vs 2)

  (void)hipFuncSetAttribute(reinterpret_cast<const void*>(gemm256_pm<0>),
                            hipFuncAttributeMaxDynamicSharedMemorySize, 131072);
  (void)hipFuncSetAttribute(reinterpret_cast<const void*>(gemm256_pm<1>),
                            hipFuncAttributeMaxDynamicSharedMemorySize, 131072);

  embcast_k<<<25, 256, 0, stream>>>(emb, embT);
  dim3 tb(32, 8);
  for (int i = 0; i < 4; ++i){
    const int win = winv[i];
    const int Kpm = win * 512;
    for (int j = 0; j < 3; ++j)
      transpose_cast<<<dim3(16,16), tb, 0, stream>>>(attn_w + (size_t)(i*4+j)*262144,
                                                     wtq + (size_t)(i*3+j)*262144, 512, 512);
    cast_k<<<128, 256, 0, stream>>>(attn_w + (size_t)(i*4+3)*262144, wcast + (size_t)i*262144);
    transpose_cast<<<dim3(16, win*16), tb, 0, stream>>>(pw[i], scratch, Kpm, 512);
    bias_fold_k<<<512, 256, 0, stream>>>(scratch, attn_b + i*2048 + 1536, cbadd + i*512, Kpm);
    // compose wtpc[j][p*512+c] = sum_m scratch[j][p*512+m] * wcast[c][m]  (deep-pipelined)
    gemm256_pm<1><<<win*4, 512, 131072, stream>>>(scratch, Kpm, wcast + (size_t)i*262144, 512,
                                                  wtpc + wpoff[i], 512, 512, Kpm);
    // qkvtab_i[100][1536] = embT @ wtq_i^T + bias(q|k|v)
    gemm_bt<<<12, 256, 0, stream>>>(embT, 512, wtq + (size_t)i*3*262144, 512,
                                    qkvtab + (size_t)i*153600, 1536,
                                    100, 1536, 512, attn_b + i*2048, 512);
  }

  for (int i = 0; i < 4; ++i){
    const int win = winv[i];
    const short* tabw = qkvtab + (size_t)i * 153600;
    const int wpb = wpbv[i];
    const int blocks = (TOK_TOTAL / win) * 8 / wpb;
    const int winp = (win < 32) ? 32 : win;
    const size_t shmem = (size_t)wpb * 80 * winp * 2;
    if (win == 16)       attn_g<16 ><<<blocks, wpb*64, shmem, stream>>>(spec, tabw, aob);
    else if (win == 32)  attn_g<32 ><<<blocks, wpb*64, shmem, stream>>>(spec, tabw, aob);
    else if (win == 64)  attn_g<64 ><<<blocks, wpb*64, shmem, stream>>>(spec, tabw, aob);
    else                 attn_g<128><<<blocks, wpb*64, shmem, stream>>>(spec, tabw, aob);
    // patch-merge split-K (kc=2048) via 256^2 pipelined GEMM, then deterministic reduce (+bias)
    const int Kpm = win * 512;
    const int S = Kpm / 2048;
    const int Mc = TOK_TOTAL / win;
    const int mtp = (Mc + 255) >> 8;
    gemm256_pm<0><<<mtp * 2 * S, 512, 131072, stream>>>(aob, Kpm, wtpc + wpoff[i], Kpm,
                                                        pbuf, Mc, 2048, 512);
    reduce_k<<<Mc / 2, 256, 0, stream>>>(pbuf, out, pb[i], cbadd + i*512,
                                         Mc, S, L_SEQ / win, roffv[i]);
  }
}

// Round 9
// 775.843 us; speedup vs baseline: 1.2020x; 1.1799x over previous
//
#include <hip/hip_runtime.h>
#include <hip/hip_bf16.h>
#include <stdint.h>

#define TOK_TOTAL 102400   // 32*3200
#define L_SEQ 3200

typedef __attribute__((ext_vector_type(8))) short bf16x8;
typedef __attribute__((ext_vector_type(4))) short s16x4;
typedef __attribute__((ext_vector_type(2))) short s16x2;
typedef __attribute__((ext_vector_type(4))) float f32x4;

__device__ __forceinline__ short f2bf(float f){
  union { __hip_bfloat16 h; short s; } u;
  u.h = __float2bfloat16(f);
  return u.s;
}

__device__ __forceinline__ f32x4 mfma16(bf16x8 a, bf16x8 b, f32x4 c){
  return __builtin_amdgcn_mfma_f32_16x16x32_bf16(a, b, c, 0, 0, 0);
}

__device__ __forceinline__ void glds16(const short* g, short* l){
  __builtin_amdgcn_global_load_lds((const __attribute__((address_space(1))) unsigned*)g,
                                   (__attribute__((address_space(3))) unsigned*)l, 16, 0, 0);
}

// bijective XCD-chunk swizzle (m204)
__device__ __forceinline__ int xswz(int bid, int nwg){
  int q = nwg >> 3, r = nwg & 7, x = bid & 7, k = bid >> 3;
  return (x < r ? x * (q + 1) : r * (q + 1) + (x - r) * q) + k;
}

// scratch4 layout offset (shorts): windows 16,32,64,128 concatenated pw^T blocks
__device__ __host__ __forceinline__ size_t soff4(int i){
  return (size_t)((16 << i) - 16) * 262144;
}

// ---------------- embT: bf16 embedding table with sqrt(512) folded (100x512) ----------------
__global__ void embcast_k(const float* __restrict__ emb, short* __restrict__ embT){
  int gid = blockIdx.x * 256 + threadIdx.x;     // 6400 threads, 8 elems each
  const float SC = 22.627416997969522f;
  const float4 f0 = ((const float4*)emb)[gid*2];
  const float4 f1 = ((const float4*)emb)[gid*2+1];
  bf16x8 o;
  o[0]=f2bf(f0.x*SC); o[1]=f2bf(f0.y*SC); o[2]=f2bf(f0.z*SC); o[3]=f2bf(f0.w*SC);
  o[4]=f2bf(f1.x*SC); o[5]=f2bf(f1.y*SC); o[6]=f2bf(f1.z*SC); o[7]=f2bf(f1.w*SC);
  *(bf16x8*)(embT + gid*8) = o;
}

// ---------------- batched transpose f32 512x512 -> bf16 512x512 for wtq (12 slices) ---------
__global__ void transpose_wtq(const float* __restrict__ attn_w, short* __restrict__ wtq){
  __shared__ float tile[32][33];
  const int z = blockIdx.z;                     // 0..11 = i*3+j
  const int i = z / 3, j = z - i * 3;
  const float* in = attn_w + (size_t)(i*4 + j) * 262144;
  short* out = wtq + (size_t)z * 262144;
  int c0 = blockIdx.x * 32, r0 = blockIdx.y * 32;
  int tx = threadIdx.x, ty = threadIdx.y;       // 32x8
  #pragma unroll
  for (int k = 0; k < 32; k += 8)
    tile[ty + k][tx] = in[(size_t)(r0 + ty + k) * 512 + c0 + tx];
  __syncthreads();
  const int t = ty * 32 + tx;
  const int c = t >> 3;
  const int r4 = (t & 7) << 2;
  s16x4 o4;
  #pragma unroll
  for (int k = 0; k < 4; ++k) o4[k] = f2bf(tile[r4 + k][c]);
  *(s16x4*)(out + (size_t)(c0 + c) * 512 + r0 + r4) = o4;
}

// ---------------- batched transpose f32 [Kpm,512] -> bf16 [512,Kpm] for pw (4 windows) -------
__global__ void transpose_pw4(const float* __restrict__ p0, const float* __restrict__ p1,
                              const float* __restrict__ p2, const float* __restrict__ p3,
                              short* __restrict__ scratch4){
  __shared__ float tile[32][33];
  const int i = blockIdx.z;
  const int win = 16 << i;
  if ((int)blockIdx.y >= win * 16) return;      // early-out pad blocks
  const float* in = (i == 0) ? p0 : (i == 1) ? p1 : (i == 2) ? p2 : p3;
  short* out = scratch4 + soff4(i);
  const int R = win * 512;
  int c0 = blockIdx.x * 32, r0 = blockIdx.y * 32;
  int tx = threadIdx.x, ty = threadIdx.y;       // 32x8
  #pragma unroll
  for (int k = 0; k < 32; k += 8)
    tile[ty + k][tx] = in[(size_t)(r0 + ty + k) * 512 + c0 + tx];
  __syncthreads();
  const int t = ty * 32 + tx;
  const int c = t >> 3;
  const int r4 = (t & 7) << 2;
  s16x4 o4;
  #pragma unroll
  for (int k = 0; k < 4; ++k) o4[k] = f2bf(tile[r4 + k][c]);
  *(s16x4*)(out + (size_t)(c0 + c) * R + r0 + r4) = o4;
}

// ---------------- batched cast f32 -> bf16 of 4 Wo matrices ----------------
__global__ void cast4_k(const float* __restrict__ attn_w, short* __restrict__ wcast){
  int gid = blockIdx.x * 256 + threadIdx.x;     // 131072 threads, 8 elems each
  const int i = gid >> 15;                      // 32768 groups per 512x512 matrix
  const int off = (gid & 32767) * 8;
  const float* in = attn_w + (size_t)(i*4 + 3) * 262144 + off;
  const float4 f0 = ((const float4*)in)[0];
  const float4 f1 = ((const float4*)in)[1];
  bf16x8 o;
  o[0]=f2bf(f0.x); o[1]=f2bf(f0.y); o[2]=f2bf(f0.z); o[3]=f2bf(f0.w);
  o[4]=f2bf(f1.x); o[5]=f2bf(f1.y); o[6]=f2bf(f1.z); o[7]=f2bf(f1.w);
  *(bf16x8*)(wcast + (size_t)i * 262144 + off) = o;
}

// ---------------- batched bias fold: cbadd[i][j] = sum_r bo_i[r&511] * pwT_i[j][r] ----------
__global__ void bias_fold4_k(const short* __restrict__ scratch4, const float* __restrict__ attn_b,
                             float* __restrict__ cbadd){
  const int i = blockIdx.x >> 9;
  const int j = blockIdx.x & 511;
  const int Kpm = (16 << i) << 9;
  const short* row = scratch4 + soff4(i) + (size_t)j * Kpm;
  const float* bo = attn_b + i * 2048 + 1536;
  float s = 0.f;
  for (int r = threadIdx.x; r < Kpm; r += 256){
    union { unsigned u; float f; } c; c.u = ((unsigned)(unsigned short)row[r]) << 16;
    s += c.f * bo[r & 511];
  }
  s += __shfl_xor(s, 1);  s += __shfl_xor(s, 2);  s += __shfl_xor(s, 4);
  s += __shfl_xor(s, 8);  s += __shfl_xor(s, 16); s += __shfl_xor(s, 32);
  __shared__ float red[4];
  if ((threadIdx.x & 63) == 0) red[threadIdx.x >> 6] = s;
  __syncthreads();
  if (threadIdx.x == 0) cbadd[i * 512 + j] = red[0] + red[1] + red[2] + red[3];
}

// ---------------- split-K reduce + bias, float4 (writes each out element exactly once) --------
__global__ void reduce_k(const float* __restrict__ part, float* __restrict__ out,
                         const float* __restrict__ pb, const float* __restrict__ cb,
                         int Mc, int S, int rpb, int roff){
  int gid = blockIdx.x * 256 + threadIdx.x;     // Mc*128 threads
  int c4 = (gid & 127) << 2;
  int rr = gid >> 7;
  float4 s = *(const float4*)(pb + c4);
  const float4 cv = *(const float4*)(cb + c4);
  s.x += cv.x; s.y += cv.y; s.z += cv.z; s.w += cv.w;
  const float* p = part + (size_t)rr * 512 + c4;
  const size_t stride = (size_t)Mc * 512;
  for (int k = 0; k < S; ++k){
    const float4 v = *(const float4*)(p + (size_t)k * stride);
    s.x += v.x; s.y += v.y; s.z += v.z; s.w += v.w;
  }
  int ob = rr / rpb;
  int orow = rr - ob * rpb;
  *(float4*)(out + (size_t)(ob * 375 + roff + orow) * 512 + c4) = s;
}

// ---------------- 128^2 GEMM C = A[M,K] @ Bt[N,K]^T, BK=64, swizzled LDS ----------------
// bf16 store + f32 bias. B4=1: batched over 4 windows (grid 48 = 4 x 12 N-tiles),
// per-window Bt/C/bias offsets decoded in-kernel (qkvtab precompute).
template<int B4>
__global__ __launch_bounds__(256)
void gemm_bt(const short* __restrict__ A, int lda,
             const short* __restrict__ Bt, int ldb,
             void* __restrict__ Cv, int ldc,
             int M, int N, int K,
             const float* __restrict__ bias,
             int kc)
{
  __shared__ short alds[8192];   // [128][64]
  __shared__ short blds[8192];

  const int t = threadIdx.x;
  int wg = xswz(blockIdx.x, gridDim.x);
  if (B4){
    const int i = wg / 12; wg -= i * 12;
    Bt += (size_t)i * 3 * 262144;
    Cv = (void*)((short*)Cv + (size_t)i * 153600);
    bias += i * 2048;
  }
  const int Mt = (M + 127) >> 7;
  const int Nt = N >> 7;
  const int bn = wg % Nt; wg /= Nt;
  const int bm = wg % Mt; wg /= Mt;
  const int ksp = wg;
  int kbeg = ksp * kc, kend = kbeg + kc; if (kend > K) kend = K;

  const int srow = t >> 3;                      // 0..31
  const int scol = (t & 7) << 3;
  const int scolz = scol ^ ((srow & 7) << 3);   // swizzled SOURCE column (m173)
  const short* ga[4]; const short* gb[4];
  #pragma unroll
  for (int p = 0; p < 4; ++p){
    int arow = bm*128 + srow + p*32; if (arow >= M) arow = M - 1;
    ga[p] = A + (size_t)arow * lda + kbeg + scolz;
    gb[p] = Bt + (size_t)(bn*128 + srow + p*32) * ldb + kbeg + scolz;
  }
  short* la = alds + t * 8;
  short* lb = blds + t * 8;

  const int wave = t >> 6;
  const int lane = t & 63;
  const int wm = (wave >> 1) << 6;
  const int wn = (wave & 1) << 6;
  const int fr = lane & 15;
  const int fk = (lane >> 4) << 3;
  const int fx = (fr & 7) << 3;

  f32x4 acc[4][4] = {};

  for (int kt = kbeg; kt < kend; kt += 64) {
    #pragma unroll
    for (int p = 0; p < 4; ++p){
      glds16(ga[p], la + p*2048);
      glds16(gb[p], lb + p*2048);
      ga[p] += 64; gb[p] += 64;
    }
    __syncthreads();
    bf16x8 af[2][4], bfr[2][4];
    #pragma unroll
    for (int ks = 0; ks < 2; ++ks){
      const int kcz = (ks*32 + fk) ^ fx;
      #pragma unroll
      for (int m = 0; m < 4; ++m) af[ks][m] = *(const bf16x8*)(alds + (wm + m*16 + fr)*64 + kcz);
      #pragma unroll
      for (int n = 0; n < 4; ++n) bfr[ks][n] = *(const bf16x8*)(blds + (wn + n*16 + fr)*64 + kcz);
    }
    #pragma unroll
    for (int ks = 0; ks < 2; ++ks)
      #pragma unroll
      for (int m = 0; m < 4; ++m)
        #pragma unroll
        for (int n = 0; n < 4; ++n)
          acc[m][n] = mfma16(af[ks][m], bfr[ks][n], acc[m][n]);
    __syncthreads();
  }

  const int rb = (lane >> 4) << 2;
  short* C = (short*)Cv;
  #pragma unroll
  for (int m = 0; m < 4; ++m){
    const int row0 = bm*128 + wm + m*16 + rb;
    #pragma unroll
    for (int n = 0; n < 4; ++n){
      const int col = bn*128 + wn + n*16 + fr;
      const float bv = bias[col];
      #pragma unroll
      for (int r = 0; r < 4; ++r){
        const int rr = row0 + r;
        if (rr < M) C[(size_t)rr * ldc + col] = f2bf(acc[m][n][r] + bv);
      }
    }
  }
}

// ---------------- 256^2 deep-pipelined GEMM (T2+T3+T4+T5) ----------------
// MODE 0 (split-K patch-merge): Cpart[ksp][M][512] = A[M,lda] @ Bt[512,ldb]^T over
//        K-slice [ksp*kc, +kc), f32 partial store.
// MODE 2 (batched compose, 4 windows in one launch, grid 960 = 64+128+256+512):
//        per window i, batch p: C[j][p*512+c] = sum_m A[j][p*512+m] * Bt[c][m];
//        A=scratch4 base, Bt=wcast base, Cv=wtpc base; offsets decoded in-kernel;
//        bf16 store.
// 512 thr = 8 waves (2Mx4N), per-wave C 128x64, BK=64, LDS 128 KiB = 2 dbuf x (A|B).
// 4 phases per K-tile; counted vmcnt (6)/(8), never drained in main loop.
template<int MODE>
__global__ __launch_bounds__(512, 2)
void gemm256_pm(const short* __restrict__ A, int lda,
                const short* __restrict__ Bt, int ldb,
                void* __restrict__ Cv, int M, int kc, int ldc)
{
  extern __shared__ short lds_s[];
  const int tid = threadIdx.x;
  int wg = xswz(blockIdx.x, gridDim.x);
  int bn, bm, ksp, kbeg, kbegB;
  if (MODE == 2){
    int i, base;
    if (wg < 64){ i = 0; base = 0; }
    else if (wg < 192){ i = 1; base = 64; }
    else if (wg < 448){ i = 2; base = 192; }
    else { i = 3; base = 448; }
    const int local = wg - base;
    bn = local & 1; bm = (local >> 1) & 1; ksp = local >> 2;   // p = 512-col batch
    const int Kpm = (16 << i) << 9;
    const size_t so = soff4(i);
    A += so; lda = Kpm;
    Bt += (size_t)i * 262144;
    Cv = (void*)((short*)Cv + so); ldc = Kpm;
    M = 512; kc = 512;
    kbeg = ksp << 9; kbegB = 0;
  } else {
    bn = wg & 1; wg >>= 1;
    const int Mt = (M + 255) >> 8;
    bm = wg % Mt; ksp = wg / Mt;
    kbeg = ksp * kc; kbegB = kbeg;
  }

  const int wave = tid >> 6, lane = tid & 63;
  const int wm = wave >> 2, wn = wave & 3;   // 2M x 4N waves
  const int fr = lane & 15, kq = lane >> 4;
  const int fx = fr & 7;
  const int sx0 = (kq ^ fx) << 3;            // swizzled 16B slot, ks=0 (shorts)
  const int sx1 = ((4 + kq) ^ fx) << 3;      // ks=1
  const int aoff = (wm * 64 + fr) << 6;      // phys A row * 64 shorts
  const int boff = (wn * 32 + fr) << 6;

  const int sr = tid >> 3;
  const int kg = ((tid & 7) ^ (sr & 7)) << 3;
  const short* srcA[2][2]; const short* srcB[2][2];
  #pragma unroll
  for (int h = 0; h < 2; ++h)
    #pragma unroll
    for (int u = 0; u < 2; ++u){
      int r = bm * 256 + u * 128 + h * 64 + sr; if (r >= M) r = M - 1;
      srcA[h][u] = A + (size_t)r * lda + kbeg + kg;
      const int br = (u * 2 + (sr >> 5)) * 64 + h * 32 + (sr & 31);
      srcB[h][u] = Bt + (size_t)(bn * 256 + br) * ldb + kbegB + kg;
    }

#define STG_A(dst, h, ko) do { \
    glds16(srcA[h][0] + (ko), (dst) + (h)*8192 + tid*8); \
    glds16(srcA[h][1] + (ko), (dst) + (h)*8192 + 4096 + tid*8); } while(0)
#define STG_B(dst, h, ko) do { \
    glds16(srcB[h][0] + (ko), (dst) + 16384 + (h)*8192 + tid*8); \
    glds16(srcB[h][1] + (ko), (dst) + 16384 + (h)*8192 + 4096 + tid*8); } while(0)

  short* Lc = lds_s;
  short* Ln = lds_s + 32768;

  f32x4 acc[8][4] = {};
  bf16x8 af[4][2], b0[2][2], b1[2][2];

  STG_A(Lc, 0, 0);  STG_B(Lc, 0, 0);
  STG_A(Lc, 1, 0);  STG_B(Lc, 1, 0);
  STG_A(Ln, 0, 64); STG_B(Ln, 0, 64);
  asm volatile("s_waitcnt vmcnt(8)" ::: "memory");
  __builtin_amdgcn_s_barrier();

  const int T = kc >> 6;
  for (int t = 0; t < T; ++t){
    const int k1 = ((t + 1 < T) ? t + 1 : T - 1) << 6;
    const int k2 = ((t + 2 < T) ? t + 2 : T - 1) << 6;
    // ---- phase 0
    #pragma unroll
    for (int m = 0; m < 4; ++m){
      af[m][0] = *(const bf16x8*)(Lc + aoff + m*1024 + sx0);
      af[m][1] = *(const bf16x8*)(Lc + aoff + m*1024 + sx1);
    }
    #pragma unroll
    for (int n = 0; n < 2; ++n){
      b0[n][0] = *(const bf16x8*)(Lc + 16384 + boff + n*1024 + sx0);
      b0[n][1] = *(const bf16x8*)(Lc + 16384 + boff + n*1024 + sx1);
    }
    STG_A(Ln, 1, k1);
    __builtin_amdgcn_s_barrier();
    asm volatile("s_waitcnt lgkmcnt(0)");
    __builtin_amdgcn_s_setprio(1);
    #pragma unroll
    for (int m = 0; m < 4; ++m)
      #pragma unroll
      for (int n = 0; n < 2; ++n){
        acc[m][n] = mfma16(af[m][0], b0[n][0], acc[m][n]);
        acc[m][n] = mfma16(af[m][1], b0[n][1], acc[m][n]);
      }
    __builtin_amdgcn_s_setprio(0);
    asm volatile("s_waitcnt vmcnt(6)" ::: "memory");
    __builtin_amdgcn_s_barrier();
    // ---- phase 1
    #pragma unroll
    for (int n = 0; n < 2; ++n){
      b1[n][0] = *(const bf16x8*)(Lc + 24576 + boff + n*1024 + sx0);
      b1[n][1] = *(const bf16x8*)(Lc + 24576 + boff + n*1024 + sx1);
    }
    STG_B(Ln, 1, k1);
    __builtin_amdgcn_s_barrier();
    asm volatile("s_waitcnt lgkmcnt(0)");
    __builtin_amdgcn_s_setprio(1);
    #pragma unroll
    for (int m = 0; m < 4; ++m)
      #pragma unroll
      for (int n = 0; n < 2; ++n){
        acc[m][2+n] = mfma16(af[m][0], b1[n][0], acc[m][2+n]);
        acc[m][2+n] = mfma16(af[m][1], b1[n][1], acc[m][2+n]);
      }
    __builtin_amdgcn_s_setprio(0);
    __builtin_amdgcn_s_barrier();
    // ---- phase 2
    #pragma unroll
    for (int m = 0; m < 4; ++m){
      af[m][0] = *(const bf16x8*)(Lc + 8192 + aoff + m*1024 + sx0);
      af[m][1] = *(const bf16x8*)(Lc + 8192 + aoff + m*1024 + sx1);
    }
    STG_A(Lc, 0, k2);
    __builtin_amdgcn_s_barrier();
    asm volatile("s_waitcnt lgkmcnt(0)");
    __builtin_amdgcn_s_setprio(1);
    #pragma unroll
    for (int m = 0; m < 4; ++m)
      #pragma unroll
      for (int n = 0; n < 2; ++n){
        acc[4+m][n] = mfma16(af[m][0], b0[n][0], acc[4+m][n]);
        acc[4+m][n] = mfma16(af[m][1], b0[n][1], acc[4+m][n]);
      }
    __builtin_amdgcn_s_setprio(0);
    __builtin_amdgcn_s_barrier();
    // ---- phase 3
    STG_B(Lc, 0, k2);
    __builtin_amdgcn_s_barrier();
    __builtin_amdgcn_s_setprio(1);
    #pragma unroll
    for (int m = 0; m < 4; ++m)
      #pragma unroll
      for (int n = 0; n < 2; ++n){
        acc[4+m][2+n] = mfma16(af[m][0], b1[n][0], acc[4+m][2+n]);
        acc[4+m][2+n] = mfma16(af[m][1], b1[n][1], acc[4+m][2+n]);
      }
    __builtin_amdgcn_s_setprio(0);
    asm volatile("s_waitcnt vmcnt(8)" ::: "memory");
    __builtin_amdgcn_s_barrier();
    short* tp = Lc; Lc = Ln; Ln = tp;
  }
#undef STG_A
#undef STG_B

  const int rb4 = kq << 2;
  if (MODE == 0){
    float* Cp = (float*)Cv + (size_t)ksp * M * 512;
    #pragma unroll
    for (int mh = 0; mh < 2; ++mh)
      #pragma unroll
      for (int m = 0; m < 4; ++m){
        const int row0 = bm*256 + wm*128 + mh*64 + m*16 + rb4;
        #pragma unroll
        for (int r = 0; r < 4; ++r){
          const int rr = row0 + r;
          if (rr < M){
            float* Crow = Cp + (size_t)rr * 512 + bn*256 + wn*64 + fr;
            #pragma unroll
            for (int nh = 0; nh < 2; ++nh)
              #pragma unroll
              for (int n = 0; n < 2; ++n)
                Crow[nh*32 + n*16] = acc[mh*4+m][nh*2+n][r];
          }
        }
      }
  } else {
    // compose: bf16 store to C[j][kbeg + c], ldc = Kpm
    short* Cs = (short*)Cv;
    #pragma unroll
    for (int mh = 0; mh < 2; ++mh)
      #pragma unroll
      for (int m = 0; m < 4; ++m){
        const int row0 = bm*256 + wm*128 + mh*64 + m*16 + rb4;
        #pragma unroll
        for (int r = 0; r < 4; ++r){
          const int rr = row0 + r;
          if (rr < M){
            short* Crow = Cs + (size_t)rr * ldc + kbeg + bn*256 + wn*64 + fr;
            #pragma unroll
            for (int nh = 0; nh < 2; ++nh)
              #pragma unroll
              for (int n = 0; n < 2; ++n)
                Crow[nh*32 + n*16] = f2bf(acc[mh*4+m][nh*2+n][r]);
          }
        }
      }
  }
}

// ---------------- table-gather windowed MHA: one wave per (window-instance, head) ------------
// tab: [100][1536] bf16 per window (Q|K|V rows per vocab value, bias folded).
// v11: swapped QK^T (in-lane softmax), packed P/V/O stores, conflict-spreading
//      swizzle key, waves-per-block from blockDim (win128 uses 2-wave blocks).
template<int WIN>
__global__ __launch_bounds__(256)
void attn_g(const int* __restrict__ spec, const short* __restrict__ tab,
            short* __restrict__ ao){
  constexpr int WINP = (WIN < 32) ? 32 : WIN;     // padded k-dim
  constexpr int KMASK = WINP / 8 - 1;             // in-row swizzle key clamp
  constexpr int NT = WIN / 16;
  extern __shared__ short smem[];                 // per wave: Vt[64][WINP] + P[16][WINP]
  const int lane = threadIdx.x & 63;
  const int w = threadIdx.x >> 6;
  const int wpb = (int)(blockDim.x >> 6);
  const int wh = blockIdx.x * wpb + w;
  const int wid = wh >> 3, h = wh & 7;
  const size_t tb = (size_t)wid * WIN;
  short* vt = smem + w * 80 * WINP;
  short* pl = vt + 64 * WINP;

  const int fr = lane & 15;
  const int fk = (lane >> 4) << 3;
  const int kq = lane >> 4;
  const int rb = kq << 2;

  // ---- V^T staging: (KRUN k x 8 d) cells, packed LDS writes.
  // element (d,k) -> vt[d*WINP + (k ^ key(d))], key(x) = ((x + (x>>3)) & KMASK) << 3
  {
    constexpr int KRUN = (WIN >= 32) ? 4 : 2;
    constexpr int ITER = (WIN / KRUN) * 8 / 64;   // 1,1,2,4
    const int dgrp = lane & 7;
    #pragma unroll
    for (int it = 0; it < ITER; ++it){
      const int kb = ((lane >> 3) + it * 8) * KRUN;
      bf16x8 vv[KRUN];
      #pragma unroll
      for (int kk = 0; kk < KRUN; ++kk)
        vv[kk] = *(const bf16x8*)(tab + (size_t)spec[tb + kb + kk] * 1536 + 1024 + h * 64 + dgrp * 8);
      #pragma unroll
      for (int j = 0; j < 8; ++j){
        const int d = dgrp * 8 + j;
        const int key = ((d + (d >> 3)) & KMASK) << 3;
        short* dst = vt + d * WINP + (kb ^ key);
        if constexpr (KRUN == 4){
          s16x4 wv; wv[0]=vv[0][j]; wv[1]=vv[1][j]; wv[2]=vv[2][j]; wv[3]=vv[3][j];
          *(s16x4*)dst = wv;
        } else {
          s16x2 wv; wv[0]=vv[0][j]; wv[1]=vv[1][j];
          *(s16x2*)dst = wv;
        }
      }
    }
  }
  if constexpr (WIN == 16){
    // zero-fill V^T pad (logical k=16..31 of every d-row): uninitialized LDS may
    // hold NaN bf16 patterns and 0*NaN = NaN. lane == d (64 lanes, 64 rows).
    const int d = lane;
    const int key = ((d + (d >> 3)) & KMASK) << 3;
    short* vrow_ = vt + d * WINP;
    const s16x4 z = {0, 0, 0, 0};
    #pragma unroll
    for (int kk = 16; kk < 32; kk += 4)
      *(s16x4*)(vrow_ + (kk ^ key)) = z;
  }

  // ---- hoisted K row pointers; K fragments in regs for NT<=4
  const short* kp8[NT];
  #pragma unroll
  for (int nt = 0; nt < NT; ++nt)
    kp8[nt] = tab + (size_t)spec[tb + nt*16 + fr] * 1536 + 512 + h*64 + fk;

  bf16x8 bkh[(NT <= 4) ? NT : 1][2];
  if constexpr (NT <= 4){
    #pragma unroll
    for (int nt = 0; nt < NT; ++nt){
      bkh[nt][0] = *(const bf16x8*)(kp8[nt]);
      bkh[nt][1] = *(const bf16x8*)(kp8[nt] + 32);
    }
  }

  const int rxq = ((fr + (fr >> 3)) & KMASK) << 3; // P-row swizzle key (row = q = fr)
  short* plq = pl + fr * WINP;

  for (int qt = 0; qt < NT; ++qt){
    // Q row token == K row token for the same (tile, fr): reuse pointer, offset -512
    const short* qrow = kp8[qt] - 512;
    bf16x8 aq0 = *(const bf16x8*)(qrow);
    bf16x8 aq1 = *(const bf16x8*)(qrow + 32);
    float s[NT][4];
    #pragma unroll
    for (int nt = 0; nt < NT; ++nt){
      bf16x8 k0, k1;
      if constexpr (NT <= 4){ k0 = bkh[nt][0]; k1 = bkh[nt][1]; }
      else { k0 = *(const bf16x8*)(kp8[nt]); k1 = *(const bf16x8*)(kp8[nt] + 32); }
      f32x4 c = {0.f, 0.f, 0.f, 0.f};
      c = mfma16(k0, aq0, c);                     // swapped: C[k_local][q = lane&15]
      c = mfma16(k1, aq1, c);
      #pragma unroll
      for (int r = 0; r < 4; ++r) s[nt][r] = c[r] * 0.125f;
    }
    // in-lane softmax for q = fr: tree max/sum over 4*NT values + 2 shfls each
    float mm[NT];
    #pragma unroll
    for (int nt = 0; nt < NT; ++nt)
      mm[nt] = fmaxf(fmaxf(s[nt][0], s[nt][1]), fmaxf(s[nt][2], s[nt][3]));
    #pragma unroll
    for (int st = NT >> 1; st >= 1; st >>= 1)
      #pragma unroll
      for (int i = 0; i < st; ++i) mm[i] = fmaxf(mm[i], mm[i + st]);
    float m = mm[0];
    m = fmaxf(m, __shfl_xor(m, 16));
    m = fmaxf(m, __shfl_xor(m, 32));
    float ss[NT];
    #pragma unroll
    for (int nt = 0; nt < NT; ++nt){
      #pragma unroll
      for (int r = 0; r < 4; ++r) s[nt][r] = __expf(s[nt][r] - m);
      ss[nt] = (s[nt][0] + s[nt][1]) + (s[nt][2] + s[nt][3]);
    }
    #pragma unroll
    for (int st = NT >> 1; st >= 1; st >>= 1)
      #pragma unroll
      for (int i = 0; i < st; ++i) ss[i] += ss[i + st];
    float sum = ss[0];
    sum += __shfl_xor(sum, 16);
    sum += __shfl_xor(sum, 32);
    const float inv = 1.f / sum;
    // packed P store: lane owns k = nt*16 + rb + 0..3 of row q=fr (contiguous, b64)
    #pragma unroll
    for (int nt = 0; nt < NT; ++nt){
      s16x4 pw;
      pw[0] = f2bf(s[nt][0] * inv); pw[1] = f2bf(s[nt][1] * inv);
      pw[2] = f2bf(s[nt][2] * inv); pw[3] = f2bf(s[nt][3] * inv);
      *(s16x4*)(plq + ((nt*16 + rb) ^ rxq)) = pw;
    }
    if (WIN == 16){
      s16x4 pz = {0, 0, 0, 0};
      *(s16x4*)(plq + ((16 + rb) ^ rxq)) = pz;
    }
    // PV with swapped operands: lane (fr,kq) gets O[q=fr][d=d0*16+kq*4+r] -> packed store
    short* aorow = ao + (tb + qt*16 + fr) * 512 + h*64 + rb;
    if constexpr (WINP / 32 <= 2){
      // hoist P fragments once (d0-invariant); cheap in VGPRs for WIN<=64
      bf16x8 aph[WINP / 32];
      #pragma unroll
      for (int ks = 0; ks < WINP/32; ++ks)
        aph[ks] = *(const bf16x8*)(pl + fr * WINP + ((ks*32 + fk) ^ rxq));
      #pragma unroll
      for (int d0 = 0; d0 < 4; ++d0){
        const int vrow = d0*16 + fr;
        const int vx = ((vrow + (vrow >> 3)) & KMASK) << 3;
        f32x4 o = {0.f, 0.f, 0.f, 0.f};
        #pragma unroll
        for (int ks = 0; ks < WINP/32; ++ks){
          bf16x8 bv = *(const bf16x8*)(vt + vrow * WINP + ((ks*32 + fk) ^ vx));
          o = mfma16(bv, aph[ks], o);
        }
        s16x4 ov;
        ov[0]=f2bf(o[0]); ov[1]=f2bf(o[1]); ov[2]=f2bf(o[2]); ov[3]=f2bf(o[3]);
        *(s16x4*)(aorow + d0*16) = ov;
      }
    } else {
      // WIN=128: reload ap per d0 (keeps VGPR below the 128 cliff)
      #pragma unroll
      for (int d0 = 0; d0 < 4; ++d0){
        const int vrow = d0*16 + fr;
        const int vx = ((vrow + (vrow >> 3)) & KMASK) << 3;
        f32x4 o = {0.f, 0.f, 0.f, 0.f};
        #pragma unroll
        for (int ks = 0; ks < WINP/32; ++ks){
          bf16x8 ap = *(const bf16x8*)(pl + fr * WINP + ((ks*32 + fk) ^ rxq));
          bf16x8 bv = *(const bf16x8*)(vt + vrow * WINP + ((ks*32 + fk) ^ vx));
          o = mfma16(bv, ap, o);
        }
        s16x4 ov;
        ov[0]=f2bf(o[0]); ov[1]=f2bf(o[1]); ov[2]=f2bf(o[2]); ov[3]=f2bf(o[3]);
        *(s16x4*)(aorow + d0*16) = ov;
      }
    }
    // no __syncthreads: smem slices are wave-private; in-wave lgkmcnt ordering suffices
  }
}

// ---------------- host ----------------
extern "C" void kernel_launch(void* const* d_in, const int* in_sizes, int n_in,
                              void* d_out, int out_size, void* d_ws, size_t ws_size,
                              hipStream_t stream){
  const int*   spec   = (const int*)d_in[0];
  const float* emb    = (const float*)d_in[1];
  const float* attn_w = (const float*)d_in[2];
  const float* attn_b = (const float*)d_in[3];
  const float* pw[4]  = {(const float*)d_in[4], (const float*)d_in[6],
                         (const float*)d_in[8], (const float*)d_in[10]};
  const float* pb[4]  = {(const float*)d_in[5], (const float*)d_in[7],
                         (const float*)d_in[9], (const float*)d_in[11]};
  float* out = (float*)d_out;

  // fixed buffers (~135.5 MB): wtq | wcast | wtpc | cbadd | embT | qkvtab
  short* wtq    = (short*)d_ws;             // [4][1536][512] transposed q,k,v
  short* wcast  = wtq + 3145728;            // [4][512][512] Wo cast
  short* wtpc   = wcast + 1048576;          // composed pm weights
  float* cbadd  = (float*)(wtpc + 62914560);// [4][512]
  short* embT   = (short*)(cbadd + 2048);   // [100][512]
  short* qkvtab = embT + 51200;             // [4][100][1536]
  short* dyn    = qkvtab + 614400;

  short* aob  = dyn;                        // [102400][512] bf16 (105 MB)
  float* pbuf = (float*)(aob + (size_t)TOK_TOTAL * 512); // split-K partials (52 MB)
  short* scratch4 = dyn;                    // all 4 pw^T blocks (125.8 MB, prep only;
                                            // aliases aob+pbuf head, dead before attn)

  static const int winv[4]  = {16, 32, 64, 128};
  static const int wpoff[4] = {0, 16*262144, 48*262144, 112*262144};
  static const int roffv[4] = {0, 200, 300, 350};
  static const int wpbv[4]  = {4, 4, 4, 2};  // waves/block: win128 uses 2-wave blocks

  (void)hipFuncSetAttribute(reinterpret_cast<const void*>(gemm256_pm<0>),
                            hipFuncAttributeMaxDynamicSharedMemorySize, 131072);
  (void)hipFuncSetAttribute(reinterpret_cast<const void*>(gemm256_pm<2>),
                            hipFuncAttributeMaxDynamicSharedMemorySize, 131072);

  dim3 tb(32, 8);
  // ---- batched prep (7 launches total) ----
  embcast_k<<<25, 256, 0, stream>>>(emb, embT);
  transpose_wtq<<<dim3(16, 16, 12), tb, 0, stream>>>(attn_w, wtq);
  cast4_k<<<512, 256, 0, stream>>>(attn_w, wcast);
  transpose_pw4<<<dim3(16, 2048, 4), tb, 0, stream>>>(pw[0], pw[1], pw[2], pw[3], scratch4);
  bias_fold4_k<<<2048, 256, 0, stream>>>(scratch4, attn_b, cbadd);
  gemm256_pm<2><<<960, 512, 131072, stream>>>(scratch4, 0, wcast, 512, wtpc, 512, 512, 512);
  gemm_bt<1><<<48, 256, 0, stream>>>(embT, 512, wtq, 512, qkvtab, 1536,
                                     100, 1536, 512, attn_b, 512);

  // ---- main loop: 3 launches per window ----
  for (int i = 0; i < 4; ++i){
    const int win = winv[i];
    const short* tabw = qkvtab + (size_t)i * 153600;
    const int wpb = wpbv[i];
    const int blocks = (TOK_TOTAL / win) * 8 / wpb;
    const int winp = (win < 32) ? 32 : win;
    const size_t shmem = (size_t)wpb * 80 * winp * 2;
    if (win == 16)       attn_g<16 ><<<blocks, wpb*64, shmem, stream>>>(spec, tabw, aob);
    else if (win == 32)  attn_g<32 ><<<blocks, wpb*64, shmem, stream>>>(spec, tabw, aob);
    else if (win == 64)  attn_g<64 ><<<blocks, wpb*64, shmem, stream>>>(spec, tabw, aob);
    else                 attn_g<128><<<blocks, wpb*64, shmem, stream>>>(spec, tabw, aob);
    // patch-merge split-K (kc=2048) via 256^2 pipelined GEMM, then deterministic reduce (+bias)
    const int Kpm = win * 512;
    const int S = Kpm / 2048;
    const int Mc = TOK_TOTAL / win;
    const int mtp = (Mc + 255) >> 8;
    gemm256_pm<0><<<mtp * 2 * S, 512, 131072, stream>>>(aob, Kpm, wtpc + wpoff[i], Kpm,
                                                        pbuf, Mc, 2048, 512);
    reduce_k<<<Mc / 2, 256, 0, stream>>>(pbuf, out, pb[i], cbadd + i*512,
                                         Mc, S, L_SEQ / win, roffv[i]);
  }
}

// Round 10
// 701.361 us; speedup vs baseline: 1.3296x; 1.1062x over previous
//
#include <hip/hip_runtime.h>
#include <hip/hip_bf16.h>
#include <stdint.h>

#define TOK_TOTAL 102400   // 32*3200
#define L_SEQ 3200

typedef __attribute__((ext_vector_type(8))) short bf16x8;
typedef __attribute__((ext_vector_type(4))) short s16x4;
typedef __attribute__((ext_vector_type(2))) short s16x2;
typedef __attribute__((ext_vector_type(4))) float f32x4;

__device__ __forceinline__ short f2bf(float f){
  union { __hip_bfloat16 h; short s; } u;
  u.h = __float2bfloat16(f);
  return u.s;
}

__device__ __forceinline__ f32x4 mfma16(bf16x8 a, bf16x8 b, f32x4 c){
  return __builtin_amdgcn_mfma_f32_16x16x32_bf16(a, b, c, 0, 0, 0);
}

__device__ __forceinline__ void glds16(const short* g, short* l){
  __builtin_amdgcn_global_load_lds((const __attribute__((address_space(1))) unsigned*)g,
                                   (__attribute__((address_space(3))) unsigned*)l, 16, 0, 0);
}

// bijective XCD-chunk swizzle (m204)
__device__ __forceinline__ int xswz(int bid, int nwg){
  int q = nwg >> 3, r = nwg & 7, x = bid & 7, k = bid >> 3;
  return (x < r ? x * (q + 1) : r * (q + 1) + (x - r) * q) + k;
}

// scratch4 layout offset (shorts): windows 16,32,64,128 concatenated pw^T blocks
__device__ __host__ __forceinline__ size_t soff4(int i){
  return (size_t)((16 << i) - 16) * 262144;
}

// ---------------- embT: bf16 embedding table with sqrt(512) folded (100x512) ----------------
__global__ void embcast_k(const float* __restrict__ emb, short* __restrict__ embT){
  int gid = blockIdx.x * 256 + threadIdx.x;     // 6400 threads, 8 elems each
  const float SC = 22.627416997969522f;
  const float4 f0 = ((const float4*)emb)[gid*2];
  const float4 f1 = ((const float4*)emb)[gid*2+1];
  bf16x8 o;
  o[0]=f2bf(f0.x*SC); o[1]=f2bf(f0.y*SC); o[2]=f2bf(f0.z*SC); o[3]=f2bf(f0.w*SC);
  o[4]=f2bf(f1.x*SC); o[5]=f2bf(f1.y*SC); o[6]=f2bf(f1.z*SC); o[7]=f2bf(f1.w*SC);
  *(bf16x8*)(embT + gid*8) = o;
}

// ---------------- batched transpose f32 512x512 -> bf16 512x512 for wtq (12 slices) ---------
__global__ void transpose_wtq(const float* __restrict__ attn_w, short* __restrict__ wtq){
  __shared__ float tile[32][33];
  const int z = blockIdx.z;                     // 0..11 = i*3+j
  const int i = z / 3, j = z - i * 3;
  const float* in = attn_w + (size_t)(i*4 + j) * 262144;
  short* out = wtq + (size_t)z * 262144;
  int c0 = blockIdx.x * 32, r0 = blockIdx.y * 32;
  int tx = threadIdx.x, ty = threadIdx.y;       // 32x8
  #pragma unroll
  for (int k = 0; k < 32; k += 8)
    tile[ty + k][tx] = in[(size_t)(r0 + ty + k) * 512 + c0 + tx];
  __syncthreads();
  const int t = ty * 32 + tx;
  const int c = t >> 3;
  const int r4 = (t & 7) << 2;
  s16x4 o4;
  #pragma unroll
  for (int k = 0; k < 4; ++k) o4[k] = f2bf(tile[r4 + k][c]);
  *(s16x4*)(out + (size_t)(c0 + c) * 512 + r0 + r4) = o4;
}

// ---------------- batched transpose f32 [Kpm,512] -> bf16 [512,Kpm] for pw (4 windows) -------
// v2: flat exact grid (no pad blocks), 128x32 tiles, float4 reads, 256B-run writes.
__global__ __launch_bounds__(256)
void transpose_pw4(const float* __restrict__ p0, const float* __restrict__ p1,
                   const float* __restrict__ p2, const float* __restrict__ p3,
                   short* __restrict__ scratch4){
  __shared__ float tile[128][33];
  int b = blockIdx.x;                           // 15360 = 16 x (64+128+256+512)
  int i, base;
  if (b < 1024){ i = 0; base = 0; }
  else if (b < 3072){ i = 1; base = 1024; }
  else if (b < 7168){ i = 2; base = 3072; }
  else { i = 3; base = 7168; }
  const int local = b - base;
  const int rt = local >> 4;                    // r-tile of 128 rows
  const int ct = local & 15;                    // c-tile of 32 cols
  const float* in = (i == 0) ? p0 : (i == 1) ? p1 : (i == 2) ? p2 : p3;
  short* out = scratch4 + soff4(i);
  const int R = (16 << i) << 9;
  const int r0 = rt << 7, c0 = ct << 5;
  const int t = threadIdx.x;
  // read: 128 rows x 32 f32, float4 per thread (8 threads/row)
  const int rr = t >> 3;                        // 0..31
  const int cc = (t & 7) << 2;
  #pragma unroll
  for (int k = 0; k < 128; k += 32){
    const float4 v = *(const float4*)(in + (size_t)(r0 + rr + k) * 512 + c0 + cc);
    tile[rr + k][cc] = v.x; tile[rr + k][cc + 1] = v.y;
    tile[rr + k][cc + 2] = v.z; tile[rr + k][cc + 3] = v.w;
  }
  __syncthreads();
  // write: 32 cols x 128 r as s16x4 (256B contiguous run per column)
  const int c = t >> 3;
  #pragma unroll
  for (int j = 0; j < 4; ++j){
    const int r = j * 32 + (t & 7) * 4;
    s16x4 o4;
    o4[0] = f2bf(tile[r][c]);     o4[1] = f2bf(tile[r + 1][c]);
    o4[2] = f2bf(tile[r + 2][c]); o4[3] = f2bf(tile[r + 3][c]);
    *(s16x4*)(out + (size_t)(c0 + c) * R + r0 + r) = o4;
  }
}

// ---------------- batched cast f32 -> bf16 of 4 Wo matrices ----------------
__global__ void cast4_k(const float* __restrict__ attn_w, short* __restrict__ wcast){
  int gid = blockIdx.x * 256 + threadIdx.x;     // 131072 threads, 8 elems each
  const int i = gid >> 15;                      // 32768 groups per 512x512 matrix
  const int off = (gid & 32767) * 8;
  const float* in = attn_w + (size_t)(i*4 + 3) * 262144 + off;
  const float4 f0 = ((const float4*)in)[0];
  const float4 f1 = ((const float4*)in)[1];
  bf16x8 o;
  o[0]=f2bf(f0.x); o[1]=f2bf(f0.y); o[2]=f2bf(f0.z); o[3]=f2bf(f0.w);
  o[4]=f2bf(f1.x); o[5]=f2bf(f1.y); o[6]=f2bf(f1.z); o[7]=f2bf(f1.w);
  *(bf16x8*)(wcast + (size_t)i * 262144 + off) = o;
}

// ---------------- batched bias fold: cbadd[i][j] = sum_r bo_i[r&511] * pwT_i[j][r] ----------
// v2: bf16x8 vectorized row reads.
__global__ void bias_fold4_k(const short* __restrict__ scratch4, const float* __restrict__ attn_b,
                             float* __restrict__ cbadd){
  const int i = blockIdx.x >> 9;
  const int j = blockIdx.x & 511;
  const int Kpm = (16 << i) << 9;
  const short* row = scratch4 + soff4(i) + (size_t)j * Kpm;
  const float* bo = attn_b + i * 2048 + 1536;
  float s = 0.f;
  for (int r = threadIdx.x * 8; r < Kpm; r += 2048){
    const bf16x8 v = *(const bf16x8*)(row + r);
    const int b0 = r & 511;
    #pragma unroll
    for (int e = 0; e < 8; ++e){
      union { unsigned u; float f; } c; c.u = ((unsigned)(unsigned short)v[e]) << 16;
      s += c.f * bo[b0 + e];
    }
  }
  s += __shfl_xor(s, 1);  s += __shfl_xor(s, 2);  s += __shfl_xor(s, 4);
  s += __shfl_xor(s, 8);  s += __shfl_xor(s, 16); s += __shfl_xor(s, 32);
  __shared__ float red[4];
  if ((threadIdx.x & 63) == 0) red[threadIdx.x >> 6] = s;
  __syncthreads();
  if (threadIdx.x == 0) cbadd[i * 512 + j] = red[0] + red[1] + red[2] + red[3];
}

// ---------------- split-K reduce + bias, float4 (writes each out element exactly once) --------
__global__ void reduce_k(const float* __restrict__ part, float* __restrict__ out,
                         const float* __restrict__ pb, const float* __restrict__ cb,
                         int Mc, int S, int rpb, int roff){
  int gid = blockIdx.x * 256 + threadIdx.x;     // Mc*128 threads
  int c4 = (gid & 127) << 2;
  int rr = gid >> 7;
  float4 s = *(const float4*)(pb + c4);
  const float4 cv = *(const float4*)(cb + c4);
  s.x += cv.x; s.y += cv.y; s.z += cv.z; s.w += cv.w;
  const float* p = part + (size_t)rr * 512 + c4;
  const size_t stride = (size_t)Mc * 512;
  for (int k = 0; k < S; ++k){
    const float4 v = *(const float4*)(p + (size_t)k * stride);
    s.x += v.x; s.y += v.y; s.z += v.z; s.w += v.w;
  }
  int ob = rr / rpb;
  int orow = rr - ob * rpb;
  *(float4*)(out + (size_t)(ob * 375 + roff + orow) * 512 + c4) = s;
}

// ---------------- 128^2 GEMM C = A[M,K] @ Bt[N,K]^T, BK=64, swizzled LDS ----------------
// bf16 store + f32 bias. B4=1: batched over 4 windows (grid 48 = 4 x 12 N-tiles),
// per-window Bt/C/bias offsets decoded in-kernel (qkvtab precompute).
template<int B4>
__global__ __launch_bounds__(256)
void gemm_bt(const short* __restrict__ A, int lda,
             const short* __restrict__ Bt, int ldb,
             void* __restrict__ Cv, int ldc,
             int M, int N, int K,
             const float* __restrict__ bias,
             int kc)
{
  __shared__ short alds[8192];   // [128][64]
  __shared__ short blds[8192];

  const int t = threadIdx.x;
  int wg = xswz(blockIdx.x, gridDim.x);
  if (B4){
    const int i = wg / 12; wg -= i * 12;
    Bt += (size_t)i * 3 * 262144;
    Cv = (void*)((short*)Cv + (size_t)i * 153600);
    bias += i * 2048;
  }
  const int Mt = (M + 127) >> 7;
  const int Nt = N >> 7;
  const int bn = wg % Nt; wg /= Nt;
  const int bm = wg % Mt; wg /= Mt;
  const int ksp = wg;
  int kbeg = ksp * kc, kend = kbeg + kc; if (kend > K) kend = K;

  const int srow = t >> 3;                      // 0..31
  const int scol = (t & 7) << 3;
  const int scolz = scol ^ ((srow & 7) << 3);   // swizzled SOURCE column (m173)
  const short* ga[4]; const short* gb[4];
  #pragma unroll
  for (int p = 0; p < 4; ++p){
    int arow = bm*128 + srow + p*32; if (arow >= M) arow = M - 1;
    ga[p] = A + (size_t)arow * lda + kbeg + scolz;
    gb[p] = Bt + (size_t)(bn*128 + srow + p*32) * ldb + kbeg + scolz;
  }
  short* la = alds + t * 8;
  short* lb = blds + t * 8;

  const int wave = t >> 6;
  const int lane = t & 63;
  const int wm = (wave >> 1) << 6;
  const int wn = (wave & 1) << 6;
  const int fr = lane & 15;
  const int fk = (lane >> 4) << 3;
  const int fx = (fr & 7) << 3;

  f32x4 acc[4][4] = {};

  for (int kt = kbeg; kt < kend; kt += 64) {
    #pragma unroll
    for (int p = 0; p < 4; ++p){
      glds16(ga[p], la + p*2048);
      glds16(gb[p], lb + p*2048);
      ga[p] += 64; gb[p] += 64;
    }
    __syncthreads();
    bf16x8 af[2][4], bfr[2][4];
    #pragma unroll
    for (int ks = 0; ks < 2; ++ks){
      const int kcz = (ks*32 + fk) ^ fx;
      #pragma unroll
      for (int m = 0; m < 4; ++m) af[ks][m] = *(const bf16x8*)(alds + (wm + m*16 + fr)*64 + kcz);
      #pragma unroll
      for (int n = 0; n < 4; ++n) bfr[ks][n] = *(const bf16x8*)(blds + (wn + n*16 + fr)*64 + kcz);
    }
    #pragma unroll
    for (int ks = 0; ks < 2; ++ks)
      #pragma unroll
      for (int m = 0; m < 4; ++m)
        #pragma unroll
        for (int n = 0; n < 4; ++n)
          acc[m][n] = mfma16(af[ks][m], bfr[ks][n], acc[m][n]);
    __syncthreads();
  }

  const int rb = (lane >> 4) << 2;
  short* C = (short*)Cv;
  #pragma unroll
  for (int m = 0; m < 4; ++m){
    const int row0 = bm*128 + wm + m*16 + rb;
    #pragma unroll
    for (int n = 0; n < 4; ++n){
      const int col = bn*128 + wn + n*16 + fr;
      const float bv = bias[col];
      #pragma unroll
      for (int r = 0; r < 4; ++r){
        const int rr = row0 + r;
        if (rr < M) C[(size_t)rr * ldc + col] = f2bf(acc[m][n][r] + bv);
      }
    }
  }
}

// ---------------- 256^2 deep-pipelined GEMM (T2+T3+T4+T5) ----------------
// MODE 0 (split-K patch-merge): Cpart[ksp][M][512] = A[M,lda] @ Bt[512,ldb]^T over
//        K-slice [ksp*kc, +kc), f32 partial store.
// MODE 2 (batched compose, 4 windows in one launch, grid 960 = 64+128+256+512):
//        per window i, batch p: C[j][p*512+c] = sum_m A[j][p*512+m] * Bt[c][m];
//        offsets decoded in-kernel; bf16 store.
// 512 thr = 8 waves (2Mx4N), per-wave C 128x64, BK=64, LDS 128 KiB = 2 dbuf x (A|B).
// 4 phases per K-tile; counted vmcnt (6)/(8), never drained in main loop.
template<int MODE>
__global__ __launch_bounds__(512, 2)
void gemm256_pm(const short* __restrict__ A, int lda,
                const short* __restrict__ Bt, int ldb,
                void* __restrict__ Cv, int M, int kc, int ldc)
{
  extern __shared__ short lds_s[];
  const int tid = threadIdx.x;
  int wg = xswz(blockIdx.x, gridDim.x);
  int bn, bm, ksp, kbeg, kbegB;
  if (MODE == 2){
    int i, base;
    if (wg < 64){ i = 0; base = 0; }
    else if (wg < 192){ i = 1; base = 64; }
    else if (wg < 448){ i = 2; base = 192; }
    else { i = 3; base = 448; }
    const int local = wg - base;
    bn = local & 1; bm = (local >> 1) & 1; ksp = local >> 2;   // p = 512-col batch
    const int Kpm = (16 << i) << 9;
    const size_t so = soff4(i);
    A += so; lda = Kpm;
    Bt += (size_t)i * 262144;
    Cv = (void*)((short*)Cv + so); ldc = Kpm;
    M = 512; kc = 512;
    kbeg = ksp << 9; kbegB = 0;
  } else {
    bn = wg & 1; wg >>= 1;
    const int Mt = (M + 255) >> 8;
    bm = wg % Mt; ksp = wg / Mt;
    kbeg = ksp * kc; kbegB = kbeg;
  }

  const int wave = tid >> 6, lane = tid & 63;
  const int wm = wave >> 2, wn = wave & 3;   // 2M x 4N waves
  const int fr = lane & 15, kq = lane >> 4;
  const int fx = fr & 7;
  const int sx0 = (kq ^ fx) << 3;            // swizzled 16B slot, ks=0 (shorts)
  const int sx1 = ((4 + kq) ^ fx) << 3;      // ks=1
  const int aoff = (wm * 64 + fr) << 6;      // phys A row * 64 shorts
  const int boff = (wn * 32 + fr) << 6;

  const int sr = tid >> 3;
  const int kg = ((tid & 7) ^ (sr & 7)) << 3;
  const short* srcA[2][2]; const short* srcB[2][2];
  #pragma unroll
  for (int h = 0; h < 2; ++h)
    #pragma unroll
    for (int u = 0; u < 2; ++u){
      int r = bm * 256 + u * 128 + h * 64 + sr; if (r >= M) r = M - 1;
      srcA[h][u] = A + (size_t)r * lda + kbeg + kg;
      const int br = (u * 2 + (sr >> 5)) * 64 + h * 32 + (sr & 31);
      srcB[h][u] = Bt + (size_t)(bn * 256 + br) * ldb + kbegB + kg;
    }

#define STG_A(dst, h, ko) do { \
    glds16(srcA[h][0] + (ko), (dst) + (h)*8192 + tid*8); \
    glds16(srcA[h][1] + (ko), (dst) + (h)*8192 + 4096 + tid*8); } while(0)
#define STG_B(dst, h, ko) do { \
    glds16(srcB[h][0] + (ko), (dst) + 16384 + (h)*8192 + tid*8); \
    glds16(srcB[h][1] + (ko), (dst) + 16384 + (h)*8192 + 4096 + tid*8); } while(0)

  short* Lc = lds_s;
  short* Ln = lds_s + 32768;

  f32x4 acc[8][4] = {};
  bf16x8 af[4][2], b0[2][2], b1[2][2];

  STG_A(Lc, 0, 0);  STG_B(Lc, 0, 0);
  STG_A(Lc, 1, 0);  STG_B(Lc, 1, 0);
  STG_A(Ln, 0, 64); STG_B(Ln, 0, 64);
  asm volatile("s_waitcnt vmcnt(8)" ::: "memory");
  __builtin_amdgcn_s_barrier();

  const int T = kc >> 6;
  for (int t = 0; t < T; ++t){
    const int k1 = ((t + 1 < T) ? t + 1 : T - 1) << 6;
    const int k2 = ((t + 2 < T) ? t + 2 : T - 1) << 6;
    // ---- phase 0
    #pragma unroll
    for (int m = 0; m < 4; ++m){
      af[m][0] = *(const bf16x8*)(Lc + aoff + m*1024 + sx0);
      af[m][1] = *(const bf16x8*)(Lc + aoff + m*1024 + sx1);
    }
    #pragma unroll
    for (int n = 0; n < 2; ++n){
      b0[n][0] = *(const bf16x8*)(Lc + 16384 + boff + n*1024 + sx0);
      b0[n][1] = *(const bf16x8*)(Lc + 16384 + boff + n*1024 + sx1);
    }
    STG_A(Ln, 1, k1);
    __builtin_amdgcn_s_barrier();
    asm volatile("s_waitcnt lgkmcnt(0)");
    __builtin_amdgcn_s_setprio(1);
    #pragma unroll
    for (int m = 0; m < 4; ++m)
      #pragma unroll
      for (int n = 0; n < 2; ++n){
        acc[m][n] = mfma16(af[m][0], b0[n][0], acc[m][n]);
        acc[m][n] = mfma16(af[m][1], b0[n][1], acc[m][n]);
      }
    __builtin_amdgcn_s_setprio(0);
    asm volatile("s_waitcnt vmcnt(6)" ::: "memory");
    __builtin_amdgcn_s_barrier();
    // ---- phase 1
    #pragma unroll
    for (int n = 0; n < 2; ++n){
      b1[n][0] = *(const bf16x8*)(Lc + 24576 + boff + n*1024 + sx0);
      b1[n][1] = *(const bf16x8*)(Lc + 24576 + boff + n*1024 + sx1);
    }
    STG_B(Ln, 1, k1);
    __builtin_amdgcn_s_barrier();
    asm volatile("s_waitcnt lgkmcnt(0)");
    __builtin_amdgcn_s_setprio(1);
    #pragma unroll
    for (int m = 0; m < 4; ++m)
      #pragma unroll
      for (int n = 0; n < 2; ++n){
        acc[m][2+n] = mfma16(af[m][0], b1[n][0], acc[m][2+n]);
        acc[m][2+n] = mfma16(af[m][1], b1[n][1], acc[m][2+n]);
      }
    __builtin_amdgcn_s_setprio(0);
    __builtin_amdgcn_s_barrier();
    // ---- phase 2
    #pragma unroll
    for (int m = 0; m < 4; ++m){
      af[m][0] = *(const bf16x8*)(Lc + 8192 + aoff + m*1024 + sx0);
      af[m][1] = *(const bf16x8*)(Lc + 8192 + aoff + m*1024 + sx1);
    }
    STG_A(Lc, 0, k2);
    __builtin_amdgcn_s_barrier();
    asm volatile("s_waitcnt lgkmcnt(0)");
    __builtin_amdgcn_s_setprio(1);
    #pragma unroll
    for (int m = 0; m < 4; ++m)
      #pragma unroll
      for (int n = 0; n < 2; ++n){
        acc[4+m][n] = mfma16(af[m][0], b0[n][0], acc[4+m][n]);
        acc[4+m][n] = mfma16(af[m][1], b0[n][1], acc[4+m][n]);
      }
    __builtin_amdgcn_s_setprio(0);
    __builtin_amdgcn_s_barrier();
    // ---- phase 3
    STG_B(Lc, 0, k2);
    __builtin_amdgcn_s_barrier();
    __builtin_amdgcn_s_setprio(1);
    #pragma unroll
    for (int m = 0; m < 4; ++m)
      #pragma unroll
      for (int n = 0; n < 2; ++n){
        acc[4+m][2+n] = mfma16(af[m][0], b1[n][0], acc[4+m][2+n]);
        acc[4+m][2+n] = mfma16(af[m][1], b1[n][1], acc[4+m][2+n]);
      }
    __builtin_amdgcn_s_setprio(0);
    asm volatile("s_waitcnt vmcnt(8)" ::: "memory");
    __builtin_amdgcn_s_barrier();
    short* tp = Lc; Lc = Ln; Ln = tp;
  }
#undef STG_A
#undef STG_B

  const int rb4 = kq << 2;
  if (MODE == 0){
    float* Cp = (float*)Cv + (size_t)ksp * M * 512;
    #pragma unroll
    for (int mh = 0; mh < 2; ++mh)
      #pragma unroll
      for (int m = 0; m < 4; ++m){
        const int row0 = bm*256 + wm*128 + mh*64 + m*16 + rb4;
        #pragma unroll
        for (int r = 0; r < 4; ++r){
          const int rr = row0 + r;
          if (rr < M){
            float* Crow = Cp + (size_t)rr * 512 + bn*256 + wn*64 + fr;
            #pragma unroll
            for (int nh = 0; nh < 2; ++nh)
              #pragma unroll
              for (int n = 0; n < 2; ++n)
                Crow[nh*32 + n*16] = acc[mh*4+m][nh*2+n][r];
          }
        }
      }
  } else {
    // compose: bf16 store to C[j][kbeg + c], ldc = Kpm
    short* Cs = (short*)Cv;
    #pragma unroll
    for (int mh = 0; mh < 2; ++mh)
      #pragma unroll
      for (int m = 0; m < 4; ++m){
        const int row0 = bm*256 + wm*128 + mh*64 + m*16 + rb4;
        #pragma unroll
        for (int r = 0; r < 4; ++r){
          const int rr = row0 + r;
          if (rr < M){
            short* Crow = Cs + (size_t)rr * ldc + kbeg + bn*256 + wn*64 + fr;
            #pragma unroll
            for (int nh = 0; nh < 2; ++nh)
              #pragma unroll
              for (int n = 0; n < 2; ++n)
                Crow[nh*32 + n*16] = f2bf(acc[mh*4+m][nh*2+n][r]);
          }
        }
      }
  }
}

// ---------------- table-gather windowed MHA: one wave per (window-instance, head) ------------
// tab: [100][1536] bf16 per window (Q|K|V rows per vocab value, bias folded).
// v11: swapped QK^T (in-lane softmax), packed P/V/O stores, conflict-spreading
//      swizzle key, waves-per-block from blockDim (win128 uses 2-wave blocks).
template<int WIN>
__global__ __launch_bounds__(256)
void attn_g(const int* __restrict__ spec, const short* __restrict__ tab,
            short* __restrict__ ao){
  constexpr int WINP = (WIN < 32) ? 32 : WIN;     // padded k-dim
  constexpr int KMASK = WINP / 8 - 1;             // in-row swizzle key clamp
  constexpr int NT = WIN / 16;
  extern __shared__ short smem[];                 // per wave: Vt[64][WINP] + P[16][WINP]
  const int lane = threadIdx.x & 63;
  const int w = threadIdx.x >> 6;
  const int wpb = (int)(blockDim.x >> 6);
  const int wh = blockIdx.x * wpb + w;
  const int wid = wh >> 3, h = wh & 7;
  const size_t tb = (size_t)wid * WIN;
  short* vt = smem + w * 80 * WINP;
  short* pl = vt + 64 * WINP;

  const int fr = lane & 15;
  const int fk = (lane >> 4) << 3;
  const int kq = lane >> 4;
  const int rb = kq << 2;

  // ---- V^T staging: (KRUN k x 8 d) cells, packed LDS writes.
  // element (d,k) -> vt[d*WINP + (k ^ key(d))], key(x) = ((x + (x>>3)) & KMASK) << 3
  {
    constexpr int KRUN = (WIN >= 32) ? 4 : 2;
    constexpr int ITER = (WIN / KRUN) * 8 / 64;   // 1,1,2,4
    const int dgrp = lane & 7;
    #pragma unroll
    for (int it = 0; it < ITER; ++it){
      const int kb = ((lane >> 3) + it * 8) * KRUN;
      bf16x8 vv[KRUN];
      #pragma unroll
      for (int kk = 0; kk < KRUN; ++kk)
        vv[kk] = *(const bf16x8*)(tab + (size_t)spec[tb + kb + kk] * 1536 + 1024 + h * 64 + dgrp * 8);
      #pragma unroll
      for (int j = 0; j < 8; ++j){
        const int d = dgrp * 8 + j;
        const int key = ((d + (d >> 3)) & KMASK) << 3;
        short* dst = vt + d * WINP + (kb ^ key);
        if constexpr (KRUN == 4){
          s16x4 wv; wv[0]=vv[0][j]; wv[1]=vv[1][j]; wv[2]=vv[2][j]; wv[3]=vv[3][j];
          *(s16x4*)dst = wv;
        } else {
          s16x2 wv; wv[0]=vv[0][j]; wv[1]=vv[1][j];
          *(s16x2*)dst = wv;
        }
      }
    }
  }
  if constexpr (WIN == 16){
    // zero-fill V^T pad (logical k=16..31 of every d-row): uninitialized LDS may
    // hold NaN bf16 patterns and 0*NaN = NaN. lane == d (64 lanes, 64 rows).
    const int d = lane;
    const int key = ((d + (d >> 3)) & KMASK) << 3;
    short* vrow_ = vt + d * WINP;
    const s16x4 z = {0, 0, 0, 0};
    #pragma unroll
    for (int kk = 16; kk < 32; kk += 4)
      *(s16x4*)(vrow_ + (kk ^ key)) = z;
  }

  // ---- hoisted K row pointers; K fragments in regs for NT<=4
  const short* kp8[NT];
  #pragma unroll
  for (int nt = 0; nt < NT; ++nt)
    kp8[nt] = tab + (size_t)spec[tb + nt*16 + fr] * 1536 + 512 + h*64 + fk;

  bf16x8 bkh[(NT <= 4) ? NT : 1][2];
  if constexpr (NT <= 4){
    #pragma unroll
    for (int nt = 0; nt < NT; ++nt){
      bkh[nt][0] = *(const bf16x8*)(kp8[nt]);
      bkh[nt][1] = *(const bf16x8*)(kp8[nt] + 32);
    }
  }

  const int rxq = ((fr + (fr >> 3)) & KMASK) << 3; // P-row swizzle key (row = q = fr)
  short* plq = pl + fr * WINP;

  for (int qt = 0; qt < NT; ++qt){
    // Q row token == K row token for the same (tile, fr): reuse pointer, offset -512
    const short* qrow = kp8[qt] - 512;
    bf16x8 aq0 = *(const bf16x8*)(qrow);
    bf16x8 aq1 = *(const bf16x8*)(qrow + 32);
    float s[NT][4];
    #pragma unroll
    for (int nt = 0; nt < NT; ++nt){
      bf16x8 k0, k1;
      if constexpr (NT <= 4){ k0 = bkh[nt][0]; k1 = bkh[nt][1]; }
      else { k0 = *(const bf16x8*)(kp8[nt]); k1 = *(const bf16x8*)(kp8[nt] + 32); }
      f32x4 c = {0.f, 0.f, 0.f, 0.f};
      c = mfma16(k0, aq0, c);                     // swapped: C[k_local][q = lane&15]
      c = mfma16(k1, aq1, c);
      #pragma unroll
      for (int r = 0; r < 4; ++r) s[nt][r] = c[r] * 0.125f;
    }
    // in-lane softmax for q = fr: tree max/sum over 4*NT values + 2 shfls each
    float mm[NT];
    #pragma unroll
    for (int nt = 0; nt < NT; ++nt)
      mm[nt] = fmaxf(fmaxf(s[nt][0], s[nt][1]), fmaxf(s[nt][2], s[nt][3]));
    #pragma unroll
    for (int st = NT >> 1; st >= 1; st >>= 1)
      #pragma unroll
      for (int i = 0; i < st; ++i) mm[i] = fmaxf(mm[i], mm[i + st]);
    float m = mm[0];
    m = fmaxf(m, __shfl_xor(m, 16));
    m = fmaxf(m, __shfl_xor(m, 32));
    float ss[NT];
    #pragma unroll
    for (int nt = 0; nt < NT; ++nt){
      #pragma unroll
      for (int r = 0; r < 4; ++r) s[nt][r] = __expf(s[nt][r] - m);
      ss[nt] = (s[nt][0] + s[nt][1]) + (s[nt][2] + s[nt][3]);
    }
    #pragma unroll
    for (int st = NT >> 1; st >= 1; st >>= 1)
      #pragma unroll
      for (int i = 0; i < st; ++i) ss[i] += ss[i + st];
    float sum = ss[0];
    sum += __shfl_xor(sum, 16);
    sum += __shfl_xor(sum, 32);
    const float inv = 1.f / sum;
    // packed P store: lane owns k = nt*16 + rb + 0..3 of row q=fr (contiguous, b64)
    #pragma unroll
    for (int nt = 0; nt < NT; ++nt){
      s16x4 pw;
      pw[0] = f2bf(s[nt][0] * inv); pw[1] = f2bf(s[nt][1] * inv);
      pw[2] = f2bf(s[nt][2] * inv); pw[3] = f2bf(s[nt][3] * inv);
      *(s16x4*)(plq + ((nt*16 + rb) ^ rxq)) = pw;
    }
    if (WIN == 16){
      s16x4 pz = {0, 0, 0, 0};
      *(s16x4*)(plq + ((16 + rb) ^ rxq)) = pz;
    }
    // PV with swapped operands: lane (fr,kq) gets O[q=fr][d=d0*16+kq*4+r] -> packed store
    short* aorow = ao + (tb + qt*16 + fr) * 512 + h*64 + rb;
    if constexpr (WINP / 32 <= 2){
      // hoist P fragments once (d0-invariant); cheap in VGPRs for WIN<=64
      bf16x8 aph[WINP / 32];
      #pragma unroll
      for (int ks = 0; ks < WINP/32; ++ks)
        aph[ks] = *(const bf16x8*)(pl + fr * WINP + ((ks*32 + fk) ^ rxq));
      #pragma unroll
      for (int d0 = 0; d0 < 4; ++d0){
        const int vrow = d0*16 + fr;
        const int vx = ((vrow + (vrow >> 3)) & KMASK) << 3;
        f32x4 o = {0.f, 0.f, 0.f, 0.f};
        #pragma unroll
        for (int ks = 0; ks < WINP/32; ++ks){
          bf16x8 bv = *(const bf16x8*)(vt + vrow * WINP + ((ks*32 + fk) ^ vx));
          o = mfma16(bv, aph[ks], o);
        }
        s16x4 ov;
        ov[0]=f2bf(o[0]); ov[1]=f2bf(o[1]); ov[2]=f2bf(o[2]); ov[3]=f2bf(o[3]);
        *(s16x4*)(aorow + d0*16) = ov;
      }
    } else {
      // WIN=128: reload ap per d0 (keeps VGPR below the 128 cliff)
      #pragma unroll
      for (int d0 = 0; d0 < 4; ++d0){
        const int vrow = d0*16 + fr;
        const int vx = ((vrow + (vrow >> 3)) & KMASK) << 3;
        f32x4 o = {0.f, 0.f, 0.f, 0.f};
        #pragma unroll
        for (int ks = 0; ks < WINP/32; ++ks){
          bf16x8 ap = *(const bf16x8*)(pl + fr * WINP + ((ks*32 + fk) ^ rxq));
          bf16x8 bv = *(const bf16x8*)(vt + vrow * WINP + ((ks*32 + fk) ^ vx));
          o = mfma16(bv, ap, o);
        }
        s16x4 ov;
        ov[0]=f2bf(o[0]); ov[1]=f2bf(o[1]); ov[2]=f2bf(o[2]); ov[3]=f2bf(o[3]);
        *(s16x4*)(aorow + d0*16) = ov;
      }
    }
    // no __syncthreads: smem slices are wave-private; in-wave lgkmcnt ordering suffices
  }
}

// ---------------- host ----------------
extern "C" void kernel_launch(void* const* d_in, const int* in_sizes, int n_in,
                              void* d_out, int out_size, void* d_ws, size_t ws_size,
                              hipStream_t stream){
  const int*   spec   = (const int*)d_in[0];
  const float* emb    = (const float*)d_in[1];
  const float* attn_w = (const float*)d_in[2];
  const float* attn_b = (const float*)d_in[3];
  const float* pw[4]  = {(const float*)d_in[4], (const float*)d_in[6],
                         (const float*)d_in[8], (const float*)d_in[10]};
  const float* pb[4]  = {(const float*)d_in[5], (const float*)d_in[7],
                         (const float*)d_in[9], (const float*)d_in[11]};
  float* out = (float*)d_out;

  // fixed buffers (~135.5 MB): wtq | wcast | wtpc | cbadd | embT | qkvtab
  short* wtq    = (short*)d_ws;             // [4][1536][512] transposed q,k,v
  short* wcast  = wtq + 3145728;            // [4][512][512] Wo cast
  short* wtpc   = wcast + 1048576;          // composed pm weights
  float* cbadd  = (float*)(wtpc + 62914560);// [4][512]
  short* embT   = (short*)(cbadd + 2048);   // [100][512]
  short* qkvtab = embT + 51200;             // [4][100][1536]
  short* dyn    = qkvtab + 614400;

  short* aob  = dyn;                        // [102400][512] bf16 (105 MB)
  float* pbuf = (float*)(aob + (size_t)TOK_TOTAL * 512); // split-K partials (52 MB)
  short* scratch4 = dyn;                    // all 4 pw^T blocks (125.8 MB, prep only;
                                            // aliases aob+pbuf head, dead before attn)

  static const int winv[4]  = {16, 32, 64, 128};
  static const int wpoff[4] = {0, 16*262144, 48*262144, 112*262144};
  static const int roffv[4] = {0, 200, 300, 350};
  static const int wpbv[4]  = {4, 4, 4, 2};  // waves/block: win128 uses 2-wave blocks

  (void)hipFuncSetAttribute(reinterpret_cast<const void*>(gemm256_pm<0>),
                            hipFuncAttributeMaxDynamicSharedMemorySize, 131072);
  (void)hipFuncSetAttribute(reinterpret_cast<const void*>(gemm256_pm<2>),
                            hipFuncAttributeMaxDynamicSharedMemorySize, 131072);

  dim3 tb(32, 8);
  // ---- batched prep (7 launches total) ----
  embcast_k<<<25, 256, 0, stream>>>(emb, embT);
  transpose_wtq<<<dim3(16, 16, 12), tb, 0, stream>>>(attn_w, wtq);
  cast4_k<<<512, 256, 0, stream>>>(attn_w, wcast);
  transpose_pw4<<<15360, 256, 0, stream>>>(pw[0], pw[1], pw[2], pw[3], scratch4);
  bias_fold4_k<<<2048, 256, 0, stream>>>(scratch4, attn_b, cbadd);
  gemm256_pm<2><<<960, 512, 131072, stream>>>(scratch4, 0, wcast, 512, wtpc, 512, 512, 512);
  gemm_bt<1><<<48, 256, 0, stream>>>(embT, 512, wtq, 512, qkvtab, 1536,
                                     100, 1536, 512, attn_b, 512);

  // ---- main loop: 3 launches per window ----
  for (int i = 0; i < 4; ++i){
    const int win = winv[i];
    const short* tabw = qkvtab + (size_t)i * 153600;
    const int wpb = wpbv[i];
    const int blocks = (TOK_TOTAL / win) * 8 / wpb;
    const int winp = (win < 32) ? 32 : win;
    const size_t shmem = (size_t)wpb * 80 * winp * 2;
    if (win == 16)       attn_g<16 ><<<blocks, wpb*64, shmem, stream>>>(spec, tabw, aob);
    else if (win == 32)  attn_g<32 ><<<blocks, wpb*64, shmem, stream>>>(spec, tabw, aob);
    else if (win == 64)  attn_g<64 ><<<blocks, wpb*64, shmem, stream>>>(spec, tabw, aob);
    else                 attn_g<128><<<blocks, wpb*64, shmem, stream>>>(spec, tabw, aob);
    // patch-merge split-K (kc=2048) via 256^2 pipelined GEMM, then deterministic reduce (+bias)
    const int Kpm = win * 512;
    const int S = Kpm / 2048;
    const int Mc = TOK_TOTAL / win;
    const int mtp = (Mc + 255) >> 8;
    gemm256_pm<0><<<mtp * 2 * S, 512, 131072, stream>>>(aob, Kpm, wtpc + wpoff[i], Kpm,
                                                        pbuf, Mc, 2048, 512);
    reduce_k<<<Mc / 2, 256, 0, stream>>>(pbuf, out, pb[i], cbadd + i*512,
                                         Mc, S, L_SEQ / win, roffv[i]);
  }
}

// Round 11
// 698.253 us; speedup vs baseline: 1.3356x; 1.0044x over previous
//
#include <hip/hip_runtime.h>
#include <hip/hip_bf16.h>
#include <stdint.h>

#define TOK_TOTAL 102400   // 32*3200
#define L_SEQ 3200

typedef __attribute__((ext_vector_type(8))) short bf16x8;
typedef __attribute__((ext_vector_type(4))) short s16x4;
typedef __attribute__((ext_vector_type(2))) short s16x2;
typedef __attribute__((ext_vector_type(4))) float f32x4;

__device__ __forceinline__ short f2bf(float f){
  union { __hip_bfloat16 h; short s; } u;
  u.h = __float2bfloat16(f);
  return u.s;
}

__device__ __forceinline__ f32x4 mfma16(bf16x8 a, bf16x8 b, f32x4 c){
  return __builtin_amdgcn_mfma_f32_16x16x32_bf16(a, b, c, 0, 0, 0);
}

__device__ __forceinline__ void glds16(const short* g, short* l){
  __builtin_amdgcn_global_load_lds((const __attribute__((address_space(1))) unsigned*)g,
                                   (__attribute__((address_space(3))) unsigned*)l, 16, 0, 0);
}

// bijective XCD-chunk swizzle (m204)
__device__ __forceinline__ int xswz(int bid, int nwg){
  int q = nwg >> 3, r = nwg & 7, x = bid & 7, k = bid >> 3;
  return (x < r ? x * (q + 1) : r * (q + 1) + (x - r) * q) + k;
}

// scratch4 layout offset (shorts): windows 16,32,64,128 concatenated pw^T blocks
__device__ __host__ __forceinline__ size_t soff4(int i){
  return (size_t)((16 << i) - 16) * 262144;
}

// ---------------- embT: bf16 embedding table with sqrt(512) folded (100x512) ----------------
__global__ void embcast_k(const float* __restrict__ emb, short* __restrict__ embT){
  int gid = blockIdx.x * 256 + threadIdx.x;     // 6400 threads, 8 elems each
  const float SC = 22.627416997969522f;
  const float4 f0 = ((const float4*)emb)[gid*2];
  const float4 f1 = ((const float4*)emb)[gid*2+1];
  bf16x8 o;
  o[0]=f2bf(f0.x*SC); o[1]=f2bf(f0.y*SC); o[2]=f2bf(f0.z*SC); o[3]=f2bf(f0.w*SC);
  o[4]=f2bf(f1.x*SC); o[5]=f2bf(f1.y*SC); o[6]=f2bf(f1.z*SC); o[7]=f2bf(f1.w*SC);
  *(bf16x8*)(embT + gid*8) = o;
}

// ---------------- batched transpose f32 512x512 -> bf16 512x512 for wtq (12 slices) ---------
__global__ void transpose_wtq(const float* __restrict__ attn_w, short* __restrict__ wtq){
  __shared__ float tile[32][33];
  const int z = blockIdx.z;                     // 0..11 = i*3+j
  const int i = z / 3, j = z - i * 3;
  const float* in = attn_w + (size_t)(i*4 + j) * 262144;
  short* out = wtq + (size_t)z * 262144;
  int c0 = blockIdx.x * 32, r0 = blockIdx.y * 32;
  int tx = threadIdx.x, ty = threadIdx.y;       // 32x8
  #pragma unroll
  for (int k = 0; k < 32; k += 8)
    tile[ty + k][tx] = in[(size_t)(r0 + ty + k) * 512 + c0 + tx];
  __syncthreads();
  const int t = ty * 32 + tx;
  const int c = t >> 3;
  const int r4 = (t & 7) << 2;
  s16x4 o4;
  #pragma unroll
  for (int k = 0; k < 4; ++k) o4[k] = f2bf(tile[r4 + k][c]);
  *(s16x4*)(out + (size_t)(c0 + c) * 512 + r0 + r4) = o4;
}

// ---------------- batched transpose f32 [Kpm,512] -> bf16 [512,Kpm] for pw (4 windows) -------
// v3: write phase remapped so 32 lanes cover ONE column -> one 256-B fully
//     contiguous segment per 32-lane half (2 segments/wave-instruction vs 8x64B).
__global__ __launch_bounds__(256)
void transpose_pw4(const float* __restrict__ p0, const float* __restrict__ p1,
                   const float* __restrict__ p2, const float* __restrict__ p3,
                   short* __restrict__ scratch4){
  __shared__ float tile[128][33];
  int b = blockIdx.x;                           // 15360 = 16 x (64+128+256+512)
  int i, base;
  if (b < 1024){ i = 0; base = 0; }
  else if (b < 3072){ i = 1; base = 1024; }
  else if (b < 7168){ i = 2; base = 3072; }
  else { i = 3; base = 7168; }
  const int local = b - base;
  const int rt = local >> 4;                    // r-tile of 128 rows
  const int ct = local & 15;                    // c-tile of 32 cols
  const float* in = (i == 0) ? p0 : (i == 1) ? p1 : (i == 2) ? p2 : p3;
  short* out = scratch4 + soff4(i);
  const int R = (16 << i) << 9;
  const int r0 = rt << 7, c0 = ct << 5;
  const int t = threadIdx.x;
  // read: 128 rows x 32 f32, float4 per thread (8 threads/row)
  const int rr = t >> 3;                        // 0..31
  const int cc = (t & 7) << 2;
  #pragma unroll
  for (int k = 0; k < 128; k += 32){
    const float4 v = *(const float4*)(in + (size_t)(r0 + rr + k) * 512 + c0 + cc);
    tile[rr + k][cc] = v.x; tile[rr + k][cc + 1] = v.y;
    tile[rr + k][cc + 2] = v.z; tile[rr + k][cc + 3] = v.w;
  }
  __syncthreads();
  // write: 4 passes; per pass 32 lanes own one column -> 256 B contiguous/half-wave
  const int c = t >> 5;                         // 0..7 within pass
  const int r = (t & 31) << 2;                  // 0..124
  #pragma unroll
  for (int pass = 0; pass < 4; ++pass){
    const int cc2 = pass * 8 + c;
    s16x4 o4;
    o4[0] = f2bf(tile[r][cc2]);     o4[1] = f2bf(tile[r + 1][cc2]);
    o4[2] = f2bf(tile[r + 2][cc2]); o4[3] = f2bf(tile[r + 3][cc2]);
    *(s16x4*)(out + (size_t)(c0 + cc2) * R + r0 + r) = o4;
  }
}

// ---------------- batched cast f32 -> bf16 of 4 Wo matrices ----------------
__global__ void cast4_k(const float* __restrict__ attn_w, short* __restrict__ wcast){
  int gid = blockIdx.x * 256 + threadIdx.x;     // 131072 threads, 8 elems each
  const int i = gid >> 15;                      // 32768 groups per 512x512 matrix
  const int off = (gid & 32767) * 8;
  const float* in = attn_w + (size_t)(i*4 + 3) * 262144 + off;
  const float4 f0 = ((const float4*)in)[0];
  const float4 f1 = ((const float4*)in)[1];
  bf16x8 o;
  o[0]=f2bf(f0.x); o[1]=f2bf(f0.y); o[2]=f2bf(f0.z); o[3]=f2bf(f0.w);
  o[4]=f2bf(f1.x); o[5]=f2bf(f1.y); o[6]=f2bf(f1.z); o[7]=f2bf(f1.w);
  *(bf16x8*)(wcast + (size_t)i * 262144 + off) = o;
}

// ---------------- batched bias fold: cbadd[i][j] = sum_r bo_i[r&511] * pwT_i[j][r] ----------
// v2: bf16x8 vectorized row reads.
__global__ void bias_fold4_k(const short* __restrict__ scratch4, const float* __restrict__ attn_b,
                             float* __restrict__ cbadd){
  const int i = blockIdx.x >> 9;
  const int j = blockIdx.x & 511;
  const int Kpm = (16 << i) << 9;
  const short* row = scratch4 + soff4(i) + (size_t)j * Kpm;
  const float* bo = attn_b + i * 2048 + 1536;
  float s = 0.f;
  for (int r = threadIdx.x * 8; r < Kpm; r += 2048){
    const bf16x8 v = *(const bf16x8*)(row + r);
    const int b0 = r & 511;
    #pragma unroll
    for (int e = 0; e < 8; ++e){
      union { unsigned u; float f; } c; c.u = ((unsigned)(unsigned short)v[e]) << 16;
      s += c.f * bo[b0 + e];
    }
  }
  s += __shfl_xor(s, 1);  s += __shfl_xor(s, 2);  s += __shfl_xor(s, 4);
  s += __shfl_xor(s, 8);  s += __shfl_xor(s, 16); s += __shfl_xor(s, 32);
  __shared__ float red[4];
  if ((threadIdx.x & 63) == 0) red[threadIdx.x >> 6] = s;
  __syncthreads();
  if (threadIdx.x == 0) cbadd[i * 512 + j] = red[0] + red[1] + red[2] + red[3];
}

// ---------------- split-K reduce + bias, float4 (writes each out element exactly once) --------
__global__ void reduce_k(const float* __restrict__ part, float* __restrict__ out,
                         const float* __restrict__ pb, const float* __restrict__ cb,
                         int Mc, int S, int rpb, int roff){
  int gid = blockIdx.x * 256 + threadIdx.x;     // Mc*128 threads
  int c4 = (gid & 127) << 2;
  int rr = gid >> 7;
  float4 s = *(const float4*)(pb + c4);
  const float4 cv = *(const float4*)(cb + c4);
  s.x += cv.x; s.y += cv.y; s.z += cv.z; s.w += cv.w;
  const float* p = part + (size_t)rr * 512 + c4;
  const size_t stride = (size_t)Mc * 512;
  for (int k = 0; k < S; ++k){
    const float4 v = *(const float4*)(p + (size_t)k * stride);
    s.x += v.x; s.y += v.y; s.z += v.z; s.w += v.w;
  }
  int ob = rr / rpb;
  int orow = rr - ob * rpb;
  *(float4*)(out + (size_t)(ob * 375 + roff + orow) * 512 + c4) = s;
}

// ---------------- 128^2 GEMM C = A[M,K] @ Bt[N,K]^T, BK=64, swizzled LDS ----------------
// bf16 store + f32 bias. B4=1: batched over 4 windows (grid 48 = 4 x 12 N-tiles),
// per-window Bt/C/bias offsets decoded in-kernel (qkvtab precompute).
template<int B4>
__global__ __launch_bounds__(256)
void gemm_bt(const short* __restrict__ A, int lda,
             const short* __restrict__ Bt, int ldb,
             void* __restrict__ Cv, int ldc,
             int M, int N, int K,
             const float* __restrict__ bias,
             int kc)
{
  __shared__ short alds[8192];   // [128][64]
  __shared__ short blds[8192];

  const int t = threadIdx.x;
  int wg = xswz(blockIdx.x, gridDim.x);
  if (B4){
    const int i = wg / 12; wg -= i * 12;
    Bt += (size_t)i * 3 * 262144;
    Cv = (void*)((short*)Cv + (size_t)i * 153600);
    bias += i * 2048;
  }
  const int Mt = (M + 127) >> 7;
  const int Nt = N >> 7;
  const int bn = wg % Nt; wg /= Nt;
  const int bm = wg % Mt; wg /= Mt;
  const int ksp = wg;
  int kbeg = ksp * kc, kend = kbeg + kc; if (kend > K) kend = K;

  const int srow = t >> 3;                      // 0..31
  const int scol = (t & 7) << 3;
  const int scolz = scol ^ ((srow & 7) << 3);   // swizzled SOURCE column (m173)
  const short* ga[4]; const short* gb[4];
  #pragma unroll
  for (int p = 0; p < 4; ++p){
    int arow = bm*128 + srow + p*32; if (arow >= M) arow = M - 1;
    ga[p] = A + (size_t)arow * lda + kbeg + scolz;
    gb[p] = Bt + (size_t)(bn*128 + srow + p*32) * ldb + kbeg + scolz;
  }
  short* la = alds + t * 8;
  short* lb = blds + t * 8;

  const int wave = t >> 6;
  const int lane = t & 63;
  const int wm = (wave >> 1) << 6;
  const int wn = (wave & 1) << 6;
  const int fr = lane & 15;
  const int fk = (lane >> 4) << 3;
  const int fx = (fr & 7) << 3;

  f32x4 acc[4][4] = {};

  for (int kt = kbeg; kt < kend; kt += 64) {
    #pragma unroll
    for (int p = 0; p < 4; ++p){
      glds16(ga[p], la + p*2048);
      glds16(gb[p], lb + p*2048);
      ga[p] += 64; gb[p] += 64;
    }
    __syncthreads();
    bf16x8 af[2][4], bfr[2][4];
    #pragma unroll
    for (int ks = 0; ks < 2; ++ks){
      const int kcz = (ks*32 + fk) ^ fx;
      #pragma unroll
      for (int m = 0; m < 4; ++m) af[ks][m] = *(const bf16x8*)(alds + (wm + m*16 + fr)*64 + kcz);
      #pragma unroll
      for (int n = 0; n < 4; ++n) bfr[ks][n] = *(const bf16x8*)(blds + (wn + n*16 + fr)*64 + kcz);
    }
    #pragma unroll
    for (int ks = 0; ks < 2; ++ks)
      #pragma unroll
      for (int m = 0; m < 4; ++m)
        #pragma unroll
        for (int n = 0; n < 4; ++n)
          acc[m][n] = mfma16(af[ks][m], bfr[ks][n], acc[m][n]);
    __syncthreads();
  }

  const int rb = (lane >> 4) << 2;
  short* C = (short*)Cv;
  #pragma unroll
  for (int m = 0; m < 4; ++m){
    const int row0 = bm*128 + wm + m*16 + rb;
    #pragma unroll
    for (int n = 0; n < 4; ++n){
      const int col = bn*128 + wn + n*16 + fr;
      const float bv = bias[col];
      #pragma unroll
      for (int r = 0; r < 4; ++r){
        const int rr = row0 + r;
        if (rr < M) C[(size_t)rr * ldc + col] = f2bf(acc[m][n][r] + bv);
      }
    }
  }
}

// ---------------- 256^2 deep-pipelined GEMM (T2+T3+T4+T5) ----------------
// MODE 0 (split-K patch-merge): Cpart[ksp][M][512] = A[M,lda] @ Bt[512,ldb]^T over
//        K-slice [ksp*kc, +kc), f32 partial store.
// MODE 2 (batched compose, 4 windows in one launch, grid 960 = 64+128+256+512):
//        per window i, batch p: C[j][p*512+c] = sum_m A[j][p*512+m] * Bt[c][m];
//        offsets decoded in-kernel; bf16 store.
// 512 thr = 8 waves (2Mx4N), per-wave C 128x64, BK=64, LDS 128 KiB = 2 dbuf x (A|B).
// 4 phases per K-tile; counted vmcnt (6)/(8), never drained in main loop.
template<int MODE>
__global__ __launch_bounds__(512, 2)
void gemm256_pm(const short* __restrict__ A, int lda,
                const short* __restrict__ Bt, int ldb,
                void* __restrict__ Cv, int M, int kc, int ldc)
{
  extern __shared__ short lds_s[];
  const int tid = threadIdx.x;
  int wg = xswz(blockIdx.x, gridDim.x);
  int bn, bm, ksp, kbeg, kbegB;
  if (MODE == 2){
    int i, base;
    if (wg < 64){ i = 0; base = 0; }
    else if (wg < 192){ i = 1; base = 64; }
    else if (wg < 448){ i = 2; base = 192; }
    else { i = 3; base = 448; }
    const int local = wg - base;
    bn = local & 1; bm = (local >> 1) & 1; ksp = local >> 2;   // p = 512-col batch
    const int Kpm = (16 << i) << 9;
    const size_t so = soff4(i);
    A += so; lda = Kpm;
    Bt += (size_t)i * 262144;
    Cv = (void*)((short*)Cv + so); ldc = Kpm;
    M = 512; kc = 512;
    kbeg = ksp << 9; kbegB = 0;
  } else {
    bn = wg & 1; wg >>= 1;
    const int Mt = (M + 255) >> 8;
    bm = wg % Mt; ksp = wg / Mt;
    kbeg = ksp * kc; kbegB = kbeg;
  }

  const int wave = tid >> 6, lane = tid & 63;
  const int wm = wave >> 2, wn = wave & 3;   // 2M x 4N waves
  const int fr = lane & 15, kq = lane >> 4;
  const int fx = fr & 7;
  const int sx0 = (kq ^ fx) << 3;            // swizzled 16B slot, ks=0 (shorts)
  const int sx1 = ((4 + kq) ^ fx) << 3;      // ks=1
  const int aoff = (wm * 64 + fr) << 6;      // phys A row * 64 shorts
  const int boff = (wn * 32 + fr) << 6;

  const int sr = tid >> 3;
  const int kg = ((tid & 7) ^ (sr & 7)) << 3;
  const short* srcA[2][2]; const short* srcB[2][2];
  #pragma unroll
  for (int h = 0; h < 2; ++h)
    #pragma unroll
    for (int u = 0; u < 2; ++u){
      int r = bm * 256 + u * 128 + h * 64 + sr; if (r >= M) r = M - 1;
      srcA[h][u] = A + (size_t)r * lda + kbeg + kg;
      const int br = (u * 2 + (sr >> 5)) * 64 + h * 32 + (sr & 31);
      srcB[h][u] = Bt + (size_t)(bn * 256 + br) * ldb + kbegB + kg;
    }

#define STG_A(dst, h, ko) do { \
    glds16(srcA[h][0] + (ko), (dst) + (h)*8192 + tid*8); \
    glds16(srcA[h][1] + (ko), (dst) + (h)*8192 + 4096 + tid*8); } while(0)
#define STG_B(dst, h, ko) do { \
    glds16(srcB[h][0] + (ko), (dst) + 16384 + (h)*8192 + tid*8); \
    glds16(srcB[h][1] + (ko), (dst) + 16384 + (h)*8192 + 4096 + tid*8); } while(0)

  short* Lc = lds_s;
  short* Ln = lds_s + 32768;

  f32x4 acc[8][4] = {};
  bf16x8 af[4][2], b0[2][2], b1[2][2];

  STG_A(Lc, 0, 0);  STG_B(Lc, 0, 0);
  STG_A(Lc, 1, 0);  STG_B(Lc, 1, 0);
  STG_A(Ln, 0, 64); STG_B(Ln, 0, 64);
  asm volatile("s_waitcnt vmcnt(8)" ::: "memory");
  __builtin_amdgcn_s_barrier();

  const int T = kc >> 6;
  for (int t = 0; t < T; ++t){
    const int k1 = ((t + 1 < T) ? t + 1 : T - 1) << 6;
    const int k2 = ((t + 2 < T) ? t + 2 : T - 1) << 6;
    // ---- phase 0
    #pragma unroll
    for (int m = 0; m < 4; ++m){
      af[m][0] = *(const bf16x8*)(Lc + aoff + m*1024 + sx0);
      af[m][1] = *(const bf16x8*)(Lc + aoff + m*1024 + sx1);
    }
    #pragma unroll
    for (int n = 0; n < 2; ++n){
      b0[n][0] = *(const bf16x8*)(Lc + 16384 + boff + n*1024 + sx0);
      b0[n][1] = *(const bf16x8*)(Lc + 16384 + boff + n*1024 + sx1);
    }
    STG_A(Ln, 1, k1);
    __builtin_amdgcn_s_barrier();
    asm volatile("s_waitcnt lgkmcnt(0)");
    __builtin_amdgcn_s_setprio(1);
    #pragma unroll
    for (int m = 0; m < 4; ++m)
      #pragma unroll
      for (int n = 0; n < 2; ++n){
        acc[m][n] = mfma16(af[m][0], b0[n][0], acc[m][n]);
        acc[m][n] = mfma16(af[m][1], b0[n][1], acc[m][n]);
      }
    __builtin_amdgcn_s_setprio(0);
    asm volatile("s_waitcnt vmcnt(6)" ::: "memory");
    __builtin_amdgcn_s_barrier();
    // ---- phase 1
    #pragma unroll
    for (int n = 0; n < 2; ++n){
      b1[n][0] = *(const bf16x8*)(Lc + 24576 + boff + n*1024 + sx0);
      b1[n][1] = *(const bf16x8*)(Lc + 24576 + boff + n*1024 + sx1);
    }
    STG_B(Ln, 1, k1);
    __builtin_amdgcn_s_barrier();
    asm volatile("s_waitcnt lgkmcnt(0)");
    __builtin_amdgcn_s_setprio(1);
    #pragma unroll
    for (int m = 0; m < 4; ++m)
      #pragma unroll
      for (int n = 0; n < 2; ++n){
        acc[m][2+n] = mfma16(af[m][0], b1[n][0], acc[m][2+n]);
        acc[m][2+n] = mfma16(af[m][1], b1[n][1], acc[m][2+n]);
      }
    __builtin_amdgcn_s_setprio(0);
    __builtin_amdgcn_s_barrier();
    // ---- phase 2
    #pragma unroll
    for (int m = 0; m < 4; ++m){
      af[m][0] = *(const bf16x8*)(Lc + 8192 + aoff + m*1024 + sx0);
      af[m][1] = *(const bf16x8*)(Lc + 8192 + aoff + m*1024 + sx1);
    }
    STG_A(Lc, 0, k2);
    __builtin_amdgcn_s_barrier();
    asm volatile("s_waitcnt lgkmcnt(0)");
    __builtin_amdgcn_s_setprio(1);
    #pragma unroll
    for (int m = 0; m < 4; ++m)
      #pragma unroll
      for (int n = 0; n < 2; ++n){
        acc[4+m][n] = mfma16(af[m][0], b0[n][0], acc[4+m][n]);
        acc[4+m][n] = mfma16(af[m][1], b0[n][1], acc[4+m][n]);
      }
    __builtin_amdgcn_s_setprio(0);
    __builtin_amdgcn_s_barrier();
    // ---- phase 3
    STG_B(Lc, 0, k2);
    __builtin_amdgcn_s_barrier();
    __builtin_amdgcn_s_setprio(1);
    #pragma unroll
    for (int m = 0; m < 4; ++m)
      #pragma unroll
      for (int n = 0; n < 2; ++n){
        acc[4+m][2+n] = mfma16(af[m][0], b1[n][0], acc[4+m][2+n]);
        acc[4+m][2+n] = mfma16(af[m][1], b1[n][1], acc[4+m][2+n]);
      }
    __builtin_amdgcn_s_setprio(0);
    asm volatile("s_waitcnt vmcnt(8)" ::: "memory");
    __builtin_amdgcn_s_barrier();
    short* tp = Lc; Lc = Ln; Ln = tp;
  }
#undef STG_A
#undef STG_B

  const int rb4 = kq << 2;
  if (MODE == 0){
    float* Cp = (float*)Cv + (size_t)ksp * M * 512;
    #pragma unroll
    for (int mh = 0; mh < 2; ++mh)
      #pragma unroll
      for (int m = 0; m < 4; ++m){
        const int row0 = bm*256 + wm*128 + mh*64 + m*16 + rb4;
        #pragma unroll
        for (int r = 0; r < 4; ++r){
          const int rr = row0 + r;
          if (rr < M){
            float* Crow = Cp + (size_t)rr * 512 + bn*256 + wn*64 + fr;
            #pragma unroll
            for (int nh = 0; nh < 2; ++nh)
              #pragma unroll
              for (int n = 0; n < 2; ++n)
                Crow[nh*32 + n*16] = acc[mh*4+m][nh*2+n][r];
          }
        }
      }
  } else {
    // compose: bf16 store to C[j][kbeg + c], ldc = Kpm
    short* Cs = (short*)Cv;
    #pragma unroll
    for (int mh = 0; mh < 2; ++mh)
      #pragma unroll
      for (int m = 0; m < 4; ++m){
        const int row0 = bm*256 + wm*128 + mh*64 + m*16 + rb4;
        #pragma unroll
        for (int r = 0; r < 4; ++r){
          const int rr = row0 + r;
          if (rr < M){
            short* Crow = Cs + (size_t)rr * ldc + kbeg + bn*256 + wn*64 + fr;
            #pragma unroll
            for (int nh = 0; nh < 2; ++nh)
              #pragma unroll
              for (int n = 0; n < 2; ++n)
                Crow[nh*32 + n*16] = f2bf(acc[mh*4+m][nh*2+n][r]);
          }
        }
      }
  }
}

// ---------------- table-gather windowed MHA: one wave per (window-instance, head) ------------
// tab: [100][1536] bf16 per window (Q|K|V rows per vocab value, bias folded).
// v11: swapped QK^T (in-lane softmax), packed P/V/O stores, conflict-spreading
//      swizzle key, waves-per-block from blockDim (win128 uses 2-wave blocks).
template<int WIN>
__global__ __launch_bounds__(256)
void attn_g(const int* __restrict__ spec, const short* __restrict__ tab,
            short* __restrict__ ao){
  constexpr int WINP = (WIN < 32) ? 32 : WIN;     // padded k-dim
  constexpr int KMASK = WINP / 8 - 1;             // in-row swizzle key clamp
  constexpr int NT = WIN / 16;
  extern __shared__ short smem[];                 // per wave: Vt[64][WINP] + P[16][WINP]
  const int lane = threadIdx.x & 63;
  const int w = threadIdx.x >> 6;
  const int wpb = (int)(blockDim.x >> 6);
  const int wh = blockIdx.x * wpb + w;
  const int wid = wh >> 3, h = wh & 7;
  const size_t tb = (size_t)wid * WIN;
  short* vt = smem + w * 80 * WINP;
  short* pl = vt + 64 * WINP;

  const int fr = lane & 15;
  const int fk = (lane >> 4) << 3;
  const int kq = lane >> 4;
  const int rb = kq << 2;

  // ---- V^T staging: (KRUN k x 8 d) cells, packed LDS writes.
  // element (d,k) -> vt[d*WINP + (k ^ key(d))], key(x) = ((x + (x>>3)) & KMASK) << 3
  {
    constexpr int KRUN = (WIN >= 32) ? 4 : 2;
    constexpr int ITER = (WIN / KRUN) * 8 / 64;   // 1,1,2,4
    const int dgrp = lane & 7;
    #pragma unroll
    for (int it = 0; it < ITER; ++it){
      const int kb = ((lane >> 3) + it * 8) * KRUN;
      bf16x8 vv[KRUN];
      #pragma unroll
      for (int kk = 0; kk < KRUN; ++kk)
        vv[kk] = *(const bf16x8*)(tab + (size_t)spec[tb + kb + kk] * 1536 + 1024 + h * 64 + dgrp * 8);
      #pragma unroll
      for (int j = 0; j < 8; ++j){
        const int d = dgrp * 8 + j;
        const int key = ((d + (d >> 3)) & KMASK) << 3;
        short* dst = vt + d * WINP + (kb ^ key);
        if constexpr (KRUN == 4){
          s16x4 wv; wv[0]=vv[0][j]; wv[1]=vv[1][j]; wv[2]=vv[2][j]; wv[3]=vv[3][j];
          *(s16x4*)dst = wv;
        } else {
          s16x2 wv; wv[0]=vv[0][j]; wv[1]=vv[1][j];
          *(s16x2*)dst = wv;
        }
      }
    }
  }
  if constexpr (WIN == 16){
    // zero-fill V^T pad (logical k=16..31 of every d-row): uninitialized LDS may
    // hold NaN bf16 patterns and 0*NaN = NaN. lane == d (64 lanes, 64 rows).
    const int d = lane;
    const int key = ((d + (d >> 3)) & KMASK) << 3;
    short* vrow_ = vt + d * WINP;
    const s16x4 z = {0, 0, 0, 0};
    #pragma unroll
    for (int kk = 16; kk < 32; kk += 4)
      *(s16x4*)(vrow_ + (kk ^ key)) = z;
  }

  // ---- hoisted K row pointers; K fragments in regs for NT<=4
  const short* kp8[NT];
  #pragma unroll
  for (int nt = 0; nt < NT; ++nt)
    kp8[nt] = tab + (size_t)spec[tb + nt*16 + fr] * 1536 + 512 + h*64 + fk;

  bf16x8 bkh[(NT <= 4) ? NT : 1][2];
  if constexpr (NT <= 4){
    #pragma unroll
    for (int nt = 0; nt < NT; ++nt){
      bkh[nt][0] = *(const bf16x8*)(kp8[nt]);
      bkh[nt][1] = *(const bf16x8*)(kp8[nt] + 32);
    }
  }

  const int rxq = ((fr + (fr >> 3)) & KMASK) << 3; // P-row swizzle key (row = q = fr)
  short* plq = pl + fr * WINP;

  for (int qt = 0; qt < NT; ++qt){
    // Q row token == K row token for the same (tile, fr): reuse pointer, offset -512
    const short* qrow = kp8[qt] - 512;
    bf16x8 aq0 = *(const bf16x8*)(qrow);
    bf16x8 aq1 = *(const bf16x8*)(qrow + 32);
    float s[NT][4];
    #pragma unroll
    for (int nt = 0; nt < NT; ++nt){
      bf16x8 k0, k1;
      if constexpr (NT <= 4){ k0 = bkh[nt][0]; k1 = bkh[nt][1]; }
      else { k0 = *(const bf16x8*)(kp8[nt]); k1 = *(const bf16x8*)(kp8[nt] + 32); }
      f32x4 c = {0.f, 0.f, 0.f, 0.f};
      c = mfma16(k0, aq0, c);                     // swapped: C[k_local][q = lane&15]
      c = mfma16(k1, aq1, c);
      #pragma unroll
      for (int r = 0; r < 4; ++r) s[nt][r] = c[r] * 0.125f;
    }
    // in-lane softmax for q = fr: tree max/sum over 4*NT values + 2 shfls each
    float mm[NT];
    #pragma unroll
    for (int nt = 0; nt < NT; ++nt)
      mm[nt] = fmaxf(fmaxf(s[nt][0], s[nt][1]), fmaxf(s[nt][2], s[nt][3]));
    #pragma unroll
    for (int st = NT >> 1; st >= 1; st >>= 1)
      #pragma unroll
      for (int i = 0; i < st; ++i) mm[i] = fmaxf(mm[i], mm[i + st]);
    float m = mm[0];
    m = fmaxf(m, __shfl_xor(m, 16));
    m = fmaxf(m, __shfl_xor(m, 32));
    float ss[NT];
    #pragma unroll
    for (int nt = 0; nt < NT; ++nt){
      #pragma unroll
      for (int r = 0; r < 4; ++r) s[nt][r] = __expf(s[nt][r] - m);
      ss[nt] = (s[nt][0] + s[nt][1]) + (s[nt][2] + s[nt][3]);
    }
    #pragma unroll
    for (int st = NT >> 1; st >= 1; st >>= 1)
      #pragma unroll
      for (int i = 0; i < st; ++i) ss[i] += ss[i + st];
    float sum = ss[0];
    sum += __shfl_xor(sum, 16);
    sum += __shfl_xor(sum, 32);
    const float inv = 1.f / sum;
    // packed P store: lane owns k = nt*16 + rb + 0..3 of row q=fr (contiguous, b64)
    #pragma unroll
    for (int nt = 0; nt < NT; ++nt){
      s16x4 pw;
      pw[0] = f2bf(s[nt][0] * inv); pw[1] = f2bf(s[nt][1] * inv);
      pw[2] = f2bf(s[nt][2] * inv); pw[3] = f2bf(s[nt][3] * inv);
      *(s16x4*)(plq + ((nt*16 + rb) ^ rxq)) = pw;
    }
    if (WIN == 16){
      s16x4 pz = {0, 0, 0, 0};
      *(s16x4*)(plq + ((16 + rb) ^ rxq)) = pz;
    }
    // PV with swapped operands: lane (fr,kq) gets O[q=fr][d=d0*16+kq*4+r] -> packed store
    short* aorow = ao + (tb + qt*16 + fr) * 512 + h*64 + rb;
    if constexpr (WINP / 32 <= 2){
      // hoist P fragments once (d0-invariant); cheap in VGPRs for WIN<=64
      bf16x8 aph[WINP / 32];
      #pragma unroll
      for (int ks = 0; ks < WINP/32; ++ks)
        aph[ks] = *(const bf16x8*)(pl + fr * WINP + ((ks*32 + fk) ^ rxq));
      #pragma unroll
      for (int d0 = 0; d0 < 4; ++d0){
        const int vrow = d0*16 + fr;
        const int vx = ((vrow + (vrow >> 3)) & KMASK) << 3;
        f32x4 o = {0.f, 0.f, 0.f, 0.f};
        #pragma unroll
        for (int ks = 0; ks < WINP/32; ++ks){
          bf16x8 bv = *(const bf16x8*)(vt + vrow * WINP + ((ks*32 + fk) ^ vx));
          o = mfma16(bv, aph[ks], o);
        }
        s16x4 ov;
        ov[0]=f2bf(o[0]); ov[1]=f2bf(o[1]); ov[2]=f2bf(o[2]); ov[3]=f2bf(o[3]);
        *(s16x4*)(aorow + d0*16) = ov;
      }
    } else {
      // WIN=128: reload ap per d0 (keeps VGPR below the 128 cliff)
      #pragma unroll
      for (int d0 = 0; d0 < 4; ++d0){
        const int vrow = d0*16 + fr;
        const int vx = ((vrow + (vrow >> 3)) & KMASK) << 3;
        f32x4 o = {0.f, 0.f, 0.f, 0.f};
        #pragma unroll
        for (int ks = 0; ks < WINP/32; ++ks){
          bf16x8 ap = *(const bf16x8*)(pl + fr * WINP + ((ks*32 + fk) ^ rxq));
          bf16x8 bv = *(const bf16x8*)(vt + vrow * WINP + ((ks*32 + fk) ^ vx));
          o = mfma16(bv, ap, o);
        }
        s16x4 ov;
        ov[0]=f2bf(o[0]); ov[1]=f2bf(o[1]); ov[2]=f2bf(o[2]); ov[3]=f2bf(o[3]);
        *(s16x4*)(aorow + d0*16) = ov;
      }
    }
    // no __syncthreads: smem slices are wave-private; in-wave lgkmcnt ordering suffices
  }
}

// ---------------- host ----------------
extern "C" void kernel_launch(void* const* d_in, const int* in_sizes, int n_in,
                              void* d_out, int out_size, void* d_ws, size_t ws_size,
                              hipStream_t stream){
  const int*   spec   = (const int*)d_in[0];
  const float* emb    = (const float*)d_in[1];
  const float* attn_w = (const float*)d_in[2];
  const float* attn_b = (const float*)d_in[3];
  const float* pw[4]  = {(const float*)d_in[4], (const float*)d_in[6],
                         (const float*)d_in[8], (const float*)d_in[10]};
  const float* pb[4]  = {(const float*)d_in[5], (const float*)d_in[7],
                         (const float*)d_in[9], (const float*)d_in[11]};
  float* out = (float*)d_out;

  // fixed buffers (~135.5 MB): wtq | wcast | wtpc | cbadd | embT | qkvtab
  short* wtq    = (short*)d_ws;             // [4][1536][512] transposed q,k,v
  short* wcast  = wtq + 3145728;            // [4][512][512] Wo cast
  short* wtpc   = wcast + 1048576;          // composed pm weights
  float* cbadd  = (float*)(wtpc + 62914560);// [4][512]
  short* embT   = (short*)(cbadd + 2048);   // [100][512]
  short* qkvtab = embT + 51200;             // [4][100][1536]
  short* dyn    = qkvtab + 614400;

  short* aob  = dyn;                        // [102400][512] bf16 (105 MB)
  float* pbuf = (float*)(aob + (size_t)TOK_TOTAL * 512); // split-K partials (52 MB)
  short* scratch4 = dyn;                    // all 4 pw^T blocks (125.8 MB, prep only;
                                            // aliases aob+pbuf head, dead before attn)

  static const int winv[4]  = {16, 32, 64, 128};
  static const int wpoff[4] = {0, 16*262144, 48*262144, 112*262144};
  static const int roffv[4] = {0, 200, 300, 350};
  static const int wpbv[4]  = {4, 4, 4, 2};  // waves/block: win128 uses 2-wave blocks

  (void)hipFuncSetAttribute(reinterpret_cast<const void*>(gemm256_pm<0>),
                            hipFuncAttributeMaxDynamicSharedMemorySize, 131072);
  (void)hipFuncSetAttribute(reinterpret_cast<const void*>(gemm256_pm<2>),
                            hipFuncAttributeMaxDynamicSharedMemorySize, 131072);

  dim3 tb(32, 8);
  // ---- batched prep (7 launches total) ----
  embcast_k<<<25, 256, 0, stream>>>(emb, embT);
  transpose_wtq<<<dim3(16, 16, 12), tb, 0, stream>>>(attn_w, wtq);
  cast4_k<<<512, 256, 0, stream>>>(attn_w, wcast);
  transpose_pw4<<<15360, 256, 0, stream>>>(pw[0], pw[1], pw[2], pw[3], scratch4);
  bias_fold4_k<<<2048, 256, 0, stream>>>(scratch4, attn_b, cbadd);
  gemm256_pm<2><<<960, 512, 131072, stream>>>(scratch4, 0, wcast, 512, wtpc, 512, 512, 512);
  gemm_bt<1><<<48, 256, 0, stream>>>(embT, 512, wtq, 512, qkvtab, 1536,
                                     100, 1536, 512, attn_b, 512);

  // ---- main loop: 3 launches per window ----
  for (int i = 0; i < 4; ++i){
    const int win = winv[i];
    const short* tabw = qkvtab + (size_t)i * 153600;
    const int wpb = wpbv[i];
    const int blocks = (TOK_TOTAL / win) * 8 / wpb;
    const int winp = (win < 32) ? 32 : win;
    const size_t shmem = (size_t)wpb * 80 * winp * 2;
    if (win == 16)       attn_g<16 ><<<blocks, wpb*64, shmem, stream>>>(spec, tabw, aob);
    else if (win == 32)  attn_g<32 ><<<blocks, wpb*64, shmem, stream>>>(spec, tabw, aob);
    else if (win == 64)  attn_g<64 ><<<blocks, wpb*64, shmem, stream>>>(spec, tabw, aob);
    else                 attn_g<128><<<blocks, wpb*64, shmem, stream>>>(spec, tabw, aob);
    // patch-merge split-K (kc=2048) via 256^2 pipelined GEMM, then deterministic reduce (+bias)
    const int Kpm = win * 512;
    const int S = Kpm / 2048;
    const int Mc = TOK_TOTAL / win;
    const int mtp = (Mc + 255) >> 8;
    gemm256_pm<0><<<mtp * 2 * S, 512, 131072, stream>>>(aob, Kpm, wtpc + wpoff[i], Kpm,
                                                        pbuf, Mc, 2048, 512);
    reduce_k<<<Mc / 2, 256, 0, stream>>>(pbuf, out, pb[i], cbadd + i*512,
                                         Mc, S, L_SEQ / win, roffv[i]);
  }
}

// Round 12
// 695.753 us; speedup vs baseline: 1.3404x; 1.0036x over previous
//
#include <hip/hip_runtime.h>
#include <hip/hip_bf16.h>
#include <stdint.h>

#define TOK_TOTAL 102400   // 32*3200
#define L_SEQ 3200

typedef __attribute__((ext_vector_type(8))) short bf16x8;
typedef __attribute__((ext_vector_type(4))) short s16x4;
typedef __attribute__((ext_vector_type(2))) short s16x2;
typedef __attribute__((ext_vector_type(4))) float f32x4;

__device__ __forceinline__ short f2bf(float f){
  union { __hip_bfloat16 h; short s; } u;
  u.h = __float2bfloat16(f);
  return u.s;
}

__device__ __forceinline__ f32x4 mfma16(bf16x8 a, bf16x8 b, f32x4 c){
  return __builtin_amdgcn_mfma_f32_16x16x32_bf16(a, b, c, 0, 0, 0);
}

__device__ __forceinline__ void glds16(const short* g, short* l){
  __builtin_amdgcn_global_load_lds((const __attribute__((address_space(1))) unsigned*)g,
                                   (__attribute__((address_space(3))) unsigned*)l, 16, 0, 0);
}

// bijective XCD-chunk swizzle (m204)
__device__ __forceinline__ int xswz(int bid, int nwg){
  int q = nwg >> 3, r = nwg & 7, x = bid & 7, k = bid >> 3;
  return (x < r ? x * (q + 1) : r * (q + 1) + (x - r) * q) + k;
}

// scratch4 layout offset (shorts): windows 16,32,64,128 concatenated pw^T blocks.
// v14: PANEL-TILED layout — element (j, r) at ((r>>6)*512 + j)*64 + (r&63).
// glds16 staging only needs 16-B K-contiguity, which panels provide; the tiled
// layout makes transpose writes fully coalescible (j-consecutive 128-B chunks).
__device__ __host__ __forceinline__ size_t soff4(int i){
  return (size_t)((16 << i) - 16) * 262144;
}

// ---------------- embT: bf16 embedding table with sqrt(512) folded (100x512) ----------------
__global__ void embcast_k(const float* __restrict__ emb, short* __restrict__ embT){
  int gid = blockIdx.x * 256 + threadIdx.x;     // 6400 threads, 8 elems each
  const float SC = 22.627416997969522f;
  const float4 f0 = ((const float4*)emb)[gid*2];
  const float4 f1 = ((const float4*)emb)[gid*2+1];
  bf16x8 o;
  o[0]=f2bf(f0.x*SC); o[1]=f2bf(f0.y*SC); o[2]=f2bf(f0.z*SC); o[3]=f2bf(f0.w*SC);
  o[4]=f2bf(f1.x*SC); o[5]=f2bf(f1.y*SC); o[6]=f2bf(f1.z*SC); o[7]=f2bf(f1.w*SC);
  *(bf16x8*)(embT + gid*8) = o;
}

// ---------------- batched transpose f32 512x512 -> bf16 512x512 for wtq (12 slices) ---------
__global__ void transpose_wtq(const float* __restrict__ attn_w, short* __restrict__ wtq){
  __shared__ float tile[32][33];
  const int z = blockIdx.z;                     // 0..11 = i*3+j
  const int i = z / 3, j = z - i * 3;
  const float* in = attn_w + (size_t)(i*4 + j) * 262144;
  short* out = wtq + (size_t)z * 262144;
  int c0 = blockIdx.x * 32, r0 = blockIdx.y * 32;
  int tx = threadIdx.x, ty = threadIdx.y;       // 32x8
  #pragma unroll
  for (int k = 0; k < 32; k += 8)
    tile[ty + k][tx] = in[(size_t)(r0 + ty + k) * 512 + c0 + tx];
  __syncthreads();
  const int t = ty * 32 + tx;
  const int c = t >> 3;
  const int r4 = (t & 7) << 2;
  s16x4 o4;
  #pragma unroll
  for (int k = 0; k < 4; ++k) o4[k] = f2bf(tile[r4 + k][c]);
  *(s16x4*)(out + (size_t)(c0 + c) * 512 + r0 + r4) = o4;
}

// ---------------- batched transpose f32 [Kpm,512] -> bf16 panel-tiled pw^T (4 windows) -------
// v4: output is panel-tiled (see soff4 comment). Per write pass, a wave emits 1 KB
//     fully contiguous (8 j-columns x 128 B within one 64-k panel) -> coalesced.
__global__ __launch_bounds__(256)
void transpose_pw4(const float* __restrict__ p0, const float* __restrict__ p1,
                   const float* __restrict__ p2, const float* __restrict__ p3,
                   short* __restrict__ scratch4){
  __shared__ float tile[128][33];
  int b = blockIdx.x;                           // 15360 = 16 x (64+128+256+512)
  int i, base;
  if (b < 1024){ i = 0; base = 0; }
  else if (b < 3072){ i = 1; base = 1024; }
  else if (b < 7168){ i = 2; base = 3072; }
  else { i = 3; base = 7168; }
  const int local = b - base;
  const int rt = local >> 4;                    // r-tile of 128 rows
  const int ct = local & 15;                    // c-tile of 32 cols
  const float* in = (i == 0) ? p0 : (i == 1) ? p1 : (i == 2) ? p2 : p3;
  short* out = scratch4 + soff4(i);
  const int r0 = rt << 7, c0 = ct << 5;
  const int t = threadIdx.x;
  // read: 128 rows x 32 f32, float4 per thread (8 threads/row)
  const int rr0 = t >> 3;                       // 0..31
  const int cc = (t & 7) << 2;
  #pragma unroll
  for (int k = 0; k < 128; k += 32){
    const float4 v = *(const float4*)(in + (size_t)(r0 + rr0 + k) * 512 + c0 + cc);
    tile[rr0 + k][cc] = v.x; tile[rr0 + k][cc + 1] = v.y;
    tile[rr0 + k][cc + 2] = v.z; tile[rr0 + k][cc + 3] = v.w;
  }
  __syncthreads();
  // write: tiled layout ((r>>6)*512 + j)*64 + (r&63); per pass 32 j x 4 r
  const int c = t >> 3;                         // 0..31 (j within tile)
  const int r4 = (t & 7) << 2;                  // 0..28 (r within 32-row group)
  #pragma unroll
  for (int g = 0; g < 4; ++g){
    const int rr = g * 32 + r4;                 // 0..124
    s16x4 o4;
    o4[0] = f2bf(tile[rr][c]);     o4[1] = f2bf(tile[rr + 1][c]);
    o4[2] = f2bf(tile[rr + 2][c]); o4[3] = f2bf(tile[rr + 3][c]);
    const int panel = (r0 >> 6) + (rr >> 6);
    *(s16x4*)(out + ((size_t)panel * 512 + c0 + c) * 64 + (rr & 63)) = o4;
  }
}

// ---------------- batched cast f32 -> bf16 of 4 Wo matrices ----------------
__global__ void cast4_k(const float* __restrict__ attn_w, short* __restrict__ wcast){
  int gid = blockIdx.x * 256 + threadIdx.x;     // 131072 threads, 8 elems each
  const int i = gid >> 15;                      // 32768 groups per 512x512 matrix
  const int off = (gid & 32767) * 8;
  const float* in = attn_w + (size_t)(i*4 + 3) * 262144 + off;
  const float4 f0 = ((const float4*)in)[0];
  const float4 f1 = ((const float4*)in)[1];
  bf16x8 o;
  o[0]=f2bf(f0.x); o[1]=f2bf(f0.y); o[2]=f2bf(f0.z); o[3]=f2bf(f0.w);
  o[4]=f2bf(f1.x); o[5]=f2bf(f1.y); o[6]=f2bf(f1.z); o[7]=f2bf(f1.w);
  *(bf16x8*)(wcast + (size_t)i * 262144 + off) = o;
}

// ---------------- batched bias fold: cbadd[i][j] = sum_r bo_i[r&511] * pwT_i[j][r] ----------
// v3: reads the panel-tiled scratch4 (same per-thread summation order as before).
__global__ void bias_fold4_k(const short* __restrict__ scratch4, const float* __restrict__ attn_b,
                             float* __restrict__ cbadd){
  const int i = blockIdx.x >> 9;
  const int j = blockIdx.x & 511;
  const int Kpm = (16 << i) << 9;
  const short* basep = scratch4 + soff4(i) + (size_t)j * 64;
  const float* bo = attn_b + i * 2048 + 1536;
  float s = 0.f;
  for (int r = threadIdx.x * 8; r < Kpm; r += 2048){
    const bf16x8 v = *(const bf16x8*)(basep + (size_t)(r >> 6) * 32768 + (r & 63));
    const int b0 = r & 511;
    #pragma unroll
    for (int e = 0; e < 8; ++e){
      union { unsigned u; float f; } c; c.u = ((unsigned)(unsigned short)v[e]) << 16;
      s += c.f * bo[b0 + e];
    }
  }
  s += __shfl_xor(s, 1);  s += __shfl_xor(s, 2);  s += __shfl_xor(s, 4);
  s += __shfl_xor(s, 8);  s += __shfl_xor(s, 16); s += __shfl_xor(s, 32);
  __shared__ float red[4];
  if ((threadIdx.x & 63) == 0) red[threadIdx.x >> 6] = s;
  __syncthreads();
  if (threadIdx.x == 0) cbadd[i * 512 + j] = red[0] + red[1] + red[2] + red[3];
}

// ---------------- split-K reduce + bias, float4 (writes each out element exactly once) --------
__global__ void reduce_k(const float* __restrict__ part, float* __restrict__ out,
                         const float* __restrict__ pb, const float* __restrict__ cb,
                         int Mc, int S, int rpb, int roff){
  int gid = blockIdx.x * 256 + threadIdx.x;     // Mc*128 threads
  int c4 = (gid & 127) << 2;
  int rr = gid >> 7;
  float4 s = *(const float4*)(pb + c4);
  const float4 cv = *(const float4*)(cb + c4);
  s.x += cv.x; s.y += cv.y; s.z += cv.z; s.w += cv.w;
  const float* p = part + (size_t)rr * 512 + c4;
  const size_t stride = (size_t)Mc * 512;
  for (int k = 0; k < S; ++k){
    const float4 v = *(const float4*)(p + (size_t)k * stride);
    s.x += v.x; s.y += v.y; s.z += v.z; s.w += v.w;
  }
  int ob = rr / rpb;
  int orow = rr - ob * rpb;
  *(float4*)(out + (size_t)(ob * 375 + roff + orow) * 512 + c4) = s;
}

// ---------------- 128^2 GEMM C = A[M,K] @ Bt[N,K]^T, BK=64, swizzled LDS ----------------
// bf16 store + f32 bias. B4=1: batched over 4 windows (grid 48 = 4 x 12 N-tiles),
// per-window Bt/C/bias offsets decoded in-kernel (qkvtab precompute).
template<int B4>
__global__ __launch_bounds__(256)
void gemm_bt(const short* __restrict__ A, int lda,
             const short* __restrict__ Bt, int ldb,
             void* __restrict__ Cv, int ldc,
             int M, int N, int K,
             const float* __restrict__ bias,
             int kc)
{
  __shared__ short alds[8192];   // [128][64]
  __shared__ short blds[8192];

  const int t = threadIdx.x;
  int wg = xswz(blockIdx.x, gridDim.x);
  if (B4){
    const int i = wg / 12; wg -= i * 12;
    Bt += (size_t)i * 3 * 262144;
    Cv = (void*)((short*)Cv + (size_t)i * 153600);
    bias += i * 2048;
  }
  const int Mt = (M + 127) >> 7;
  const int Nt = N >> 7;
  const int bn = wg % Nt; wg /= Nt;
  const int bm = wg % Mt; wg /= Mt;
  const int ksp = wg;
  int kbeg = ksp * kc, kend = kbeg + kc; if (kend > K) kend = K;

  const int srow = t >> 3;                      // 0..31
  const int scol = (t & 7) << 3;
  const int scolz = scol ^ ((srow & 7) << 3);   // swizzled SOURCE column (m173)
  const short* ga[4]; const short* gb[4];
  #pragma unroll
  for (int p = 0; p < 4; ++p){
    int arow = bm*128 + srow + p*32; if (arow >= M) arow = M - 1;
    ga[p] = A + (size_t)arow * lda + kbeg + scolz;
    gb[p] = Bt + (size_t)(bn*128 + srow + p*32) * ldb + kbeg + scolz;
  }
  short* la = alds + t * 8;
  short* lb = blds + t * 8;

  const int wave = t >> 6;
  const int lane = t & 63;
  const int wm = (wave >> 1) << 6;
  const int wn = (wave & 1) << 6;
  const int fr = lane & 15;
  const int fk = (lane >> 4) << 3;
  const int fx = (fr & 7) << 3;

  f32x4 acc[4][4] = {};

  for (int kt = kbeg; kt < kend; kt += 64) {
    #pragma unroll
    for (int p = 0; p < 4; ++p){
      glds16(ga[p], la + p*2048);
      glds16(gb[p], lb + p*2048);
      ga[p] += 64; gb[p] += 64;
    }
    __syncthreads();
    bf16x8 af[2][4], bfr[2][4];
    #pragma unroll
    for (int ks = 0; ks < 2; ++ks){
      const int kcz = (ks*32 + fk) ^ fx;
      #pragma unroll
      for (int m = 0; m < 4; ++m) af[ks][m] = *(const bf16x8*)(alds + (wm + m*16 + fr)*64 + kcz);
      #pragma unroll
      for (int n = 0; n < 4; ++n) bfr[ks][n] = *(const bf16x8*)(blds + (wn + n*16 + fr)*64 + kcz);
    }
    #pragma unroll
    for (int ks = 0; ks < 2; ++ks)
      #pragma unroll
      for (int m = 0; m < 4; ++m)
        #pragma unroll
        for (int n = 0; n < 4; ++n)
          acc[m][n] = mfma16(af[ks][m], bfr[ks][n], acc[m][n]);
    __syncthreads();
  }

  const int rb = (lane >> 4) << 2;
  short* C = (short*)Cv;
  #pragma unroll
  for (int m = 0; m < 4; ++m){
    const int row0 = bm*128 + wm + m*16 + rb;
    #pragma unroll
    for (int n = 0; n < 4; ++n){
      const int col = bn*128 + wn + n*16 + fr;
      const float bv = bias[col];
      #pragma unroll
      for (int r = 0; r < 4; ++r){
        const int rr = row0 + r;
        if (rr < M) C[(size_t)rr * ldc + col] = f2bf(acc[m][n][r] + bv);
      }
    }
  }
}

// ---------------- 256^2 deep-pipelined GEMM (T2+T3+T4+T5) ----------------
// MODE 0 (split-K patch-merge): Cpart[ksp][M][512] = A[M,lda] @ Bt[512,ldb]^T over
//        K-slice [ksp*kc, +kc), f32 partial store. A is linear row-major.
// MODE 2 (batched compose, 4 windows in one launch, grid 960 = 64+128+256+512):
//        per window i, batch p: C[j][p*512+c] = sum_m A[j][p*512+m] * Bt[c][m];
//        A = scratch4 in PANEL-TILED layout (element (j,k): ((k>>6)*512+j)*64+(k&63));
//        one panel per BK=64 step -> srcA advance is ko*512 shorts. bf16 store.
// 512 thr = 8 waves (2Mx4N), per-wave C 128x64, BK=64, LDS 128 KiB = 2 dbuf x (A|B).
// 4 phases per K-tile; counted vmcnt (6)/(8), never drained in main loop.
template<int MODE>
__global__ __launch_bounds__(512, 2)
void gemm256_pm(const short* __restrict__ A, int lda,
                const short* __restrict__ Bt, int ldb,
                void* __restrict__ Cv, int M, int kc, int ldc)
{
  extern __shared__ short lds_s[];
  const int tid = threadIdx.x;
  int wg = xswz(blockIdx.x, gridDim.x);
  int bn, bm, ksp, kbeg, kbegB;
  if (MODE == 2){
    int i, base;
    if (wg < 64){ i = 0; base = 0; }
    else if (wg < 192){ i = 1; base = 64; }
    else if (wg < 448){ i = 2; base = 192; }
    else { i = 3; base = 448; }
    const int local = wg - base;
    bn = local & 1; bm = (local >> 1) & 1; ksp = local >> 2;   // p = 512-col batch
    const int Kpm = (16 << i) << 9;
    const size_t so = soff4(i);
    A += so;
    Bt += (size_t)i * 262144;
    Cv = (void*)((short*)Cv + so); ldc = Kpm;
    M = 512; kc = 512;
    kbeg = ksp << 9; kbegB = 0;
  } else {
    bn = wg & 1; wg >>= 1;
    const int Mt = (M + 255) >> 8;
    bm = wg % Mt; ksp = wg / Mt;
    kbeg = ksp * kc; kbegB = kbeg;
  }
  const int AST = (MODE == 2) ? 512 : 1;       // A K-advance multiplier (panel-tiled)

  const int wave = tid >> 6, lane = tid & 63;
  const int wm = wave >> 2, wn = wave & 3;   // 2M x 4N waves
  const int fr = lane & 15, kq = lane >> 4;
  const int fx = fr & 7;
  const int sx0 = (kq ^ fx) << 3;            // swizzled 16B slot, ks=0 (shorts)
  const int sx1 = ((4 + kq) ^ fx) << 3;      // ks=1
  const int aoff = (wm * 64 + fr) << 6;      // phys A row * 64 shorts
  const int boff = (wn * 32 + fr) << 6;

  const int sr = tid >> 3;
  const int kg = ((tid & 7) ^ (sr & 7)) << 3;
  const short* srcA[2][2]; const short* srcB[2][2];
  #pragma unroll
  for (int h = 0; h < 2; ++h)
    #pragma unroll
    for (int u = 0; u < 2; ++u){
      int r = bm * 256 + u * 128 + h * 64 + sr; if (r >= M) r = M - 1;
      if (MODE == 2)
        srcA[h][u] = A + (size_t)(kbeg >> 6) * 32768 + (size_t)r * 64 + kg;
      else
        srcA[h][u] = A + (size_t)r * lda + kbeg + kg;
      const int br = (u * 2 + (sr >> 5)) * 64 + h * 32 + (sr & 31);
      srcB[h][u] = Bt + (size_t)(bn * 256 + br) * ldb + kbegB + kg;
    }

#define STG_A(dst, h, ko) do { \
    glds16(srcA[h][0] + (size_t)(ko) * AST, (dst) + (h)*8192 + tid*8); \
    glds16(srcA[h][1] + (size_t)(ko) * AST, (dst) + (h)*8192 + 4096 + tid*8); } while(0)
#define STG_B(dst, h, ko) do { \
    glds16(srcB[h][0] + (ko), (dst) + 16384 + (h)*8192 + tid*8); \
    glds16(srcB[h][1] + (ko), (dst) + 16384 + (h)*8192 + 4096 + tid*8); } while(0)

  short* Lc = lds_s;
  short* Ln = lds_s + 32768;

  f32x4 acc[8][4] = {};
  bf16x8 af[4][2], b0[2][2], b1[2][2];

  STG_A(Lc, 0, 0);  STG_B(Lc, 0, 0);
  STG_A(Lc, 1, 0);  STG_B(Lc, 1, 0);
  STG_A(Ln, 0, 64); STG_B(Ln, 0, 64);
  asm volatile("s_waitcnt vmcnt(8)" ::: "memory");
  __builtin_amdgcn_s_barrier();

  const int T = kc >> 6;
  for (int t = 0; t < T; ++t){
    const int k1 = ((t + 1 < T) ? t + 1 : T - 1) << 6;
    const int k2 = ((t + 2 < T) ? t + 2 : T - 1) << 6;
    // ---- phase 0
    #pragma unroll
    for (int m = 0; m < 4; ++m){
      af[m][0] = *(const bf16x8*)(Lc + aoff + m*1024 + sx0);
      af[m][1] = *(const bf16x8*)(Lc + aoff + m*1024 + sx1);
    }
    #pragma unroll
    for (int n = 0; n < 2; ++n){
      b0[n][0] = *(const bf16x8*)(Lc + 16384 + boff + n*1024 + sx0);
      b0[n][1] = *(const bf16x8*)(Lc + 16384 + boff + n*1024 + sx1);
    }
    STG_A(Ln, 1, k1);
    __builtin_amdgcn_s_barrier();
    asm volatile("s_waitcnt lgkmcnt(0)");
    __builtin_amdgcn_s_setprio(1);
    #pragma unroll
    for (int m = 0; m < 4; ++m)
      #pragma unroll
      for (int n = 0; n < 2; ++n){
        acc[m][n] = mfma16(af[m][0], b0[n][0], acc[m][n]);
        acc[m][n] = mfma16(af[m][1], b0[n][1], acc[m][n]);
      }
    __builtin_amdgcn_s_setprio(0);
    asm volatile("s_waitcnt vmcnt(6)" ::: "memory");
    __builtin_amdgcn_s_barrier();
    // ---- phase 1
    #pragma unroll
    for (int n = 0; n < 2; ++n){
      b1[n][0] = *(const bf16x8*)(Lc + 24576 + boff + n*1024 + sx0);
      b1[n][1] = *(const bf16x8*)(Lc + 24576 + boff + n*1024 + sx1);
    }
    STG_B(Ln, 1, k1);
    __builtin_amdgcn_s_barrier();
    asm volatile("s_waitcnt lgkmcnt(0)");
    __builtin_amdgcn_s_setprio(1);
    #pragma unroll
    for (int m = 0; m < 4; ++m)
      #pragma unroll
      for (int n = 0; n < 2; ++n){
        acc[m][2+n] = mfma16(af[m][0], b1[n][0], acc[m][2+n]);
        acc[m][2+n] = mfma16(af[m][1], b1[n][1], acc[m][2+n]);
      }
    __builtin_amdgcn_s_setprio(0);
    __builtin_amdgcn_s_barrier();
    // ---- phase 2
    #pragma unroll
    for (int m = 0; m < 4; ++m){
      af[m][0] = *(const bf16x8*)(Lc + 8192 + aoff + m*1024 + sx0);
      af[m][1] = *(const bf16x8*)(Lc + 8192 + aoff + m*1024 + sx1);
    }
    STG_A(Lc, 0, k2);
    __builtin_amdgcn_s_barrier();
    asm volatile("s_waitcnt lgkmcnt(0)");
    __builtin_amdgcn_s_setprio(1);
    #pragma unroll
    for (int m = 0; m < 4; ++m)
      #pragma unroll
      for (int n = 0; n < 2; ++n){
        acc[4+m][n] = mfma16(af[m][0], b0[n][0], acc[4+m][n]);
        acc[4+m][n] = mfma16(af[m][1], b0[n][1], acc[4+m][n]);
      }
    __builtin_amdgcn_s_setprio(0);
    __builtin_amdgcn_s_barrier();
    // ---- phase 3
    STG_B(Lc, 0, k2);
    __builtin_amdgcn_s_barrier();
    __builtin_amdgcn_s_setprio(1);
    #pragma unroll
    for (int m = 0; m < 4; ++m)
      #pragma unroll
      for (int n = 0; n < 2; ++n){
        acc[4+m][2+n] = mfma16(af[m][0], b1[n][0], acc[4+m][2+n]);
        acc[4+m][2+n] = mfma16(af[m][1], b1[n][1], acc[4+m][2+n]);
      }
    __builtin_amdgcn_s_setprio(0);
    asm volatile("s_waitcnt vmcnt(8)" ::: "memory");
    __builtin_amdgcn_s_barrier();
    short* tp = Lc; Lc = Ln; Ln = tp;
  }
#undef STG_A
#undef STG_B

  const int rb4 = kq << 2;
  if (MODE == 0){
    float* Cp = (float*)Cv + (size_t)ksp * M * 512;
    #pragma unroll
    for (int mh = 0; mh < 2; ++mh)
      #pragma unroll
      for (int m = 0; m < 4; ++m){
        const int row0 = bm*256 + wm*128 + mh*64 + m*16 + rb4;
        #pragma unroll
        for (int r = 0; r < 4; ++r){
          const int rr = row0 + r;
          if (rr < M){
            float* Crow = Cp + (size_t)rr * 512 + bn*256 + wn*64 + fr;
            #pragma unroll
            for (int nh = 0; nh < 2; ++nh)
              #pragma unroll
              for (int n = 0; n < 2; ++n)
                Crow[nh*32 + n*16] = acc[mh*4+m][nh*2+n][r];
          }
        }
      }
  } else {
    // compose: bf16 store to C[j][kbeg + c], ldc = Kpm (wtpc stays row-major)
    short* Cs = (short*)Cv;
    #pragma unroll
    for (int mh = 0; mh < 2; ++mh)
      #pragma unroll
      for (int m = 0; m < 4; ++m){
        const int row0 = bm*256 + wm*128 + mh*64 + m*16 + rb4;
        #pragma unroll
        for (int r = 0; r < 4; ++r){
          const int rr = row0 + r;
          if (rr < M){
            short* Crow = Cs + (size_t)rr * ldc + kbeg + bn*256 + wn*64 + fr;
            #pragma unroll
            for (int nh = 0; nh < 2; ++nh)
              #pragma unroll
              for (int n = 0; n < 2; ++n)
                Crow[nh*32 + n*16] = f2bf(acc[mh*4+m][nh*2+n][r]);
          }
        }
      }
  }
}

// ---------------- table-gather windowed MHA: one wave per (window-instance, head) ------------
// tab: [100][1536] bf16 per window (Q|K|V rows per vocab value, bias folded).
// v11: swapped QK^T (in-lane softmax), packed P/V/O stores, conflict-spreading
//      swizzle key, waves-per-block from blockDim (win128 uses 2-wave blocks).
template<int WIN>
__global__ __launch_bounds__(256)
void attn_g(const int* __restrict__ spec, const short* __restrict__ tab,
            short* __restrict__ ao){
  constexpr int WINP = (WIN < 32) ? 32 : WIN;     // padded k-dim
  constexpr int KMASK = WINP / 8 - 1;             // in-row swizzle key clamp
  constexpr int NT = WIN / 16;
  extern __shared__ short smem[];                 // per wave: Vt[64][WINP] + P[16][WINP]
  const int lane = threadIdx.x & 63;
  const int w = threadIdx.x >> 6;
  const int wpb = (int)(blockDim.x >> 6);
  const int wh = blockIdx.x * wpb + w;
  const int wid = wh >> 3, h = wh & 7;
  const size_t tb = (size_t)wid * WIN;
  short* vt = smem + w * 80 * WINP;
  short* pl = vt + 64 * WINP;

  const int fr = lane & 15;
  const int fk = (lane >> 4) << 3;
  const int kq = lane >> 4;
  const int rb = kq << 2;

  // ---- V^T staging: (KRUN k x 8 d) cells, packed LDS writes.
  // element (d,k) -> vt[d*WINP + (k ^ key(d))], key(x) = ((x + (x>>3)) & KMASK) << 3
  {
    constexpr int KRUN = (WIN >= 32) ? 4 : 2;
    constexpr int ITER = (WIN / KRUN) * 8 / 64;   // 1,1,2,4
    const int dgrp = lane & 7;
    #pragma unroll
    for (int it = 0; it < ITER; ++it){
      const int kb = ((lane >> 3) + it * 8) * KRUN;
      bf16x8 vv[KRUN];
      #pragma unroll
      for (int kk = 0; kk < KRUN; ++kk)
        vv[kk] = *(const bf16x8*)(tab + (size_t)spec[tb + kb + kk] * 1536 + 1024 + h * 64 + dgrp * 8);
      #pragma unroll
      for (int j = 0; j < 8; ++j){
        const int d = dgrp * 8 + j;
        const int key = ((d + (d >> 3)) & KMASK) << 3;
        short* dst = vt + d * WINP + (kb ^ key);
        if constexpr (KRUN == 4){
          s16x4 wv; wv[0]=vv[0][j]; wv[1]=vv[1][j]; wv[2]=vv[2][j]; wv[3]=vv[3][j];
          *(s16x4*)dst = wv;
        } else {
          s16x2 wv; wv[0]=vv[0][j]; wv[1]=vv[1][j];
          *(s16x2*)dst = wv;
        }
      }
    }
  }
  if constexpr (WIN == 16){
    // zero-fill V^T pad (logical k=16..31 of every d-row): uninitialized LDS may
    // hold NaN bf16 patterns and 0*NaN = NaN. lane == d (64 lanes, 64 rows).
    const int d = lane;
    const int key = ((d + (d >> 3)) & KMASK) << 3;
    short* vrow_ = vt + d * WINP;
    const s16x4 z = {0, 0, 0, 0};
    #pragma unroll
    for (int kk = 16; kk < 32; kk += 4)
      *(s16x4*)(vrow_ + (kk ^ key)) = z;
  }

  // ---- hoisted K row pointers; K fragments in regs for NT<=4
  const short* kp8[NT];
  #pragma unroll
  for (int nt = 0; nt < NT; ++nt)
    kp8[nt] = tab + (size_t)spec[tb + nt*16 + fr] * 1536 + 512 + h*64 + fk;

  bf16x8 bkh[(NT <= 4) ? NT : 1][2];
  if constexpr (NT <= 4){
    #pragma unroll
    for (int nt = 0; nt < NT; ++nt){
      bkh[nt][0] = *(const bf16x8*)(kp8[nt]);
      bkh[nt][1] = *(const bf16x8*)(kp8[nt] + 32);
    }
  }

  const int rxq = ((fr + (fr >> 3)) & KMASK) << 3; // P-row swizzle key (row = q = fr)
  short* plq = pl + fr * WINP;

  for (int qt = 0; qt < NT; ++qt){
    // Q row token == K row token for the same (tile, fr): reuse pointer, offset -512
    const short* qrow = kp8[qt] - 512;
    bf16x8 aq0 = *(const bf16x8*)(qrow);
    bf16x8 aq1 = *(const bf16x8*)(qrow + 32);
    float s[NT][4];
    #pragma unroll
    for (int nt = 0; nt < NT; ++nt){
      bf16x8 k0, k1;
      if constexpr (NT <= 4){ k0 = bkh[nt][0]; k1 = bkh[nt][1]; }
      else { k0 = *(const bf16x8*)(kp8[nt]); k1 = *(const bf16x8*)(kp8[nt] + 32); }
      f32x4 c = {0.f, 0.f, 0.f, 0.f};
      c = mfma16(k0, aq0, c);                     // swapped: C[k_local][q = lane&15]
      c = mfma16(k1, aq1, c);
      #pragma unroll
      for (int r = 0; r < 4; ++r) s[nt][r] = c[r] * 0.125f;
    }
    // in-lane softmax for q = fr: tree max/sum over 4*NT values + 2 shfls each
    float mm[NT];
    #pragma unroll
    for (int nt = 0; nt < NT; ++nt)
      mm[nt] = fmaxf(fmaxf(s[nt][0], s[nt][1]), fmaxf(s[nt][2], s[nt][3]));
    #pragma unroll
    for (int st = NT >> 1; st >= 1; st >>= 1)
      #pragma unroll
      for (int i = 0; i < st; ++i) mm[i] = fmaxf(mm[i], mm[i + st]);
    float m = mm[0];
    m = fmaxf(m, __shfl_xor(m, 16));
    m = fmaxf(m, __shfl_xor(m, 32));
    float ss[NT];
    #pragma unroll
    for (int nt = 0; nt < NT; ++nt){
      #pragma unroll
      for (int r = 0; r < 4; ++r) s[nt][r] = __expf(s[nt][r] - m);
      ss[nt] = (s[nt][0] + s[nt][1]) + (s[nt][2] + s[nt][3]);
    }
    #pragma unroll
    for (int st = NT >> 1; st >= 1; st >>= 1)
      #pragma unroll
      for (int i = 0; i < st; ++i) ss[i] += ss[i + st];
    float sum = ss[0];
    sum += __shfl_xor(sum, 16);
    sum += __shfl_xor(sum, 32);
    const float inv = 1.f / sum;
    // packed P store: lane owns k = nt*16 + rb + 0..3 of row q=fr (contiguous, b64)
    #pragma unroll
    for (int nt = 0; nt < NT; ++nt){
      s16x4 pw;
      pw[0] = f2bf(s[nt][0] * inv); pw[1] = f2bf(s[nt][1] * inv);
      pw[2] = f2bf(s[nt][2] * inv); pw[3] = f2bf(s[nt][3] * inv);
      *(s16x4*)(plq + ((nt*16 + rb) ^ rxq)) = pw;
    }
    if (WIN == 16){
      s16x4 pz = {0, 0, 0, 0};
      *(s16x4*)(plq + ((16 + rb) ^ rxq)) = pz;
    }
    // PV with swapped operands: lane (fr,kq) gets O[q=fr][d=d0*16+kq*4+r] -> packed store
    short* aorow = ao + (tb + qt*16 + fr) * 512 + h*64 + rb;
    if constexpr (WINP / 32 <= 2){
      // hoist P fragments once (d0-invariant); cheap in VGPRs for WIN<=64
      bf16x8 aph[WINP / 32];
      #pragma unroll
      for (int ks = 0; ks < WINP/32; ++ks)
        aph[ks] = *(const bf16x8*)(pl + fr * WINP + ((ks*32 + fk) ^ rxq));
      #pragma unroll
      for (int d0 = 0; d0 < 4; ++d0){
        const int vrow = d0*16 + fr;
        const int vx = ((vrow + (vrow >> 3)) & KMASK) << 3;
        f32x4 o = {0.f, 0.f, 0.f, 0.f};
        #pragma unroll
        for (int ks = 0; ks < WINP/32; ++ks){
          bf16x8 bv = *(const bf16x8*)(vt + vrow * WINP + ((ks*32 + fk) ^ vx));
          o = mfma16(bv, aph[ks], o);
        }
        s16x4 ov;
        ov[0]=f2bf(o[0]); ov[1]=f2bf(o[1]); ov[2]=f2bf(o[2]); ov[3]=f2bf(o[3]);
        *(s16x4*)(aorow + d0*16) = ov;
      }
    } else {
      // WIN=128: reload ap per d0 (keeps VGPR below the 128 cliff)
      #pragma unroll
      for (int d0 = 0; d0 < 4; ++d0){
        const int vrow = d0*16 + fr;
        const int vx = ((vrow + (vrow >> 3)) & KMASK) << 3;
        f32x4 o = {0.f, 0.f, 0.f, 0.f};
        #pragma unroll
        for (int ks = 0; ks < WINP/32; ++ks){
          bf16x8 ap = *(const bf16x8*)(pl + fr * WINP + ((ks*32 + fk) ^ rxq));
          bf16x8 bv = *(const bf16x8*)(vt + vrow * WINP + ((ks*32 + fk) ^ vx));
          o = mfma16(bv, ap, o);
        }
        s16x4 ov;
        ov[0]=f2bf(o[0]); ov[1]=f2bf(o[1]); ov[2]=f2bf(o[2]); ov[3]=f2bf(o[3]);
        *(s16x4*)(aorow + d0*16) = ov;
      }
    }
    // no __syncthreads: smem slices are wave-private; in-wave lgkmcnt ordering suffices
  }
}

// ---------------- host ----------------
extern "C" void kernel_launch(void* const* d_in, const int* in_sizes, int n_in,
                              void* d_out, int out_size, void* d_ws, size_t ws_size,
                              hipStream_t stream){
  const int*   spec   = (const int*)d_in[0];
  const float* emb    = (const float*)d_in[1];
  const float* attn_w = (const float*)d_in[2];
  const float* attn_b = (const float*)d_in[3];
  const float* pw[4]  = {(const float*)d_in[4], (const float*)d_in[6],
                         (const float*)d_in[8], (const float*)d_in[10]};
  const float* pb[4]  = {(const float*)d_in[5], (const float*)d_in[7],
                         (const float*)d_in[9], (const float*)d_in[11]};
  float* out = (float*)d_out;

  // fixed buffers (~135.5 MB): wtq | wcast | wtpc | cbadd | embT | qkvtab
  short* wtq    = (short*)d_ws;             // [4][1536][512] transposed q,k,v
  short* wcast  = wtq + 3145728;            // [4][512][512] Wo cast
  short* wtpc   = wcast + 1048576;          // composed pm weights
  float* cbadd  = (float*)(wtpc + 62914560);// [4][512]
  short* embT   = (short*)(cbadd + 2048);   // [100][512]
  short* qkvtab = embT + 51200;             // [4][100][1536]
  short* dyn    = qkvtab + 614400;

  short* aob  = dyn;                        // [102400][512] bf16 (105 MB)
  float* pbuf = (float*)(aob + (size_t)TOK_TOTAL * 512); // split-K partials (52 MB)
  short* scratch4 = dyn;                    // all 4 pw^T panel-tiled blocks (125.8 MB,
                                            // prep only; aliases aob+pbuf head)

  static const int winv[4]  = {16, 32, 64, 128};
  static const int wpoff[4] = {0, 16*262144, 48*262144, 112*262144};
  static const int roffv[4] = {0, 200, 300, 350};
  static const int wpbv[4]  = {4, 4, 4, 2};  // waves/block: win128 uses 2-wave blocks

  (void)hipFuncSetAttribute(reinterpret_cast<const void*>(gemm256_pm<0>),
                            hipFuncAttributeMaxDynamicSharedMemorySize, 131072);
  (void)hipFuncSetAttribute(reinterpret_cast<const void*>(gemm256_pm<2>),
                            hipFuncAttributeMaxDynamicSharedMemorySize, 131072);

  dim3 tb(32, 8);
  // ---- batched prep (7 launches total) ----
  embcast_k<<<25, 256, 0, stream>>>(emb, embT);
  transpose_wtq<<<dim3(16, 16, 12), tb, 0, stream>>>(attn_w, wtq);
  cast4_k<<<512, 256, 0, stream>>>(attn_w, wcast);
  transpose_pw4<<<15360, 256, 0, stream>>>(pw[0], pw[1], pw[2], pw[3], scratch4);
  bias_fold4_k<<<2048, 256, 0, stream>>>(scratch4, attn_b, cbadd);
  gemm256_pm<2><<<960, 512, 131072, stream>>>(scratch4, 0, wcast, 512, wtpc, 512, 512, 512);
  gemm_bt<1><<<48, 256, 0, stream>>>(embT, 512, wtq, 512, qkvtab, 1536,
                                     100, 1536, 512, attn_b, 512);

  // ---- main loop: 3 launches per window ----
  for (int i = 0; i < 4; ++i){
    const int win = winv[i];
    const short* tabw = qkvtab + (size_t)i * 153600;
    const int wpb = wpbv[i];
    const int blocks = (TOK_TOTAL / win) * 8 / wpb;
    const int winp = (win < 32) ? 32 : win;
    const size_t shmem = (size_t)wpb * 80 * winp * 2;
    if (win == 16)       attn_g<16 ><<<blocks, wpb*64, shmem, stream>>>(spec, tabw, aob);
    else if (win == 32)  attn_g<32 ><<<blocks, wpb*64, shmem, stream>>>(spec, tabw, aob);
    else if (win == 64)  attn_g<64 ><<<blocks, wpb*64, shmem, stream>>>(spec, tabw, aob);
    else                 attn_g<128><<<blocks, wpb*64, shmem, stream>>>(spec, tabw, aob);
    // patch-merge split-K (kc=2048) via 256^2 pipelined GEMM, then deterministic reduce (+bias)
    const int Kpm = win * 512;
    const int S = Kpm / 2048;
    const int Mc = TOK_TOTAL / win;
    const int mtp = (Mc + 255) >> 8;
    gemm256_pm<0><<<mtp * 2 * S, 512, 131072, stream>>>(aob, Kpm, wtpc + wpoff[i], Kpm,
                                                        pbuf, Mc, 2048, 512);
    reduce_k<<<Mc / 2, 256, 0, stream>>>(pbuf, out, pb[i], cbadd + i*512,
                                         Mc, S, L_SEQ / win, roffv[i]);
  }
}